// Round 1
// baseline (2946.626 us; speedup 1.0000x reference)
//
#include <hip/hip_runtime.h>

// CriterionSA: CAM + grid-PAM + CKA loss, fp32 features, fp64 gram/CKA.
// ws layout (floats): buf0[26214400] | buf1[26214400] | G[13312 doubles]
//   buf0: CAM_out / (q,k scratch) / PAM_out   buf1: E_cam / P(attn)
// required ws = 209,821,696 bytes (~200.1 MiB)

constexpr int BB = 16;    // batch
constexpr int CH = 256;   // channels
constexpr int HW = 6400;  // 80*80
constexpr int IMW = 80;

// ---------------------------------------------------------------- CAM energy
// E[t][b] = Xf Xf^T  (256x256, inner n=6400). 64x64 tile per block.
__global__ __launch_bounds__(256) void cam_energy_k(const float* __restrict__ fS,
                                                    const float* __restrict__ fT,
                                                    float* __restrict__ E) {
  const int tile = blockIdx.x, b = blockIdx.y, t = blockIdx.z;
  const float* X = (t ? fT : fS) + (size_t)b * CH * HW;
  float* Eb = E + ((size_t)t * BB + b) * CH * CH;
  const int ti = tile >> 2, tj = tile & 3;
  __shared__ float As[64][72];  // As[nn][row]
  __shared__ float Bs[64][72];
  const int tid = threadIdx.x;
  const int ty = tid >> 4, tx = tid & 15;
  const int r = tid >> 2, seg = (tid & 3) << 4;
  float acc[4][4] = {};
  const float* pa = X + (size_t)(ti * 64 + r) * HW + seg;
  const float* pb = X + (size_t)(tj * 64 + r) * HW + seg;
  for (int n0 = 0; n0 < HW; n0 += 64) {
#pragma unroll
    for (int q = 0; q < 4; ++q) {
      float4 va = *(const float4*)(pa + n0 + q * 4);
      float4 vb = *(const float4*)(pb + n0 + q * 4);
      const int nn = seg + q * 4;
      As[nn + 0][r] = va.x; As[nn + 1][r] = va.y; As[nn + 2][r] = va.z; As[nn + 3][r] = va.w;
      Bs[nn + 0][r] = vb.x; Bs[nn + 1][r] = vb.y; Bs[nn + 2][r] = vb.z; Bs[nn + 3][r] = vb.w;
    }
    __syncthreads();
#pragma unroll 8
    for (int nn = 0; nn < 64; ++nn) {
      float4 a4 = *(const float4*)&As[nn][ty << 2];
      float4 b4 = *(const float4*)&Bs[nn][tx << 2];
      float av[4] = {a4.x, a4.y, a4.z, a4.w};
      float bw[4] = {b4.x, b4.y, b4.z, b4.w};
#pragma unroll
      for (int i = 0; i < 4; ++i)
#pragma unroll
        for (int j = 0; j < 4; ++j) acc[i][j] = fmaf(av[i], bw[j], acc[i][j]);
    }
    __syncthreads();
  }
#pragma unroll
  for (int i = 0; i < 4; ++i) {
    const int row = ti * 64 + (ty << 2) + i;
    float4 v = make_float4(acc[i][0], acc[i][1], acc[i][2], acc[i][3]);
    *(float4*)&Eb[(size_t)row * CH + tj * 64 + (tx << 2)] = v;
  }
}

// ------------------------------------------------------------- CAM softmax
// attn = softmax(rowmax - E) = exp(rowmin - E) / sum(exp(rowmin - E)), in-place.
__global__ __launch_bounds__(64) void cam_softmax_k(float* __restrict__ E) {
  const int c = blockIdx.x, b = blockIdx.y, t = blockIdx.z;
  float* row = E + (((size_t)t * BB + b) * CH + c) * CH;
  const int lane = threadIdx.x;
  float4 x = ((const float4*)row)[lane];
  float mn = fminf(fminf(x.x, x.y), fminf(x.z, x.w));
  for (int off = 32; off; off >>= 1) mn = fminf(mn, __shfl_xor(mn, off));
  float4 p;
  p.x = __expf(mn - x.x); p.y = __expf(mn - x.y);
  p.z = __expf(mn - x.z); p.w = __expf(mn - x.w);
  float s = (p.x + p.y) + (p.z + p.w);
  for (int off = 32; off; off >>= 1) s += __shfl_xor(s, off);
  const float inv = 1.0f / s;
  p.x *= inv; p.y *= inv; p.z *= inv; p.w *= inv;
  ((float4*)row)[lane] = p;
}

// ---------------------------------------------------------------- CAM out
// OUT[b][c][n] = gamma * sum_d attn[c][d] X[d][n] + X[c][n]
__global__ __launch_bounds__(256) void cam_out_k(const float* __restrict__ E,
                                                 const float* __restrict__ fS,
                                                 const float* __restrict__ fT,
                                                 const float* __restrict__ gcam,
                                                 float* __restrict__ OUT, int t) {
  const int rt = blockIdx.x / 100, ntile = blockIdx.x % 100, b = blockIdx.y;
  const float* X = (t ? fT : fS) + (size_t)b * CH * HW;
  const float* A = E + ((size_t)t * BB + b) * CH * CH;
  __shared__ float As[64][72];  // As[d_local][row]
  __shared__ float Bs[64][76];  // Bs[d_local][n_local]
  const int tid = threadIdx.x;
  const int ty = tid >> 4, tx = tid & 15;
  const int r = tid >> 2, seg = (tid & 3) << 4;
  float acc[4][4] = {};
  for (int c0 = 0; c0 < CH; c0 += 64) {
#pragma unroll
    for (int q = 0; q < 4; ++q) {
      const int idx = seg + q * 4;
      float4 va = *(const float4*)(A + (size_t)(rt * 64 + r) * CH + c0 + idx);
      As[idx + 0][r] = va.x; As[idx + 1][r] = va.y; As[idx + 2][r] = va.z; As[idx + 3][r] = va.w;
      float4 vb = *(const float4*)(X + (size_t)(c0 + r) * HW + ntile * 64 + idx);
      *(float4*)&Bs[r][idx] = vb;
    }
    __syncthreads();
#pragma unroll 8
    for (int cl = 0; cl < 64; ++cl) {
      float4 a4 = *(const float4*)&As[cl][ty << 2];
      float4 b4 = *(const float4*)&Bs[cl][tx << 2];
      float av[4] = {a4.x, a4.y, a4.z, a4.w};
      float bw[4] = {b4.x, b4.y, b4.z, b4.w};
#pragma unroll
      for (int i = 0; i < 4; ++i)
#pragma unroll
        for (int j = 0; j < 4; ++j) acc[i][j] = fmaf(av[i], bw[j], acc[i][j]);
    }
    __syncthreads();
  }
  const float g = gcam[0];
#pragma unroll
  for (int i = 0; i < 4; ++i) {
    const int row = rt * 64 + (ty << 2) + i;
    const int ncol = ntile * 64 + (tx << 2);
    float4 xv = *(const float4*)&X[(size_t)row * HW + ncol];
    float4 v;
    v.x = g * acc[i][0] + xv.x; v.y = g * acc[i][1] + xv.y;
    v.z = g * acc[i][2] + xv.z; v.w = g * acc[i][3] + xv.w;
    *(float4*)&OUT[((size_t)b * CH + row) * HW + ncol] = v;
  }
}

// ---------------------------------------------------------------- PAM q/k
// rows 0..31 -> q[n][kk] (n-major), rows 32..63 -> k[kk][n]
__global__ __launch_bounds__(256) void pam_qk_k(const float* __restrict__ fS,
                                                const float* __restrict__ fT,
                                                const float* __restrict__ Wq,
                                                const float* __restrict__ bq,
                                                const float* __restrict__ Wk,
                                                const float* __restrict__ bk,
                                                float* __restrict__ qbuf,
                                                float* __restrict__ kbuf, int t) {
  const int ntile = blockIdx.x;  // 0..3 (64 n each)
  const int ccb = blockIdx.y;    // chunk*16 + b
  const int ck = ccb >> 4, b = ccb & 15;
  const int gi = ck / 5, gj = ck % 5;
  const float* X = (t ? fT : fS) + (size_t)b * CH * HW;
  __shared__ float As[64][72];
  __shared__ float Bs[64][76];
  const int tid = threadIdx.x;
  const int ty = tid >> 4, tx = tid & 15;
  const int r = tid >> 2, seg = (tid & 3) << 4;
  float acc[4][4] = {};
  const float* Arow = (r < 32) ? (Wq + (size_t)r * CH) : (Wk + (size_t)(r - 32) * CH);
  for (int c0 = 0; c0 < CH; c0 += 64) {
#pragma unroll
    for (int q = 0; q < 4; ++q) {
      const int idx = seg + q * 4;
      float4 va = *(const float4*)(Arow + c0 + idx);
      As[idx + 0][r] = va.x; As[idx + 1][r] = va.y; As[idx + 2][r] = va.z; As[idx + 3][r] = va.w;
      const int n = ntile * 64 + idx;
      float4 vb = *(const float4*)(X + (size_t)(c0 + r) * HW +
                                   (gi * 16 + (n >> 4)) * IMW + gj * 16 + (n & 15));
      *(float4*)&Bs[r][idx] = vb;
    }
    __syncthreads();
#pragma unroll 8
    for (int cl = 0; cl < 64; ++cl) {
      float4 a4 = *(const float4*)&As[cl][ty << 2];
      float4 b4 = *(const float4*)&Bs[cl][tx << 2];
      float av[4] = {a4.x, a4.y, a4.z, a4.w};
      float bw[4] = {b4.x, b4.y, b4.z, b4.w};
#pragma unroll
      for (int i = 0; i < 4; ++i)
#pragma unroll
        for (int j = 0; j < 4; ++j) acc[i][j] = fmaf(av[i], bw[j], acc[i][j]);
    }
    __syncthreads();
  }
#pragma unroll
  for (int i = 0; i < 4; ++i) {
    const int rr = (ty << 2) + i;
    if (rr < 32) {
      const float bias = bq[rr];
#pragma unroll
      for (int j = 0; j < 4; ++j) {
        const int n = ntile * 64 + (tx << 2) + j;
        qbuf[((size_t)ccb * 256 + n) * 32 + rr] = acc[i][j] + bias;
      }
    } else {
      const float bias = bk[rr - 32];
      const int n = ntile * 64 + (tx << 2);
      float4 v = make_float4(acc[i][0] + bias, acc[i][1] + bias,
                             acc[i][2] + bias, acc[i][3] + bias);
      *(float4*)&kbuf[((size_t)ccb * 32 + (rr - 32)) * 256 + n] = v;
    }
  }
}

// --------------------------------------------------- PAM energy + softmax
// P[jq][m] = softmax_m( sum_kk q[jq][kk] k[kk][m] )  (32 query rows per block)
__global__ __launch_bounds__(256) void pam_es_k(const float* __restrict__ qbuf,
                                                const float* __restrict__ kbuf,
                                                float* __restrict__ P) {
  const int jt = blockIdx.x << 5;
  const int ccb = blockIdx.y;
  __shared__ float qs[32][36];
  __shared__ float S[32][256];
  const int tid = threadIdx.x;
  {
    const float* qt = qbuf + (size_t)ccb * 8192 + (size_t)jt * 32;
    float4 v = ((const float4*)qt)[tid];
    const int jj = tid >> 3, kk = (tid & 7) << 2;
    qs[jj][kk + 0] = v.x; qs[jj][kk + 1] = v.y; qs[jj][kk + 2] = v.z; qs[jj][kk + 3] = v.w;
  }
  float kc[32];
#pragma unroll
  for (int kk = 0; kk < 32; ++kk) kc[kk] = kbuf[((size_t)ccb * 32 + kk) * 256 + tid];
  __syncthreads();
#pragma unroll 4
  for (int jj = 0; jj < 32; ++jj) {
    float s = 0.f;
#pragma unroll
    for (int kq = 0; kq < 8; ++kq) {
      float4 qv = *(const float4*)&qs[jj][kq << 2];
      s = fmaf(qv.x, kc[4 * kq + 0], s);
      s = fmaf(qv.y, kc[4 * kq + 1], s);
      s = fmaf(qv.z, kc[4 * kq + 2], s);
      s = fmaf(qv.w, kc[4 * kq + 3], s);
    }
    S[jj][tid] = s;
  }
  __syncthreads();
  const int w = tid >> 6, lane = tid & 63;
  float* Pc = P + (size_t)ccb * 65536;
#pragma unroll
  for (int rr = 0; rr < 8; ++rr) {
    const int jj = (w << 3) + rr;
    float4 v = *(const float4*)&S[jj][lane << 2];
    float m = fmaxf(fmaxf(v.x, v.y), fmaxf(v.z, v.w));
    for (int off = 32; off; off >>= 1) m = fmaxf(m, __shfl_xor(m, off));
    float4 p;
    p.x = __expf(v.x - m); p.y = __expf(v.y - m);
    p.z = __expf(v.z - m); p.w = __expf(v.w - m);
    float s = (p.x + p.y) + (p.z + p.w);
    for (int off = 32; off; off >>= 1) s += __shfl_xor(s, off);
    const float inv = 1.f / s;
    p.x *= inv; p.y *= inv; p.z *= inv; p.w *= inv;
    *(float4*)&Pc[(size_t)(jt + jj) * 256 + (lane << 2)] = p;
  }
}

// ---------------------------------------------------------------- PAM out
// OUT[ccb][d][j] = g*( sum_c Wv[d][c] * (sum_n X[c][n] P[j][n]) + bv[d] ) + X[d][j]
__global__ __launch_bounds__(512) void pam_out_k(const float* __restrict__ P,
                                                 const float* __restrict__ fS,
                                                 const float* __restrict__ fT,
                                                 const float* __restrict__ Wv,
                                                 const float* __restrict__ bv,
                                                 const float* __restrict__ gpam,
                                                 float* __restrict__ OUT, int t) {
  const int jt = blockIdx.x;   // 0..3 (64 j each)
  const int ccb = blockIdx.y;
  const int ck = ccb >> 4, b = ccb & 15;
  const int gi = ck / 5, gj = ck % 5;
  const float* X = (t ? fT : fS) + (size_t)b * CH * HW;
  const float* Pc = P + (size_t)ccb * 65536;
  __shared__ float At[64][72];
  __shared__ float Bt[64][72];
  __shared__ float Ts[256][68];
  const int tid = threadIdx.x;
  const int ty = tid >> 5, tx = tid & 31;  // micro: 4 rows x 2 cols
  const int r = tid >> 3, seg = (tid & 7) << 3;
  // phase 1: Ts[c][j] = sum_n X[c][n] * P[j][n]
  for (int ct = 0; ct < 4; ++ct) {
    float acc[4][2] = {};
    for (int n0 = 0; n0 < 256; n0 += 64) {
#pragma unroll
      for (int q = 0; q < 2; ++q) {
        const int nn = seg + q * 4;
        const int n = n0 + nn;
        float4 va = *(const float4*)(X + (size_t)(ct * 64 + r) * HW +
                                     (gi * 16 + (n >> 4)) * IMW + gj * 16 + (n & 15));
        At[nn + 0][r] = va.x; At[nn + 1][r] = va.y; At[nn + 2][r] = va.z; At[nn + 3][r] = va.w;
        float4 vb = *(const float4*)(Pc + (size_t)(jt * 64 + r) * 256 + n);
        Bt[nn + 0][r] = vb.x; Bt[nn + 1][r] = vb.y; Bt[nn + 2][r] = vb.z; Bt[nn + 3][r] = vb.w;
      }
      __syncthreads();
#pragma unroll 8
      for (int nn = 0; nn < 64; ++nn) {
        float4 a4 = *(const float4*)&At[nn][ty << 2];
        float2 b2 = *(const float2*)&Bt[nn][tx << 1];
        float av[4] = {a4.x, a4.y, a4.z, a4.w};
        float bw[2] = {b2.x, b2.y};
#pragma unroll
        for (int i = 0; i < 4; ++i)
#pragma unroll
          for (int j = 0; j < 2; ++j) acc[i][j] = fmaf(av[i], bw[j], acc[i][j]);
      }
      __syncthreads();
    }
#pragma unroll
    for (int i = 0; i < 4; ++i) {
      Ts[ct * 64 + (ty << 2) + i][(tx << 1) + 0] = acc[i][0];
      Ts[ct * 64 + (ty << 2) + i][(tx << 1) + 1] = acc[i][1];
    }
  }
  __syncthreads();
  // phase 2
  const float g = gpam[0];
  for (int dt = 0; dt < 4; ++dt) {
    float acc[4][2] = {};
    for (int c0 = 0; c0 < 256; c0 += 64) {
#pragma unroll
      for (int q = 0; q < 2; ++q) {
        const int cl = seg + q * 4;
        float4 va = *(const float4*)(Wv + (size_t)(dt * 64 + r) * CH + c0 + cl);
        At[cl + 0][r] = va.x; At[cl + 1][r] = va.y; At[cl + 2][r] = va.z; At[cl + 3][r] = va.w;
      }
      __syncthreads();
#pragma unroll 8
      for (int cl = 0; cl < 64; ++cl) {
        float4 a4 = *(const float4*)&At[cl][ty << 2];
        float2 b2 = *(const float2*)&Ts[c0 + cl][tx << 1];
        float av[4] = {a4.x, a4.y, a4.z, a4.w};
        float bw[2] = {b2.x, b2.y};
#pragma unroll
        for (int i = 0; i < 4; ++i)
#pragma unroll
          for (int j = 0; j < 2; ++j) acc[i][j] = fmaf(av[i], bw[j], acc[i][j]);
      }
      __syncthreads();
    }
#pragma unroll
    for (int i = 0; i < 4; ++i) {
      const int d = dt * 64 + (ty << 2) + i;
      const int j = jt * 64 + (tx << 1);
      const float bias = bv[d];
      float2 xv = *(const float2*)(X + (size_t)d * HW +
                                   (gi * 16 + (j >> 4)) * IMW + gj * 16 + (j & 15));
      float2 v;
      v.x = g * (acc[i][0] + bias) + xv.x;
      v.y = g * (acc[i][1] + bias) + xv.y;
      *(float2*)&OUT[(size_t)ccb * 65536 + (size_t)d * 256 + j] = v;
    }
  }
}

// ------------------------------------------------------------------- gram
// G[g][b1][b2] += sum_i Z[g][b1][i] Z[g][b2][i]  (fp32 per-512 tile -> fp64)
__global__ __launch_bounds__(256) void gram_k(const float* __restrict__ Z, size_t gStride,
                                              size_t bStride, double* __restrict__ G) {
  __shared__ float Zs[16][516];
  const int tid = threadIdx.x;
  const int b1 = tid >> 4, b2 = tid & 15;
  const float* Zg = Z + (size_t)blockIdx.y * gStride;
  const size_t i0 = (size_t)blockIdx.x * 4096;
  double accD = 0.0;
  for (int tt = 0; tt < 8; ++tt) {
    __syncthreads();
#pragma unroll
    for (int b = 0; b < 16; ++b) {
      const float* p = Zg + (size_t)b * bStride + i0 + tt * 512;
      Zs[b][tid] = p[tid];
      Zs[b][tid + 256] = p[tid + 256];
    }
    __syncthreads();
    float4 a = make_float4(0.f, 0.f, 0.f, 0.f);
#pragma unroll 8
    for (int e = 0; e < 128; ++e) {
      float4 za = *(const float4*)&Zs[b1][e << 2];
      float4 zb = *(const float4*)&Zs[b2][e << 2];
      a.x = fmaf(za.x, zb.x, a.x);
      a.y = fmaf(za.y, zb.y, a.y);
      a.z = fmaf(za.z, zb.z, a.z);
      a.w = fmaf(za.w, zb.w, a.w);
    }
    accD += (double)((a.x + a.y) + (a.z + a.w));
  }
  atomicAdd(&G[(size_t)blockIdx.y * 256 + tid], accD);
}

// -------------------------------------------------------------- final CKA
__global__ __launch_bounds__(256) void cka_final_k(const double* __restrict__ G,
                                                   float* __restrict__ out) {
  __shared__ double red[256];
  __shared__ double srm[16], scm[16];
  __shared__ double stm;
  const int tid = threadIdx.x;
  const int r = tid >> 4, c = tid & 15;

  auto center = [&](double k) -> double {
    red[tid] = k;
    __syncthreads();
    for (int off = 8; off; off >>= 1) {
      if (c < off) red[tid] += red[tid + off];
      __syncthreads();
    }
    if (c == 0) srm[r] = red[tid] * (1.0 / 16.0);
    __syncthreads();
    red[c * 16 + r] = k;
    __syncthreads();
    for (int off = 8; off; off >>= 1) {
      if (r < off) red[c * 16 + r] += red[c * 16 + r + off];
      __syncthreads();
    }
    if (r == 0) scm[c] = red[c * 16] * (1.0 / 16.0);
    __syncthreads();
    if (tid == 0) {
      double s = 0.0;
      for (int i = 0; i < 16; ++i) s += srm[i];
      stm = s * (1.0 / 16.0);
    }
    __syncthreads();
    double v = k - srm[r] - scm[c] + stm;
    __syncthreads();
    return v;
  };
  auto reduce_sum = [&](double v) -> double {
    red[tid] = v;
    __syncthreads();
    for (int off = 128; off; off >>= 1) {
      if (tid < off) red[tid] += red[tid + off];
      __syncthreads();
    }
    double s = red[0];
    __syncthreads();
    return s;
  };
  auto cka_loss = [&](const double* KX, const double* KY) -> double {
    double cx = center(KX[tid]);
    double cy = center(KY[tid]);
    double h = reduce_sum(cx * cy);
    double v1 = reduce_sum(cx * cx);
    double v2 = reduce_sum(cy * cy);
    return -log(fabs(h / (sqrt(v1) * sqrt(v2))) + 1e-8);
  };

  double lossCAM = cka_loss(G, G + 256);
  double s = 0.0;
  for (int q = 0; q < 25; ++q)
    s += cka_loss(G + 512 + q * 256, G + 512 + 6400 + q * 256);
  if (tid == 0) {
    out[0] = (float)lossCAM;
    out[1] = (float)(s * (1.0 / 25.0));
  }
}

extern "C" void kernel_launch(void* const* d_in, const int* in_sizes, int n_in,
                              void* d_out, int out_size, void* d_ws, size_t ws_size,
                              hipStream_t stream) {
  (void)in_sizes; (void)n_in; (void)out_size; (void)ws_size;
  const float* fS = (const float*)d_in[0];
  const float* fT = (const float*)d_in[1];
  const float* Wq = (const float*)d_in[2];
  const float* bq = (const float*)d_in[3];
  const float* Wk = (const float*)d_in[4];
  const float* bk = (const float*)d_in[5];
  const float* Wv = (const float*)d_in[6];
  const float* bv = (const float*)d_in[7];
  const float* gcam = (const float*)d_in[8];
  const float* gpam = (const float*)d_in[9];
  float* out = (float*)d_out;

  float* buf0 = (float*)d_ws;            // 26214400 floats
  float* buf1 = buf0 + 26214400;         // 26214400 floats
  double* G = (double*)(buf1 + 26214400);// 13312 doubles
  float* Ecam = buf1;                    // 2*16*256*256 floats
  float* qbuf = buf0;                    // 400*256*32
  float* kbuf = buf0 + 3276800;          // 400*32*256
  float* Pbuf = buf1;                    // 400*256*256

  hipMemsetAsync(G, 0, 13312 * sizeof(double), stream);

  // ---- CAM ----
  cam_energy_k<<<dim3(16, 16, 2), 256, 0, stream>>>(fS, fT, Ecam);
  cam_softmax_k<<<dim3(256, 16, 2), 64, 0, stream>>>(Ecam);
  for (int t = 0; t < 2; ++t) {
    cam_out_k<<<dim3(400, 16), 256, 0, stream>>>(Ecam, fS, fT, gcam, buf0, t);
    gram_k<<<dim3(400, 1), 256, 0, stream>>>(buf0, (size_t)0, (size_t)1638400, G + t * 256);
  }
  // ---- PAM ----
  for (int t = 0; t < 2; ++t) {
    pam_qk_k<<<dim3(4, 400), 256, 0, stream>>>(fS, fT, Wq, bq, Wk, bk, qbuf, kbuf, t);
    pam_es_k<<<dim3(8, 400), 256, 0, stream>>>(qbuf, kbuf, Pbuf);
    pam_out_k<<<dim3(4, 400), 512, 0, stream>>>(Pbuf, fS, fT, Wv, bv, gpam, buf0, t);
    gram_k<<<dim3(16, 25), 256, 0, stream>>>(buf0, (size_t)1048576, (size_t)65536,
                                             G + 512 + t * 6400);
  }
  cka_final_k<<<1, 256, 0, stream>>>(G, out);
}

// Round 3
// 1312.091 us; speedup vs baseline: 2.2457x; 2.2457x over previous
//
#include <hip/hip_runtime.h>

// CriterionSA: CAM + grid-PAM + CKA loss.
// GEMMs in split-bf16 MFMA (hi/lo, 3 MFMAs: hh+hl+lh); cam_energy plain bf16
// (softmax saturated: diag ~6400 vs offdiag ~300). Grams fp32-tile -> fp64.
// ws layout (floats): buf0[26214400] | buf1[26214400] | G[13312 doubles]
//   CAM: buf1 = E0|E1 (attn), buf0 = CAM_out
//   PAM: buf0 = V;  buf1 = P per ccb (head 16384 floats = q|k scratch),
//        PV writes out[d][j] over P[ccb] in-place (single block owns ccb).
// required ws = 209,821,696 bytes (~200.1 MiB) -- same as round 1.

typedef short bf16x8 __attribute__((ext_vector_type(8)));
typedef float f32x4 __attribute__((ext_vector_type(4)));

constexpr int BB = 16;    // batch
constexpr int CH = 256;   // channels
constexpr int HW = 6400;  // 80*80
constexpr int IMW = 80;

// LDS tile layout: [row][128B] = hi 32 bf16 | lo 32 bf16 (or k-half0|k-half1),
// 16B-slot swizzle ^((row&7)<<4) -> frag reads ~2-way conflict max.
__device__ __forceinline__ int lds_off(int row, int half, int k2) {
  return row * 128 + ((((half << 6)) | k2) ^ ((row & 7) << 4));
}

__device__ __forceinline__ bf16x8 frag_ld(const char* base, int row, int half, int lane) {
  int off = row * 128 + ((((half << 6)) | ((lane >> 4) << 4)) ^ ((lane & 7) << 4));
  return *(const bf16x8*)(base + off);
}

__device__ __forceinline__ void cvt2(float x, unsigned short& h, unsigned short& l) {
  unsigned u = __float_as_uint(x);
  h = (unsigned short)(u >> 16);                       // truncated hi
  float r = x - __uint_as_float(u & 0xffff0000u);
  l = (unsigned short)(__float_as_uint(r) >> 16);      // truncated residual
}

__device__ __forceinline__ void cvt4(float4 v, ushort4& h, ushort4& l) {
  cvt2(v.x, h.x, l.x); cvt2(v.y, h.y, l.y);
  cvt2(v.z, h.z, l.z); cvt2(v.w, h.w, l.w);
}

__device__ __forceinline__ unsigned short bf_rnd(float x) {
  unsigned u = __float_as_uint(x);
  return (unsigned short)((u + 0x8000u) >> 16);
}

// ---------------------------------------------------------------- CAM energy
// E[t][b] = Xf Xf^T (256x256, K=6400 split in 2 halves). PARTS=1 bf16, BK=64.
__global__ __launch_bounds__(256) void cam_energy_k(const float* __restrict__ fS,
                                                    const float* __restrict__ fT,
                                                    float* __restrict__ Ebuf) {
  const int mt = blockIdx.x >> 1, nt = blockIdx.x & 1;
  const int b = blockIdx.y;
  const int t = blockIdx.z >> 1, kh = blockIdx.z & 1;
  const float* X = (t ? fT : fS) + (size_t)b * CH * HW + kh * 3200;
  __shared__ unsigned short lds[2 * 128 * 64];
  char* Ab = (char*)lds;
  char* Bb = (char*)lds + 16384;
  const int tid = threadIdx.x, lane = tid & 63, w = tid >> 6;
  const int wr = w >> 1, wc = w & 1;
  const int r0 = tid >> 3, kq = tid & 7;
  f32x4 acc[4][4] = {};
  const float* Ag = X + (size_t)mt * 128 * HW;
  const float* Bg = X + (size_t)nt * 128 * HW;
  for (int k0 = 0; k0 < 3200; k0 += 64) {
#pragma unroll
    for (int q = 0; q < 4; ++q) {
      int rr = r0 + 32 * q;
#pragma unroll
      for (int h = 0; h < 2; ++h) {
        float4 va = *(const float4*)(Ag + (size_t)rr * HW + k0 + h * 32 + kq * 4);
        float4 vb = *(const float4*)(Bg + (size_t)rr * HW + k0 + h * 32 + kq * 4);
        ushort4 ua, ub;
        ua.x = bf_rnd(va.x); ua.y = bf_rnd(va.y); ua.z = bf_rnd(va.z); ua.w = bf_rnd(va.w);
        ub.x = bf_rnd(vb.x); ub.y = bf_rnd(vb.y); ub.z = bf_rnd(vb.z); ub.w = bf_rnd(vb.w);
        *(ushort4*)(Ab + lds_off(rr, h, kq * 8)) = ua;
        *(ushort4*)(Bb + lds_off(rr, h, kq * 8)) = ub;
      }
    }
    __syncthreads();
    bf16x8 bfr[2][4];
#pragma unroll
    for (int h = 0; h < 2; ++h)
#pragma unroll
      for (int n = 0; n < 4; ++n)
        bfr[h][n] = frag_ld(Bb, wc * 64 + n * 16 + (lane & 15), h, lane);
#pragma unroll
    for (int m = 0; m < 4; ++m) {
      int arow = wr * 64 + m * 16 + (lane & 15);
      bf16x8 a0 = frag_ld(Ab, arow, 0, lane);
      bf16x8 a1 = frag_ld(Ab, arow, 1, lane);
#pragma unroll
      for (int n = 0; n < 4; ++n)
        acc[m][n] = __builtin_amdgcn_mfma_f32_16x16x32_bf16(a0, bfr[0][n], acc[m][n], 0, 0, 0);
#pragma unroll
      for (int n = 0; n < 4; ++n)
        acc[m][n] = __builtin_amdgcn_mfma_f32_16x16x32_bf16(a1, bfr[1][n], acc[m][n], 0, 0, 0);
    }
    __syncthreads();
  }
  float* Eb = Ebuf + (size_t)kh * 2097152 + ((size_t)t * BB + b) * 65536;
#pragma unroll
  for (int m = 0; m < 4; ++m)
#pragma unroll
    for (int n = 0; n < 4; ++n) {
      int row = mt * 128 + wr * 64 + m * 16 + ((lane >> 4) << 2);
      int col = nt * 128 + wc * 64 + n * 16 + (lane & 15);
#pragma unroll
      for (int r2 = 0; r2 < 4; ++r2)
        Eb[(size_t)(row + r2) * 256 + col] = acc[m][n][r2];
    }
}

// ------------------------------------------------------------- CAM softmax
// attn = exp(rowmin - (E0+E1)) / sum, written to E0.
__global__ __launch_bounds__(64) void cam_softmax_k(float* __restrict__ E0,
                                                    const float* __restrict__ E1) {
  const int c = blockIdx.x, b = blockIdx.y, t = blockIdx.z;
  size_t off = (((size_t)t * BB + b) * CH + c) * CH;
  float* row = E0 + off;
  const float* row1 = E1 + off;
  const int lane = threadIdx.x;
  float4 x = ((const float4*)row)[lane];
  float4 y = ((const float4*)row1)[lane];
  x.x += y.x; x.y += y.y; x.z += y.z; x.w += y.w;
  float mn = fminf(fminf(x.x, x.y), fminf(x.z, x.w));
  for (int o = 32; o; o >>= 1) mn = fminf(mn, __shfl_xor(mn, o));
  float4 p;
  p.x = __expf(mn - x.x); p.y = __expf(mn - x.y);
  p.z = __expf(mn - x.z); p.w = __expf(mn - x.w);
  float s = (p.x + p.y) + (p.z + p.w);
  for (int o = 32; o; o >>= 1) s += __shfl_xor(s, o);
  const float inv = 1.0f / s;
  p.x *= inv; p.y *= inv; p.z *= inv; p.w *= inv;
  ((float4*)row)[lane] = p;
}

// ----------------------------------------------------- A(256x256) @ X GEMM
// MODE 0 (cam_out): OUT[c][n] = g*sum_d A[c][d] X[d][n] + X[c][n]
// MODE 1 (pam_V):   OUT[d][n] = sum_c Wv[d][c] X[c][n] + bv[d]
// split-bf16, 128x128 tile, K=256, B staged transposed.
template <int MODE>
__global__ __launch_bounds__(256) void ax_k(const float* __restrict__ Abase, int Astride,
                                            const float* __restrict__ X,
                                            float* __restrict__ OUT,
                                            const float* __restrict__ bvec,
                                            const float* __restrict__ gsc) {
  const int mt = blockIdx.x / 50, nt = blockIdx.x % 50;
  const int b = blockIdx.y;
  const float* A = Abase + (size_t)b * Astride;
  const float* Xb = X + (size_t)b * CH * HW;
  float* OUTb = OUT + (size_t)b * CH * HW;
  const int nbase = nt * 128;
  __shared__ unsigned short lds[2 * 128 * 64];
  char* Ab = (char*)lds;
  char* Bb = (char*)lds + 16384;
  const int tid = threadIdx.x, lane = tid & 63, w = tid >> 6;
  const int wr = w >> 1, wc = w & 1;
  const int r0 = tid >> 3, kq = tid & 7;      // A staging
  const int n4 = (tid & 31) * 4, c0l = tid >> 5;  // B staging
  f32x4 acc[4][4] = {};
  float4 ra[4], rb[4];
#pragma unroll
  for (int q = 0; q < 4; ++q) {
    ra[q] = *(const float4*)(A + (size_t)(mt * 128 + r0 + 32 * q) * 256 + kq * 4);
    rb[q] = *(const float4*)(Xb + (size_t)(c0l + 8 * q) * HW + nbase + n4);
  }
  for (int s = 0; s < 8; ++s) {
#pragma unroll
    for (int q = 0; q < 4; ++q) {
      int rr = r0 + 32 * q;
      ushort4 h4, l4;
      cvt4(ra[q], h4, l4);
      *(ushort4*)(Ab + lds_off(rr, 0, kq * 8)) = h4;
      *(ushort4*)(Ab + lds_off(rr, 1, kq * 8)) = l4;
    }
#pragma unroll
    for (int q = 0; q < 4; ++q) {
      int cc = c0l + 8 * q;
      float4 v = rb[q];
#pragma unroll
      for (int jj = 0; jj < 4; ++jj) {
        int j = (jj + tid) & 3;   // rotate -> full (row&7) spread per inst
        float e = (j == 0) ? v.x : (j == 1) ? v.y : (j == 2) ? v.z : v.w;
        unsigned short h, l;
        cvt2(e, h, l);
        int row = n4 + j;
        *(unsigned short*)(Bb + lds_off(row, 0, cc * 2)) = h;
        *(unsigned short*)(Bb + lds_off(row, 1, cc * 2)) = l;
      }
    }
    __syncthreads();
    if (s < 7) {
      int k0 = (s + 1) * 32;
#pragma unroll
      for (int q = 0; q < 4; ++q) {
        ra[q] = *(const float4*)(A + (size_t)(mt * 128 + r0 + 32 * q) * 256 + k0 + kq * 4);
        rb[q] = *(const float4*)(Xb + (size_t)(k0 + c0l + 8 * q) * HW + nbase + n4);
      }
    }
    bf16x8 bfr[2][4];
#pragma unroll
    for (int h = 0; h < 2; ++h)
#pragma unroll
      for (int n = 0; n < 4; ++n)
        bfr[h][n] = frag_ld(Bb, wc * 64 + n * 16 + (lane & 15), h, lane);
#pragma unroll
    for (int m = 0; m < 4; ++m) {
      int arow = wr * 64 + m * 16 + (lane & 15);
      bf16x8 a0 = frag_ld(Ab, arow, 0, lane);
      bf16x8 a1 = frag_ld(Ab, arow, 1, lane);
#pragma unroll
      for (int n = 0; n < 4; ++n)
        acc[m][n] = __builtin_amdgcn_mfma_f32_16x16x32_bf16(a0, bfr[0][n], acc[m][n], 0, 0, 0);
#pragma unroll
      for (int n = 0; n < 4; ++n)
        acc[m][n] = __builtin_amdgcn_mfma_f32_16x16x32_bf16(a0, bfr[1][n], acc[m][n], 0, 0, 0);
#pragma unroll
      for (int n = 0; n < 4; ++n)
        acc[m][n] = __builtin_amdgcn_mfma_f32_16x16x32_bf16(a1, bfr[0][n], acc[m][n], 0, 0, 0);
    }
    __syncthreads();
  }
  float g = 0.f;
  if (MODE == 0) g = gsc[0];
#pragma unroll
  for (int m = 0; m < 4; ++m)
#pragma unroll
    for (int n = 0; n < 4; ++n) {
      int row = mt * 128 + wr * 64 + m * 16 + ((lane >> 4) << 2);
      int col = nbase + wc * 64 + n * 16 + (lane & 15);
#pragma unroll
      for (int r2 = 0; r2 < 4; ++r2) {
        size_t o = (size_t)(row + r2) * HW + col;
        float v = acc[m][n][r2];
        if (MODE == 0) OUTb[o] = g * v + Xb[o];
        else           OUTb[o] = v + bvec[row + r2];
      }
    }
}

// ---------------------------------------------------------------- PAM q/k
// rows 0..31 -> q[n][kk] at P[ccb][0..8191], rows 32..63 -> k[kk][n] at +8192
__global__ __launch_bounds__(256) void pam_qk_k(const float* __restrict__ fS,
                                                const float* __restrict__ fT,
                                                const float* __restrict__ Wq,
                                                const float* __restrict__ bq,
                                                const float* __restrict__ Wk,
                                                const float* __restrict__ bk,
                                                float* __restrict__ Pbuf, int t) {
  const int ntile = blockIdx.x;
  const int ccb = blockIdx.y;
  const int ck = ccb >> 4, b = ccb & 15;
  const int gi = ck / 5, gj = ck % 5;
  const float* X = (t ? fT : fS) + (size_t)b * CH * HW;
  float* Pb = Pbuf + (size_t)ccb * 65536;
  __shared__ float As[64][72];
  __shared__ float Bs[64][76];
  const int tid = threadIdx.x;
  const int ty = tid >> 4, tx = tid & 15;
  const int r = tid >> 2, seg = (tid & 3) << 4;
  float acc[4][4] = {};
  const float* Arow = (r < 32) ? (Wq + (size_t)r * CH) : (Wk + (size_t)(r - 32) * CH);
  for (int c0 = 0; c0 < CH; c0 += 64) {
#pragma unroll
    for (int q = 0; q < 4; ++q) {
      const int idx = seg + q * 4;
      float4 va = *(const float4*)(Arow + c0 + idx);
      As[idx + 0][r] = va.x; As[idx + 1][r] = va.y; As[idx + 2][r] = va.z; As[idx + 3][r] = va.w;
      const int n = ntile * 64 + idx;
      float4 vb = *(const float4*)(X + (size_t)(c0 + r) * HW +
                                   (gi * 16 + (n >> 4)) * IMW + gj * 16 + (n & 15));
      *(float4*)&Bs[r][idx] = vb;
    }
    __syncthreads();
#pragma unroll 8
    for (int cl = 0; cl < 64; ++cl) {
      float4 a4 = *(const float4*)&As[cl][ty << 2];
      float4 b4 = *(const float4*)&Bs[cl][tx << 2];
      float av[4] = {a4.x, a4.y, a4.z, a4.w};
      float bw[4] = {b4.x, b4.y, b4.z, b4.w};
#pragma unroll
      for (int i = 0; i < 4; ++i)
#pragma unroll
        for (int j = 0; j < 4; ++j) acc[i][j] = fmaf(av[i], bw[j], acc[i][j]);
    }
    __syncthreads();
  }
#pragma unroll
  for (int i = 0; i < 4; ++i) {
    const int rr = (ty << 2) + i;
    if (rr < 32) {
      const float bias = bq[rr];
#pragma unroll
      for (int j = 0; j < 4; ++j) {
        const int n = ntile * 64 + (tx << 2) + j;
        Pb[n * 32 + rr] = acc[i][j] + bias;
      }
    } else {
      const float bias = bk[rr - 32];
      const int n = ntile * 64 + (tx << 2);
      float4 v = make_float4(acc[i][0] + bias, acc[i][1] + bias,
                             acc[i][2] + bias, acc[i][3] + bias);
      *(float4*)&Pb[8192 + (rr - 32) * 256 + n] = v;
    }
  }
}

// --------------------------------------------------- PAM energy + softmax
// One block per ccb: loads q,k from P[ccb] head into LDS/regs, then writes
// P[ccb][j][m] = softmax_m(q[j]. k[.][m]) over the same region (safe).
__global__ __launch_bounds__(256) void pam_es_k(float* __restrict__ Pbuf) {
  const int ccb = blockIdx.x;
  float* Pc = Pbuf + (size_t)ccb * 65536;
  __shared__ float qs[256][32];
  __shared__ float S[32][256];
  const int tid = threadIdx.x;
#pragma unroll
  for (int qq = 0; qq < 8; ++qq) {
    int j = (tid >> 3) + 32 * qq;
    float4 v = *(const float4*)(Pc + j * 32 + (tid & 7) * 4);
    *(float4*)&qs[j][(tid & 7) * 4] = v;
  }
  float kc[32];
#pragma unroll
  for (int kk = 0; kk < 32; ++kk) kc[kk] = Pc[8192 + kk * 256 + tid];
  __syncthreads();
  const int w = tid >> 6, lane = tid & 63;
  for (int p = 0; p < 8; ++p) {
#pragma unroll 4
    for (int j2 = 0; j2 < 32; ++j2) {
      int row = p * 32 + j2;
      float s = 0.f;
#pragma unroll
      for (int k8 = 0; k8 < 8; ++k8) {
        float4 qv = *(const float4*)&qs[row][k8 * 4];
        s = fmaf(qv.x, kc[k8 * 4 + 0], s);
        s = fmaf(qv.y, kc[k8 * 4 + 1], s);
        s = fmaf(qv.z, kc[k8 * 4 + 2], s);
        s = fmaf(qv.w, kc[k8 * 4 + 3], s);
      }
      S[j2][tid] = s;
    }
    __syncthreads();
#pragma unroll
    for (int rr = 0; rr < 8; ++rr) {
      int jj = w * 8 + rr;
      float4 v = *(const float4*)&S[jj][lane << 2];
      float m = fmaxf(fmaxf(v.x, v.y), fmaxf(v.z, v.w));
      for (int o = 32; o; o >>= 1) m = fmaxf(m, __shfl_xor(m, o));
      float4 pv;
      pv.x = __expf(v.x - m); pv.y = __expf(v.y - m);
      pv.z = __expf(v.z - m); pv.w = __expf(v.w - m);
      float s = (pv.x + pv.y) + (pv.z + pv.w);
      for (int o = 32; o; o >>= 1) s += __shfl_xor(s, o);
      const float inv = 1.f / s;
      pv.x *= inv; pv.y *= inv; pv.z *= inv; pv.w *= inv;
      *(float4*)&Pc[(size_t)(p * 32 + jj) * 256 + (lane << 2)] = pv;
    }
    __syncthreads();
  }
}

// ---------------------------------------------------------------- PAM PV
// One 512-thr block per ccb: out[d][j] = g*sum_n V[d][n] P[j][n] + X[d][n(j)],
// written over P[ccb] after all reads complete. split-bf16, 256x256, K=256.
__global__ __launch_bounds__(512) void pam_pv_k(float* __restrict__ P,
                                                const float* __restrict__ V,
                                                const float* __restrict__ fS,
                                                const float* __restrict__ fT,
                                                const float* __restrict__ gsc, int t) {
  const int ccb = blockIdx.x;
  const int ck = ccb >> 4, b = ccb & 15;
  const int gi = ck / 5, gj = ck % 5;
  const float* Xb = (t ? fT : fS) + (size_t)b * CH * HW;
  const float* Vb = V + (size_t)b * CH * HW;
  float* Pc = P + (size_t)ccb * 65536;
  __shared__ unsigned short lds[2 * 256 * 64];
  char* Ab = (char*)lds;
  char* Bb = (char*)lds + 32768;
  const int tid = threadIdx.x, lane = tid & 63, w = tid >> 6;
  const int wr = w >> 2, wc = w & 3;
  const int r0 = tid >> 3, kq = tid & 7;
  const int pbase = gi * 16 * IMW + gj * 16;
  f32x4 acc[8][4] = {};
  for (int s = 0; s < 8; ++s) {
    int k0 = s * 32;
    int jj = k0 + kq * 4;
    int ngl = pbase + (jj >> 4) * IMW + (jj & 15);
#pragma unroll
    for (int q = 0; q < 4; ++q) {
      int rr = r0 + 64 * q;
      float4 va = *(const float4*)(Vb + (size_t)rr * HW + ngl);
      float4 vb = *(const float4*)(Pc + (size_t)rr * 256 + k0 + kq * 4);
      ushort4 h4, l4;
      cvt4(va, h4, l4);
      *(ushort4*)(Ab + lds_off(rr, 0, kq * 8)) = h4;
      *(ushort4*)(Ab + lds_off(rr, 1, kq * 8)) = l4;
      cvt4(vb, h4, l4);
      *(ushort4*)(Bb + lds_off(rr, 0, kq * 8)) = h4;
      *(ushort4*)(Bb + lds_off(rr, 1, kq * 8)) = l4;
    }
    __syncthreads();
    bf16x8 bfr[2][4];
#pragma unroll
    for (int h = 0; h < 2; ++h)
#pragma unroll
      for (int n = 0; n < 4; ++n)
        bfr[h][n] = frag_ld(Bb, wc * 64 + n * 16 + (lane & 15), h, lane);
#pragma unroll
    for (int m = 0; m < 8; ++m) {
      int arow = wr * 128 + m * 16 + (lane & 15);
      bf16x8 a0 = frag_ld(Ab, arow, 0, lane);
      bf16x8 a1 = frag_ld(Ab, arow, 1, lane);
#pragma unroll
      for (int n = 0; n < 4; ++n)
        acc[m][n] = __builtin_amdgcn_mfma_f32_16x16x32_bf16(a0, bfr[0][n], acc[m][n], 0, 0, 0);
#pragma unroll
      for (int n = 0; n < 4; ++n)
        acc[m][n] = __builtin_amdgcn_mfma_f32_16x16x32_bf16(a0, bfr[1][n], acc[m][n], 0, 0, 0);
#pragma unroll
      for (int n = 0; n < 4; ++n)
        acc[m][n] = __builtin_amdgcn_mfma_f32_16x16x32_bf16(a1, bfr[0][n], acc[m][n], 0, 0, 0);
    }
    __syncthreads();
  }
  const float g = gsc[0];
#pragma unroll
  for (int m = 0; m < 8; ++m)
#pragma unroll
    for (int n = 0; n < 4; ++n) {
      int row = wr * 128 + m * 16 + ((lane >> 4) << 2);
      int col = wc * 64 + n * 16 + (lane & 15);
      int ngl = pbase + (col >> 4) * IMW + (col & 15);
#pragma unroll
      for (int r2 = 0; r2 < 4; ++r2) {
        float v = g * acc[m][n][r2] + Xb[(size_t)(row + r2) * HW + ngl];
        Pc[(size_t)(row + r2) * 256 + col] = v;
      }
    }
}

// ------------------------------------------------------------------- gram
__global__ __launch_bounds__(256) void gram_k(const float* __restrict__ Z, size_t gStride,
                                              size_t bStride, double* __restrict__ G) {
  __shared__ float Zs[16][516];
  const int tid = threadIdx.x;
  const int b1 = tid >> 4, b2 = tid & 15;
  const float* Zg = Z + (size_t)blockIdx.y * gStride;
  const size_t i0 = (size_t)blockIdx.x * 4096;
  double accD = 0.0;
  for (int tt = 0; tt < 8; ++tt) {
    __syncthreads();
#pragma unroll
    for (int b = 0; b < 16; ++b) {
      const float* p = Zg + (size_t)b * bStride + i0 + tt * 512;
      Zs[b][tid] = p[tid];
      Zs[b][tid + 256] = p[tid + 256];
    }
    __syncthreads();
    float4 a = make_float4(0.f, 0.f, 0.f, 0.f);
#pragma unroll 8
    for (int e = 0; e < 128; ++e) {
      float4 za = *(const float4*)&Zs[b1][e << 2];
      float4 zb = *(const float4*)&Zs[b2][e << 2];
      a.x = fmaf(za.x, zb.x, a.x);
      a.y = fmaf(za.y, zb.y, a.y);
      a.z = fmaf(za.z, zb.z, a.z);
      a.w = fmaf(za.w, zb.w, a.w);
    }
    accD += (double)((a.x + a.y) + (a.z + a.w));
  }
  atomicAdd(&G[(size_t)blockIdx.y * 256 + tid], accD);
}

// -------------------------------------------------------------- final CKA
__global__ __launch_bounds__(256) void cka_final_k(const double* __restrict__ G,
                                                   float* __restrict__ out) {
  __shared__ double red[256];
  __shared__ double srm[16], scm[16];
  __shared__ double stm;
  const int tid = threadIdx.x;
  const int r = tid >> 4, c = tid & 15;

  auto center = [&](double k) -> double {
    red[tid] = k;
    __syncthreads();
    for (int off = 8; off; off >>= 1) {
      if (c < off) red[tid] += red[tid + off];
      __syncthreads();
    }
    if (c == 0) srm[r] = red[tid] * (1.0 / 16.0);
    __syncthreads();
    red[c * 16 + r] = k;
    __syncthreads();
    for (int off = 8; off; off >>= 1) {
      if (r < off) red[c * 16 + r] += red[c * 16 + r + off];
      __syncthreads();
    }
    if (r == 0) scm[c] = red[c * 16] * (1.0 / 16.0);
    __syncthreads();
    if (tid == 0) {
      double s = 0.0;
      for (int i = 0; i < 16; ++i) s += srm[i];
      stm = s * (1.0 / 16.0);
    }
    __syncthreads();
    double v = k - srm[r] - scm[c] + stm;
    __syncthreads();
    return v;
  };
  auto reduce_sum = [&](double v) -> double {
    red[tid] = v;
    __syncthreads();
    for (int off = 128; off; off >>= 1) {
      if (tid < off) red[tid] += red[tid + off];
      __syncthreads();
    }
    double s = red[0];
    __syncthreads();
    return s;
  };
  auto cka_loss = [&](const double* KX, const double* KY) -> double {
    double cx = center(KX[tid]);
    double cy = center(KY[tid]);
    double h = reduce_sum(cx * cy);
    double v1 = reduce_sum(cx * cx);
    double v2 = reduce_sum(cy * cy);
    return -log(fabs(h / (sqrt(v1) * sqrt(v2))) + 1e-8);
  };

  double lossCAM = cka_loss(G, G + 256);
  double s = 0.0;
  for (int q = 0; q < 25; ++q)
    s += cka_loss(G + 512 + q * 256, G + 512 + 6400 + q * 256);
  if (tid == 0) {
    out[0] = (float)lossCAM;
    out[1] = (float)(s * (1.0 / 25.0));
  }
}

extern "C" void kernel_launch(void* const* d_in, const int* in_sizes, int n_in,
                              void* d_out, int out_size, void* d_ws, size_t ws_size,
                              hipStream_t stream) {
  (void)in_sizes; (void)n_in; (void)out_size; (void)ws_size;
  const float* fS = (const float*)d_in[0];
  const float* fT = (const float*)d_in[1];
  const float* Wq = (const float*)d_in[2];
  const float* bq = (const float*)d_in[3];
  const float* Wk = (const float*)d_in[4];
  const float* bk = (const float*)d_in[5];
  const float* Wv = (const float*)d_in[6];
  const float* bv = (const float*)d_in[7];
  const float* gcam = (const float*)d_in[8];
  const float* gpam = (const float*)d_in[9];
  float* out = (float*)d_out;

  float* buf0 = (float*)d_ws;              // 26214400 floats
  float* buf1 = buf0 + 26214400;           // 26214400 floats
  double* G = (double*)(buf1 + 26214400);  // 13312 doubles
  float* E0 = buf1;                        // 2*16*65536
  float* E1 = buf1 + 2097152;
  float* Pbuf = buf1;                      // 400*65536

  hipMemsetAsync(G, 0, 13312 * sizeof(double), stream);

  // ---- CAM ----
  cam_energy_k<<<dim3(4, 16, 4), 256, 0, stream>>>(fS, fT, buf1);
  cam_softmax_k<<<dim3(256, 16, 2), 64, 0, stream>>>(E0, E1);
  for (int t = 0; t < 2; ++t) {
    ax_k<0><<<dim3(100, 16), 256, 0, stream>>>(E0 + (size_t)t * BB * 65536, 65536,
                                               t ? fT : fS, buf0, nullptr, gcam);
    gram_k<<<dim3(400, 1), 256, 0, stream>>>(buf0, (size_t)0, (size_t)1638400, G + t * 256);
  }
  // ---- PAM ----
  for (int t = 0; t < 2; ++t) {
    ax_k<1><<<dim3(100, 16), 256, 0, stream>>>(Wv, 0, t ? fT : fS, buf0, bv, nullptr);
    pam_qk_k<<<dim3(4, 400), 256, 0, stream>>>(fS, fT, Wq, bq, Wk, bk, Pbuf, t);
    pam_es_k<<<dim3(400), 256, 0, stream>>>(Pbuf);
    pam_pv_k<<<dim3(400), 512, 0, stream>>>(Pbuf, buf0, fS, fT, gpam, t);
    gram_k<<<dim3(16, 25), 256, 0, stream>>>(Pbuf, (size_t)1048576, (size_t)65536,
                                             G + 512 + t * 6400);
  }
  cka_final_k<<<1, 256, 0, stream>>>(G, out);
}

// Round 4
// 1276.073 us; speedup vs baseline: 2.3091x; 1.0282x over previous
//
#include <hip/hip_runtime.h>

// CriterionSA: CAM + grid-PAM + CKA loss.
// GEMMs in split-bf16 MFMA (hi/lo, 3 MFMAs: hh+hl+lh); cam_energy plain bf16
// (softmax saturated). Grams via MFMA split-bf16 (A-frag == B-frag for Z Z^T),
// fp32 acc over 1024 k -> fp64 atomics. CKA in fp64, 26 parallel blocks.
// ws layout (floats): buf0[26214400] | buf1[26214400] | G[13312 doubles]
//   CAM: buf1 = E0|E1 (attn), buf0 = CAM_out
//   PAM: buf0 = V;  buf1 = P per ccb (head 16384 floats = q|k scratch),
//        PV writes out[d][j] over P[ccb] in-place (single block owns ccb).
//   losses scratch: first 26 doubles of buf0 (dead at CKA time).
// required ws = 209,821,696 bytes (~200.1 MiB) -- same as rounds 1-3.

typedef short bf16x8 __attribute__((ext_vector_type(8)));
typedef float f32x4 __attribute__((ext_vector_type(4)));

constexpr int BB = 16;    // batch
constexpr int CH = 256;   // channels
constexpr int HW = 6400;  // 80*80
constexpr int IMW = 80;

// LDS tile layout: [row][128B] = hi 32 bf16 | lo 32 bf16 (or k-half0|k-half1),
// 16B-slot swizzle ^((row&7)<<4) -> frag reads ~2-way conflict max.
__device__ __forceinline__ int lds_off(int row, int half, int k2) {
  return row * 128 + ((((half << 6)) | k2) ^ ((row & 7) << 4));
}

__device__ __forceinline__ bf16x8 frag_ld(const char* base, int row, int half, int lane) {
  int off = row * 128 + ((((half << 6)) | ((lane >> 4) << 4)) ^ ((lane & 7) << 4));
  return *(const bf16x8*)(base + off);
}

__device__ __forceinline__ void cvt2(float x, unsigned short& h, unsigned short& l) {
  unsigned u = __float_as_uint(x);
  h = (unsigned short)(u >> 16);                       // truncated hi
  float r = x - __uint_as_float(u & 0xffff0000u);
  l = (unsigned short)(__float_as_uint(r) >> 16);      // truncated residual
}

__device__ __forceinline__ void cvt4(float4 v, ushort4& h, ushort4& l) {
  cvt2(v.x, h.x, l.x); cvt2(v.y, h.y, l.y);
  cvt2(v.z, h.z, l.z); cvt2(v.w, h.w, l.w);
}

__device__ __forceinline__ void cvt8(float4 v0, float4 v1, bf16x8& hi, bf16x8& lo) {
  unsigned short h, l;
  cvt2(v0.x, h, l); hi[0] = (short)h; lo[0] = (short)l;
  cvt2(v0.y, h, l); hi[1] = (short)h; lo[1] = (short)l;
  cvt2(v0.z, h, l); hi[2] = (short)h; lo[2] = (short)l;
  cvt2(v0.w, h, l); hi[3] = (short)h; lo[3] = (short)l;
  cvt2(v1.x, h, l); hi[4] = (short)h; lo[4] = (short)l;
  cvt2(v1.y, h, l); hi[5] = (short)h; lo[5] = (short)l;
  cvt2(v1.z, h, l); hi[6] = (short)h; lo[6] = (short)l;
  cvt2(v1.w, h, l); hi[7] = (short)h; lo[7] = (short)l;
}

__device__ __forceinline__ unsigned short bf_rnd(float x) {
  unsigned u = __float_as_uint(x);
  return (unsigned short)((u + 0x8000u) >> 16);
}

// ---------------------------------------------------------------- CAM energy
// E[t][b] = Xf Xf^T (256x256, K=6400 split in 2 halves). Symmetric: 3 tiles,
// x=0:(0,0) x=1:(1,1) diag (stage one panel, A==B), x=2:(0,1)+mirror write.
__global__ __launch_bounds__(256) void cam_energy_k(const float* __restrict__ fS,
                                                    const float* __restrict__ fT,
                                                    float* __restrict__ Ebuf) {
  const int x = blockIdx.x;
  const int mt = (x == 1) ? 1 : 0;
  const int nt = (x == 0) ? 0 : 1;
  const bool diag = (x < 2);
  const int b = blockIdx.y;
  const int t = blockIdx.z >> 1, kh = blockIdx.z & 1;
  const float* X = (t ? fT : fS) + (size_t)b * CH * HW + kh * 3200;
  __shared__ unsigned short lds[2 * 128 * 64];
  char* Ab = (char*)lds;
  char* Bb = diag ? (char*)lds : ((char*)lds + 16384);
  const int tid = threadIdx.x, lane = tid & 63, w = tid >> 6;
  const int wr = w >> 1, wc = w & 1;
  const int r0 = tid >> 3, kq = tid & 7;
  f32x4 acc[4][4] = {};
  const float* Ag = X + (size_t)mt * 128 * HW;
  const float* Bg = X + (size_t)nt * 128 * HW;
  for (int k0 = 0; k0 < 3200; k0 += 64) {
#pragma unroll
    for (int q = 0; q < 4; ++q) {
      int rr = r0 + 32 * q;
#pragma unroll
      for (int h = 0; h < 2; ++h) {
        float4 va = *(const float4*)(Ag + (size_t)rr * HW + k0 + h * 32 + kq * 4);
        ushort4 ua;
        ua.x = bf_rnd(va.x); ua.y = bf_rnd(va.y); ua.z = bf_rnd(va.z); ua.w = bf_rnd(va.w);
        *(ushort4*)(Ab + lds_off(rr, h, kq * 8)) = ua;
        if (!diag) {
          float4 vb = *(const float4*)(Bg + (size_t)rr * HW + k0 + h * 32 + kq * 4);
          ushort4 ub;
          ub.x = bf_rnd(vb.x); ub.y = bf_rnd(vb.y); ub.z = bf_rnd(vb.z); ub.w = bf_rnd(vb.w);
          *(ushort4*)(Bb + lds_off(rr, h, kq * 8)) = ub;
        }
      }
    }
    __syncthreads();
    bf16x8 bfr[2][4];
#pragma unroll
    for (int h = 0; h < 2; ++h)
#pragma unroll
      for (int n = 0; n < 4; ++n)
        bfr[h][n] = frag_ld(Bb, wc * 64 + n * 16 + (lane & 15), h, lane);
#pragma unroll
    for (int m = 0; m < 4; ++m) {
      int arow = wr * 64 + m * 16 + (lane & 15);
      bf16x8 a0 = frag_ld(Ab, arow, 0, lane);
      bf16x8 a1 = frag_ld(Ab, arow, 1, lane);
#pragma unroll
      for (int n = 0; n < 4; ++n)
        acc[m][n] = __builtin_amdgcn_mfma_f32_16x16x32_bf16(a0, bfr[0][n], acc[m][n], 0, 0, 0);
#pragma unroll
      for (int n = 0; n < 4; ++n)
        acc[m][n] = __builtin_amdgcn_mfma_f32_16x16x32_bf16(a1, bfr[1][n], acc[m][n], 0, 0, 0);
    }
    __syncthreads();
  }
  float* Eb = Ebuf + (size_t)kh * 2097152 + ((size_t)t * BB + b) * 65536;
#pragma unroll
  for (int m = 0; m < 4; ++m)
#pragma unroll
    for (int n = 0; n < 4; ++n) {
      int row = mt * 128 + wr * 64 + m * 16 + ((lane >> 4) << 2);
      int col = nt * 128 + wc * 64 + n * 16 + (lane & 15);
#pragma unroll
      for (int r2 = 0; r2 < 4; ++r2) {
        Eb[(size_t)(row + r2) * 256 + col] = acc[m][n][r2];
        if (!diag) Eb[(size_t)col * 256 + (row + r2)] = acc[m][n][r2];
      }
    }
}

// ------------------------------------------------------------- CAM softmax
// attn = exp(rowmin - (E0+E1)) / sum, written to E0.
__global__ __launch_bounds__(64) void cam_softmax_k(float* __restrict__ E0,
                                                    const float* __restrict__ E1) {
  const int c = blockIdx.x, b = blockIdx.y, t = blockIdx.z;
  size_t off = (((size_t)t * BB + b) * CH + c) * CH;
  float* row = E0 + off;
  const float* row1 = E1 + off;
  const int lane = threadIdx.x;
  float4 x = ((const float4*)row)[lane];
  float4 y = ((const float4*)row1)[lane];
  x.x += y.x; x.y += y.y; x.z += y.z; x.w += y.w;
  float mn = fminf(fminf(x.x, x.y), fminf(x.z, x.w));
  for (int o = 32; o; o >>= 1) mn = fminf(mn, __shfl_xor(mn, o));
  float4 p;
  p.x = __expf(mn - x.x); p.y = __expf(mn - x.y);
  p.z = __expf(mn - x.z); p.w = __expf(mn - x.w);
  float s = (p.x + p.y) + (p.z + p.w);
  for (int o = 32; o; o >>= 1) s += __shfl_xor(s, o);
  const float inv = 1.0f / s;
  p.x *= inv; p.y *= inv; p.z *= inv; p.w *= inv;
  ((float4*)row)[lane] = p;
}

// ----------------------------------------------------- A(256x256) @ X GEMM
// MODE 0 (cam_out): OUT[c][n] = g*sum_d A[c][d] X[d][n] + X[c][n]
// MODE 1 (pam_V):   OUT[d][n] = sum_c Wv[d][c] X[c][n] + bv[d]
// split-bf16, 128x128 tile, K=256, B staged transposed.
template <int MODE>
__global__ __launch_bounds__(256) void ax_k(const float* __restrict__ Abase, int Astride,
                                            const float* __restrict__ X,
                                            float* __restrict__ OUT,
                                            const float* __restrict__ bvec,
                                            const float* __restrict__ gsc) {
  const int mt = blockIdx.x / 50, nt = blockIdx.x % 50;
  const int b = blockIdx.y;
  const float* A = Abase + (size_t)b * Astride;
  const float* Xb = X + (size_t)b * CH * HW;
  float* OUTb = OUT + (size_t)b * CH * HW;
  const int nbase = nt * 128;
  __shared__ unsigned short lds[2 * 128 * 64];
  char* Ab = (char*)lds;
  char* Bb = (char*)lds + 16384;
  const int tid = threadIdx.x, lane = tid & 63, w = tid >> 6;
  const int wr = w >> 1, wc = w & 1;
  const int r0 = tid >> 3, kq = tid & 7;      // A staging
  const int n4 = (tid & 31) * 4, c0l = tid >> 5;  // B staging
  f32x4 acc[4][4] = {};
  float4 ra[4], rb[4];
#pragma unroll
  for (int q = 0; q < 4; ++q) {
    ra[q] = *(const float4*)(A + (size_t)(mt * 128 + r0 + 32 * q) * 256 + kq * 4);
    rb[q] = *(const float4*)(Xb + (size_t)(c0l + 8 * q) * HW + nbase + n4);
  }
  for (int s = 0; s < 8; ++s) {
#pragma unroll
    for (int q = 0; q < 4; ++q) {
      int rr = r0 + 32 * q;
      ushort4 h4, l4;
      cvt4(ra[q], h4, l4);
      *(ushort4*)(Ab + lds_off(rr, 0, kq * 8)) = h4;
      *(ushort4*)(Ab + lds_off(rr, 1, kq * 8)) = l4;
    }
#pragma unroll
    for (int q = 0; q < 4; ++q) {
      int cc = c0l + 8 * q;
      float4 v = rb[q];
#pragma unroll
      for (int jj = 0; jj < 4; ++jj) {
        int j = (jj + tid) & 3;   // rotate -> full (row&7) spread per inst
        float e = (j == 0) ? v.x : (j == 1) ? v.y : (j == 2) ? v.z : v.w;
        unsigned short h, l;
        cvt2(e, h, l);
        int row = n4 + j;
        *(unsigned short*)(Bb + lds_off(row, 0, cc * 2)) = h;
        *(unsigned short*)(Bb + lds_off(row, 1, cc * 2)) = l;
      }
    }
    __syncthreads();
    if (s < 7) {
      int k0 = (s + 1) * 32;
#pragma unroll
      for (int q = 0; q < 4; ++q) {
        ra[q] = *(const float4*)(A + (size_t)(mt * 128 + r0 + 32 * q) * 256 + k0 + kq * 4);
        rb[q] = *(const float4*)(Xb + (size_t)(k0 + c0l + 8 * q) * HW + nbase + n4);
      }
    }
    bf16x8 bfr[2][4];
#pragma unroll
    for (int h = 0; h < 2; ++h)
#pragma unroll
      for (int n = 0; n < 4; ++n)
        bfr[h][n] = frag_ld(Bb, wc * 64 + n * 16 + (lane & 15), h, lane);
#pragma unroll
    for (int m = 0; m < 4; ++m) {
      int arow = wr * 64 + m * 16 + (lane & 15);
      bf16x8 a0 = frag_ld(Ab, arow, 0, lane);
      bf16x8 a1 = frag_ld(Ab, arow, 1, lane);
#pragma unroll
      for (int n = 0; n < 4; ++n)
        acc[m][n] = __builtin_amdgcn_mfma_f32_16x16x32_bf16(a0, bfr[0][n], acc[m][n], 0, 0, 0);
#pragma unroll
      for (int n = 0; n < 4; ++n)
        acc[m][n] = __builtin_amdgcn_mfma_f32_16x16x32_bf16(a0, bfr[1][n], acc[m][n], 0, 0, 0);
#pragma unroll
      for (int n = 0; n < 4; ++n)
        acc[m][n] = __builtin_amdgcn_mfma_f32_16x16x32_bf16(a1, bfr[0][n], acc[m][n], 0, 0, 0);
    }
    __syncthreads();
  }
  float g = 0.f;
  if (MODE == 0) g = gsc[0];
#pragma unroll
  for (int m = 0; m < 4; ++m)
#pragma unroll
    for (int n = 0; n < 4; ++n) {
      int row = mt * 128 + wr * 64 + m * 16 + ((lane >> 4) << 2);
      int col = nbase + wc * 64 + n * 16 + (lane & 15);
#pragma unroll
      for (int r2 = 0; r2 < 4; ++r2) {
        size_t o = (size_t)(row + r2) * HW + col;
        float v = acc[m][n][r2];
        if (MODE == 0) OUTb[o] = g * v + Xb[o];
        else           OUTb[o] = v + bvec[row + r2];
      }
    }
}

// ---------------------------------------------------------------- PAM q/k
// rows 0..31 -> q[n][kk] at P[ccb][0..8191], rows 32..63 -> k[kk][n] at +8192
__global__ __launch_bounds__(256) void pam_qk_k(const float* __restrict__ fS,
                                                const float* __restrict__ fT,
                                                const float* __restrict__ Wq,
                                                const float* __restrict__ bq,
                                                const float* __restrict__ Wk,
                                                const float* __restrict__ bk,
                                                float* __restrict__ Pbuf, int t) {
  const int ntile = blockIdx.x;
  const int ccb = blockIdx.y;
  const int ck = ccb >> 4, b = ccb & 15;
  const int gi = ck / 5, gj = ck % 5;
  const float* X = (t ? fT : fS) + (size_t)b * CH * HW;
  float* Pb = Pbuf + (size_t)ccb * 65536;
  __shared__ float As[64][72];
  __shared__ float Bs[64][76];
  const int tid = threadIdx.x;
  const int ty = tid >> 4, tx = tid & 15;
  const int r = tid >> 2, seg = (tid & 3) << 4;
  float acc[4][4] = {};
  const float* Arow = (r < 32) ? (Wq + (size_t)r * CH) : (Wk + (size_t)(r - 32) * CH);
  for (int c0 = 0; c0 < CH; c0 += 64) {
#pragma unroll
    for (int q = 0; q < 4; ++q) {
      const int idx = seg + q * 4;
      float4 va = *(const float4*)(Arow + c0 + idx);
      As[idx + 0][r] = va.x; As[idx + 1][r] = va.y; As[idx + 2][r] = va.z; As[idx + 3][r] = va.w;
      const int n = ntile * 64 + idx;
      float4 vb = *(const float4*)(X + (size_t)(c0 + r) * HW +
                                   (gi * 16 + (n >> 4)) * IMW + gj * 16 + (n & 15));
      *(float4*)&Bs[r][idx] = vb;
    }
    __syncthreads();
#pragma unroll 8
    for (int cl = 0; cl < 64; ++cl) {
      float4 a4 = *(const float4*)&As[cl][ty << 2];
      float4 b4 = *(const float4*)&Bs[cl][tx << 2];
      float av[4] = {a4.x, a4.y, a4.z, a4.w};
      float bw[4] = {b4.x, b4.y, b4.z, b4.w};
#pragma unroll
      for (int i = 0; i < 4; ++i)
#pragma unroll
        for (int j = 0; j < 4; ++j) acc[i][j] = fmaf(av[i], bw[j], acc[i][j]);
    }
    __syncthreads();
  }
#pragma unroll
  for (int i = 0; i < 4; ++i) {
    const int rr = (ty << 2) + i;
    if (rr < 32) {
      const float bias = bq[rr];
#pragma unroll
      for (int j = 0; j < 4; ++j) {
        const int n = ntile * 64 + (tx << 2) + j;
        Pb[n * 32 + rr] = acc[i][j] + bias;
      }
    } else {
      const float bias = bk[rr - 32];
      const int n = ntile * 64 + (tx << 2);
      float4 v = make_float4(acc[i][0] + bias, acc[i][1] + bias,
                             acc[i][2] + bias, acc[i][3] + bias);
      *(float4*)&Pb[8192 + (rr - 32) * 256 + n] = v;
    }
  }
}

// --------------------------------------------------- PAM energy + softmax
// One block per ccb: loads q,k from P[ccb] head into LDS/regs, then writes
// P[ccb][j][m] = softmax_m(q[j]. k[.][m]) over the same region (safe).
__global__ __launch_bounds__(256) void pam_es_k(float* __restrict__ Pbuf) {
  const int ccb = blockIdx.x;
  float* Pc = Pbuf + (size_t)ccb * 65536;
  __shared__ float qs[256][32];
  __shared__ float S[32][256];
  const int tid = threadIdx.x;
#pragma unroll
  for (int qq = 0; qq < 8; ++qq) {
    int j = (tid >> 3) + 32 * qq;
    float4 v = *(const float4*)(Pc + j * 32 + (tid & 7) * 4);
    *(float4*)&qs[j][(tid & 7) * 4] = v;
  }
  float kc[32];
#pragma unroll
  for (int kk = 0; kk < 32; ++kk) kc[kk] = Pc[8192 + kk * 256 + tid];
  __syncthreads();
  const int w = tid >> 6, lane = tid & 63;
  for (int p = 0; p < 8; ++p) {
#pragma unroll 4
    for (int j2 = 0; j2 < 32; ++j2) {
      int row = p * 32 + j2;
      float s = 0.f;
#pragma unroll
      for (int k8 = 0; k8 < 8; ++k8) {
        float4 qv = *(const float4*)&qs[row][k8 * 4];
        s = fmaf(qv.x, kc[k8 * 4 + 0], s);
        s = fmaf(qv.y, kc[k8 * 4 + 1], s);
        s = fmaf(qv.z, kc[k8 * 4 + 2], s);
        s = fmaf(qv.w, kc[k8 * 4 + 3], s);
      }
      S[j2][tid] = s;
    }
    __syncthreads();
#pragma unroll
    for (int rr = 0; rr < 8; ++rr) {
      int jj = w * 8 + rr;
      float4 v = *(const float4*)&S[jj][lane << 2];
      float m = fmaxf(fmaxf(v.x, v.y), fmaxf(v.z, v.w));
      for (int o = 32; o; o >>= 1) m = fmaxf(m, __shfl_xor(m, o));
      float4 pv;
      pv.x = __expf(v.x - m); pv.y = __expf(v.y - m);
      pv.z = __expf(v.z - m); pv.w = __expf(v.w - m);
      float s = (pv.x + pv.y) + (pv.z + pv.w);
      for (int o = 32; o; o >>= 1) s += __shfl_xor(s, o);
      const float inv = 1.f / s;
      pv.x *= inv; pv.y *= inv; pv.z *= inv; pv.w *= inv;
      *(float4*)&Pc[(size_t)(p * 32 + jj) * 256 + (lane << 2)] = pv;
    }
    __syncthreads();
  }
}

// ---------------------------------------------------------------- PAM PV
// One 512-thr block per ccb: out[d][j] = g*sum_n V[d][n] P[j][n] + X[d][n(j)],
// written over P[ccb] after all reads complete. split-bf16, 256x256, K=256.
__global__ __launch_bounds__(512) void pam_pv_k(float* __restrict__ P,
                                                const float* __restrict__ V,
                                                const float* __restrict__ fS,
                                                const float* __restrict__ fT,
                                                const float* __restrict__ gsc, int t) {
  const int ccb = blockIdx.x;
  const int ck = ccb >> 4, b = ccb & 15;
  const int gi = ck / 5, gj = ck % 5;
  const float* Xb = (t ? fT : fS) + (size_t)b * CH * HW;
  const float* Vb = V + (size_t)b * CH * HW;
  float* Pc = P + (size_t)ccb * 65536;
  __shared__ unsigned short lds[2 * 256 * 64];
  char* Ab = (char*)lds;
  char* Bb = (char*)lds + 32768;
  const int tid = threadIdx.x, lane = tid & 63, w = tid >> 6;
  const int wr = w >> 2, wc = w & 3;
  const int r0 = tid >> 3, kq = tid & 7;
  const int pbase = gi * 16 * IMW + gj * 16;
  f32x4 acc[8][4] = {};
  for (int s = 0; s < 8; ++s) {
    int k0 = s * 32;
    int jj = k0 + kq * 4;
    int ngl = pbase + (jj >> 4) * IMW + (jj & 15);
#pragma unroll
    for (int q = 0; q < 4; ++q) {
      int rr = r0 + 64 * q;
      float4 va = *(const float4*)(Vb + (size_t)rr * HW + ngl);
      float4 vb = *(const float4*)(Pc + (size_t)rr * 256 + k0 + kq * 4);
      ushort4 h4, l4;
      cvt4(va, h4, l4);
      *(ushort4*)(Ab + lds_off(rr, 0, kq * 8)) = h4;
      *(ushort4*)(Ab + lds_off(rr, 1, kq * 8)) = l4;
      cvt4(vb, h4, l4);
      *(ushort4*)(Bb + lds_off(rr, 0, kq * 8)) = h4;
      *(ushort4*)(Bb + lds_off(rr, 1, kq * 8)) = l4;
    }
    __syncthreads();
    bf16x8 bfr[2][4];
#pragma unroll
    for (int h = 0; h < 2; ++h)
#pragma unroll
      for (int n = 0; n < 4; ++n)
        bfr[h][n] = frag_ld(Bb, wc * 64 + n * 16 + (lane & 15), h, lane);
#pragma unroll
    for (int m = 0; m < 8; ++m) {
      int arow = wr * 128 + m * 16 + (lane & 15);
      bf16x8 a0 = frag_ld(Ab, arow, 0, lane);
      bf16x8 a1 = frag_ld(Ab, arow, 1, lane);
#pragma unroll
      for (int n = 0; n < 4; ++n)
        acc[m][n] = __builtin_amdgcn_mfma_f32_16x16x32_bf16(a0, bfr[0][n], acc[m][n], 0, 0, 0);
#pragma unroll
      for (int n = 0; n < 4; ++n)
        acc[m][n] = __builtin_amdgcn_mfma_f32_16x16x32_bf16(a0, bfr[1][n], acc[m][n], 0, 0, 0);
#pragma unroll
      for (int n = 0; n < 4; ++n)
        acc[m][n] = __builtin_amdgcn_mfma_f32_16x16x32_bf16(a1, bfr[0][n], acc[m][n], 0, 0, 0);
    }
    __syncthreads();
  }
  const float g = gsc[0];
#pragma unroll
  for (int m = 0; m < 8; ++m)
#pragma unroll
    for (int n = 0; n < 4; ++n) {
      int row = wr * 128 + m * 16 + ((lane >> 4) << 2);
      int col = wc * 64 + n * 16 + (lane & 15);
      int ngl = pbase + (col >> 4) * IMW + (col & 15);
#pragma unroll
      for (int r2 = 0; r2 < 4; ++r2) {
        float v = g * acc[m][n][r2] + Xb[(size_t)(row + r2) * HW + ngl];
        Pc[(size_t)(row + r2) * 256 + col] = v;
      }
    }
}

// ------------------------------------------------------------- gram (MFMA)
// G[group][b1][b2] += Z[b1].Z[b2] via split-bf16 MFMA; A-frag == B-frag.
// Block: 4 waves x 1024 k (covers 4096 k). Each element read exactly once.
// fp32 acc over 1024 k (3x MFMA chain), then fp64 atomics to G.
__global__ __launch_bounds__(256) void gram_mfma_k(const float* __restrict__ Z,
                                                   size_t gStride, size_t bStride,
                                                   double* __restrict__ G) {
  const int tid = threadIdx.x, lane = tid & 63, w = tid >> 6;
  const float* Zg = Z + (size_t)blockIdx.y * gStride;
  const float* p = Zg + (size_t)(lane & 15) * bStride +
                   (size_t)blockIdx.x * 4096 + w * 1024 + ((lane >> 4) << 3);
  f32x4 acc = {};
#pragma unroll 4
  for (int s = 0; s < 32; ++s) {
    float4 v0 = *(const float4*)(p + s * 32);
    float4 v1 = *(const float4*)(p + s * 32 + 4);
    bf16x8 hi, lo;
    cvt8(v0, v1, hi, lo);
    acc = __builtin_amdgcn_mfma_f32_16x16x32_bf16(hi, hi, acc, 0, 0, 0);
    acc = __builtin_amdgcn_mfma_f32_16x16x32_bf16(hi, lo, acc, 0, 0, 0);
    acc = __builtin_amdgcn_mfma_f32_16x16x32_bf16(lo, hi, acc, 0, 0, 0);
  }
  double* Gt = G + (size_t)blockIdx.y * 256;
  const int col = lane & 15, row0 = (lane >> 4) << 2;
#pragma unroll
  for (int i = 0; i < 4; ++i)
    atomicAdd(&Gt[(size_t)(row0 + i) * 16 + col], (double)acc[i]);
}

// -------------------------------------------------------------- CKA pairs
// One block per loss pair: q=0 -> CAM, q=1..25 -> PAM chunk q-1.
__global__ __launch_bounds__(256) void cka_pair_k(const double* __restrict__ G,
                                                  double* __restrict__ losses) {
  const int q = blockIdx.x;
  const double* KX = (q == 0) ? G : G + 512 + (size_t)(q - 1) * 256;
  const double* KY = (q == 0) ? G + 256 : G + 512 + 6400 + (size_t)(q - 1) * 256;
  __shared__ double red[256];
  __shared__ double srm[16], scm[16];
  __shared__ double stm;
  const int tid = threadIdx.x;
  const int r = tid >> 4, c = tid & 15;

  auto center = [&](double k) -> double {
    red[tid] = k;
    __syncthreads();
    for (int off = 8; off; off >>= 1) {
      if (c < off) red[tid] += red[tid + off];
      __syncthreads();
    }
    if (c == 0) srm[r] = red[tid] * (1.0 / 16.0);
    __syncthreads();
    red[c * 16 + r] = k;
    __syncthreads();
    for (int off = 8; off; off >>= 1) {
      if (r < off) red[c * 16 + r] += red[c * 16 + r + off];
      __syncthreads();
    }
    if (r == 0) scm[c] = red[c * 16] * (1.0 / 16.0);
    __syncthreads();
    if (tid == 0) {
      double s = 0.0;
      for (int i = 0; i < 16; ++i) s += srm[i];
      stm = s * (1.0 / 16.0);
    }
    __syncthreads();
    double v = k - srm[r] - scm[c] + stm;
    __syncthreads();
    return v;
  };
  auto reduce_sum = [&](double v) -> double {
    red[tid] = v;
    __syncthreads();
    for (int off = 128; off; off >>= 1) {
      if (tid < off) red[tid] += red[tid + off];
      __syncthreads();
    }
    double s = red[0];
    __syncthreads();
    return s;
  };
  double cx = center(KX[tid]);
  double cy = center(KY[tid]);
  double h = reduce_sum(cx * cy);
  double v1 = reduce_sum(cx * cx);
  double v2 = reduce_sum(cy * cy);
  if (tid == 0) losses[q] = -log(fabs(h / (sqrt(v1) * sqrt(v2))) + 1e-8);
}

__global__ void cka_combine_k(const double* __restrict__ losses,
                              float* __restrict__ out) {
  if (threadIdx.x == 0) {
    out[0] = (float)losses[0];
    double s = 0.0;
    for (int q = 1; q <= 25; ++q) s += losses[q];
    out[1] = (float)(s * (1.0 / 25.0));
  }
}

extern "C" void kernel_launch(void* const* d_in, const int* in_sizes, int n_in,
                              void* d_out, int out_size, void* d_ws, size_t ws_size,
                              hipStream_t stream) {
  (void)in_sizes; (void)n_in; (void)out_size; (void)ws_size;
  const float* fS = (const float*)d_in[0];
  const float* fT = (const float*)d_in[1];
  const float* Wq = (const float*)d_in[2];
  const float* bq = (const float*)d_in[3];
  const float* Wk = (const float*)d_in[4];
  const float* bk = (const float*)d_in[5];
  const float* Wv = (const float*)d_in[6];
  const float* bv = (const float*)d_in[7];
  const float* gcam = (const float*)d_in[8];
  const float* gpam = (const float*)d_in[9];
  float* out = (float*)d_out;

  float* buf0 = (float*)d_ws;              // 26214400 floats
  float* buf1 = buf0 + 26214400;           // 26214400 floats
  double* G = (double*)(buf1 + 26214400);  // 13312 doubles
  float* E0 = buf1;                        // 2*16*65536
  float* E1 = buf1 + 2097152;
  float* Pbuf = buf1;                      // 400*65536
  double* losses = (double*)buf0;          // 26 doubles, dead region at CKA time

  hipMemsetAsync(G, 0, 13312 * sizeof(double), stream);

  // ---- CAM ----
  cam_energy_k<<<dim3(3, 16, 4), 256, 0, stream>>>(fS, fT, buf1);
  cam_softmax_k<<<dim3(256, 16, 2), 64, 0, stream>>>(E0, E1);
  for (int t = 0; t < 2; ++t) {
    ax_k<0><<<dim3(100, 16), 256, 0, stream>>>(E0 + (size_t)t * BB * 65536, 65536,
                                               t ? fT : fS, buf0, nullptr, gcam);
    gram_mfma_k<<<dim3(400, 1), 256, 0, stream>>>(buf0, (size_t)0, (size_t)1638400,
                                                  G + t * 256);
  }
  // ---- PAM ----
  for (int t = 0; t < 2; ++t) {
    ax_k<1><<<dim3(100, 16), 256, 0, stream>>>(Wv, 0, t ? fT : fS, buf0, bv, nullptr);
    pam_qk_k<<<dim3(4, 400), 256, 0, stream>>>(fS, fT, Wq, bq, Wk, bk, Pbuf, t);
    pam_es_k<<<dim3(400), 256, 0, stream>>>(Pbuf);
    pam_pv_k<<<dim3(400), 512, 0, stream>>>(Pbuf, buf0, fS, fT, gpam, t);
    gram_mfma_k<<<dim3(16, 25), 256, 0, stream>>>(Pbuf, (size_t)1048576, (size_t)65536,
                                                  G + 512 + t * 6400);
  }
  cka_pair_k<<<dim3(26), 256, 0, stream>>>(G, losses);
  cka_combine_k<<<dim3(1), 64, 0, stream>>>(losses, out);
}

// Round 7
// 1122.242 us; speedup vs baseline: 2.6257x; 1.1371x over previous
//
#include <hip/hip_runtime.h>

// CriterionSA: CAM + grid-PAM + CKA loss.
// GEMMs in split-bf16 MFMA (hi/lo, 3 MFMAs: hh+hl+lh); cam_energy plain bf16
// (softmax saturated). Grams via MFMA split-bf16 (A-frag == B-frag for Z Z^T),
// fp32 acc -> fp64 atomics. CKA in fp64, 26 parallel blocks.
// ws layout (floats): buf0[26214400] | buf1[26214400] | G[13312 doubles]
//   CAM: buf1 = 10 partial E buffers (K-split), softmax sums -> partial0 = attn
//        buf0 = CAM_out
//   PAM per t: buf0[0..3.28M) = q_t[b][n][32], [3.28M..6.55M) = k[b][32][n]
//        es -> P in buf1; then V = ax_k<1> overwrites buf0; pv writes over P.
// required ws = 209,821,696 bytes (~200.1 MiB) -- same as rounds 1-6.
// R6 fix: qk_k B-staging covered only 128 of 256 LDS rows (NaN in loss_PAM);
// staging map now n4=(tid&63)*4, c0l=tid>>6, 8 k-slots per thread.

typedef short bf16x8 __attribute__((ext_vector_type(8)));
typedef float f32x4 __attribute__((ext_vector_type(4)));

constexpr int BB = 16;    // batch
constexpr int CH = 256;   // channels
constexpr int HW = 6400;  // 80*80
constexpr int IMW = 80;

// LDS tile layout: [row][128B] = hi 32 bf16 | lo 32 bf16 (or k-half0|k-half1),
// 16B-slot swizzle ^((row&7)<<4) -> frag reads ~2-way conflict max.
__device__ __forceinline__ int lds_off(int row, int half, int k2) {
  return row * 128 + ((((half << 6)) | k2) ^ ((row & 7) << 4));
}

__device__ __forceinline__ bf16x8 frag_ld(const char* base, int row, int half, int lane) {
  int off = row * 128 + ((((half << 6)) | ((lane >> 4) << 4)) ^ ((lane & 7) << 4));
  return *(const bf16x8*)(base + off);
}

__device__ __forceinline__ void cvt2(float x, unsigned short& h, unsigned short& l) {
  unsigned u = __float_as_uint(x);
  h = (unsigned short)(u >> 16);                       // truncated hi
  float r = x - __uint_as_float(u & 0xffff0000u);
  l = (unsigned short)(__float_as_uint(r) >> 16);      // truncated residual
}

__device__ __forceinline__ void cvt4(float4 v, ushort4& h, ushort4& l) {
  cvt2(v.x, h.x, l.x); cvt2(v.y, h.y, l.y);
  cvt2(v.z, h.z, l.z); cvt2(v.w, h.w, l.w);
}

__device__ __forceinline__ void cvt8(float4 v0, float4 v1, bf16x8& hi, bf16x8& lo) {
  unsigned short h, l;
  cvt2(v0.x, h, l); hi[0] = (short)h; lo[0] = (short)l;
  cvt2(v0.y, h, l); hi[1] = (short)h; lo[1] = (short)l;
  cvt2(v0.z, h, l); hi[2] = (short)h; lo[2] = (short)l;
  cvt2(v0.w, h, l); hi[3] = (short)h; lo[3] = (short)l;
  cvt2(v1.x, h, l); hi[4] = (short)h; lo[4] = (short)l;
  cvt2(v1.y, h, l); hi[5] = (short)h; lo[5] = (short)l;
  cvt2(v1.z, h, l); hi[6] = (short)h; lo[6] = (short)l;
  cvt2(v1.w, h, l); hi[7] = (short)h; lo[7] = (short)l;
}

__device__ __forceinline__ unsigned short bf_rnd(float x) {
  unsigned u = __float_as_uint(x);
  return (unsigned short)((u + 0x8000u) >> 16);
}

// ---------------------------------------------------------------- CAM energy
// Partial E[kc][t][b] = X(:,kslice) X(:,kslice)^T, kc=0..9 (K=640 each).
// One 512-thread block computes the FULL 256x256 tile: one LDS panel is both
// MFMA operands (A-frag == B-frag). Plain bf16 (softmax saturated).
__global__ __launch_bounds__(512) void cam_energy_k(const float* __restrict__ fS,
                                                    const float* __restrict__ fT,
                                                    float* __restrict__ part) {
  const int kc = blockIdx.x, b = blockIdx.y, t = blockIdx.z;
  const float* X = (t ? fT : fS) + (size_t)b * CH * HW;
  __shared__ unsigned short lds[256 * 64];  // 32 KB: 256 rows x 128B
  char* Ab = (char*)lds;
  const int tid = threadIdx.x, lane = tid & 63, w = tid >> 6;
  const int wr = w >> 2, wc = w & 3;
  const int r0 = tid >> 1, half = tid & 1;
  f32x4 acc[8][4] = {};
  for (int it = 0; it < 10; ++it) {
    const int k0 = (kc * 10 + it) * 64 + half * 32;
    float4 v[8];
#pragma unroll
    for (int q = 0; q < 8; ++q)
      v[q] = *(const float4*)(X + (size_t)r0 * HW + k0 + q * 4);
    __syncthreads();   // prev iter's frag reads done before overwrite
#pragma unroll
    for (int q = 0; q < 8; ++q) {
      ushort4 u;
      u.x = bf_rnd(v[q].x); u.y = bf_rnd(v[q].y);
      u.z = bf_rnd(v[q].z); u.w = bf_rnd(v[q].w);
      *(ushort4*)(Ab + lds_off(r0, half, q * 8)) = u;
    }
    __syncthreads();
    bf16x8 bfr[2][4];
#pragma unroll
    for (int h = 0; h < 2; ++h)
#pragma unroll
      for (int n = 0; n < 4; ++n)
        bfr[h][n] = frag_ld(Ab, wc * 64 + n * 16 + (lane & 15), h, lane);
#pragma unroll
    for (int m = 0; m < 8; ++m) {
      int arow = wr * 128 + m * 16 + (lane & 15);
      bf16x8 a0 = frag_ld(Ab, arow, 0, lane);
      bf16x8 a1 = frag_ld(Ab, arow, 1, lane);
#pragma unroll
      for (int n = 0; n < 4; ++n)
        acc[m][n] = __builtin_amdgcn_mfma_f32_16x16x32_bf16(a0, bfr[0][n], acc[m][n], 0, 0, 0);
#pragma unroll
      for (int n = 0; n < 4; ++n)
        acc[m][n] = __builtin_amdgcn_mfma_f32_16x16x32_bf16(a1, bfr[1][n], acc[m][n], 0, 0, 0);
    }
  }
  float* Eb = part + (((size_t)kc * 2 + t) * BB + b) * 65536;
#pragma unroll
  for (int m = 0; m < 8; ++m)
#pragma unroll
    for (int n = 0; n < 4; ++n) {
      int row = wr * 128 + m * 16 + ((lane >> 4) << 2);
      int col = wc * 64 + n * 16 + (lane & 15);
#pragma unroll
      for (int r2 = 0; r2 < 4; ++r2)
        Eb[(size_t)(row + r2) * 256 + col] = acc[m][n][r2];
    }
}

// ------------------------------------------------------------- CAM softmax
// attn = exp(rowmin - sum_p partE[p]) / rowsum, written into partial 0.
__global__ __launch_bounds__(64) void cam_softmax_k(float* __restrict__ part) {
  const int c = blockIdx.x, b = blockIdx.y, t = blockIdx.z;
  const size_t base = (((size_t)t * BB + b) * CH + c) * CH;
  const int lane = threadIdx.x;
  float4 x = make_float4(0.f, 0.f, 0.f, 0.f);
#pragma unroll
  for (int p = 0; p < 10; ++p) {
    float4 y = ((const float4*)(part + (size_t)p * 2097152 + base))[lane];
    x.x += y.x; x.y += y.y; x.z += y.z; x.w += y.w;
  }
  float mn = fminf(fminf(x.x, x.y), fminf(x.z, x.w));
  for (int o = 32; o; o >>= 1) mn = fminf(mn, __shfl_xor(mn, o));
  float4 p4;
  p4.x = __expf(mn - x.x); p4.y = __expf(mn - x.y);
  p4.z = __expf(mn - x.z); p4.w = __expf(mn - x.w);
  float s = (p4.x + p4.y) + (p4.z + p4.w);
  for (int o = 32; o; o >>= 1) s += __shfl_xor(s, o);
  const float inv = 1.0f / s;
  p4.x *= inv; p4.y *= inv; p4.z *= inv; p4.w *= inv;
  ((float4*)(part + base))[lane] = p4;
}

// ----------------------------------------------------- A(256x256) @ X GEMM
// MODE 0 (cam_out): OUT[c][n] = g*sum_d A[c][d] X[d][n] + X[c][n]
// MODE 1 (pam_V):   OUT[d][n] = sum_c Wv[d][c] X[c][n] + bv[d]
// split-bf16, 128x128 tile, K=256, B staged transposed.
template <int MODE>
__global__ __launch_bounds__(256) void ax_k(const float* __restrict__ Abase, int Astride,
                                            const float* __restrict__ X,
                                            float* __restrict__ OUT,
                                            const float* __restrict__ bvec,
                                            const float* __restrict__ gsc) {
  const int mt = blockIdx.x / 50, nt = blockIdx.x % 50;
  const int b = blockIdx.y;
  const float* A = Abase + (size_t)b * Astride;
  const float* Xb = X + (size_t)b * CH * HW;
  float* OUTb = OUT + (size_t)b * CH * HW;
  const int nbase = nt * 128;
  __shared__ unsigned short lds[2 * 128 * 64];
  char* Ab = (char*)lds;
  char* Bb = (char*)lds + 16384;
  const int tid = threadIdx.x, lane = tid & 63, w = tid >> 6;
  const int wr = w >> 1, wc = w & 1;
  const int r0 = tid >> 3, kq = tid & 7;      // A staging
  const int n4 = (tid & 31) * 4, c0l = tid >> 5;  // B staging
  f32x4 acc[4][4] = {};
  float4 ra[4], rb[4];
#pragma unroll
  for (int q = 0; q < 4; ++q) {
    ra[q] = *(const float4*)(A + (size_t)(mt * 128 + r0 + 32 * q) * 256 + kq * 4);
    rb[q] = *(const float4*)(Xb + (size_t)(c0l + 8 * q) * HW + nbase + n4);
  }
  for (int s = 0; s < 8; ++s) {
#pragma unroll
    for (int q = 0; q < 4; ++q) {
      int rr = r0 + 32 * q;
      ushort4 h4, l4;
      cvt4(ra[q], h4, l4);
      *(ushort4*)(Ab + lds_off(rr, 0, kq * 8)) = h4;
      *(ushort4*)(Ab + lds_off(rr, 1, kq * 8)) = l4;
    }
#pragma unroll
    for (int q = 0; q < 4; ++q) {
      int cc = c0l + 8 * q;
      float4 v = rb[q];
#pragma unroll
      for (int jj = 0; jj < 4; ++jj) {
        int j = (jj + tid) & 3;   // rotate -> full (row&7) spread per inst
        float e = (j == 0) ? v.x : (j == 1) ? v.y : (j == 2) ? v.z : v.w;
        unsigned short h, l;
        cvt2(e, h, l);
        int row = n4 + j;
        *(unsigned short*)(Bb + lds_off(row, 0, cc * 2)) = h;
        *(unsigned short*)(Bb + lds_off(row, 1, cc * 2)) = l;
      }
    }
    __syncthreads();
    if (s < 7) {
      int k0 = (s + 1) * 32;
#pragma unroll
      for (int q = 0; q < 4; ++q) {
        ra[q] = *(const float4*)(A + (size_t)(mt * 128 + r0 + 32 * q) * 256 + k0 + kq * 4);
        rb[q] = *(const float4*)(Xb + (size_t)(k0 + c0l + 8 * q) * HW + nbase + n4);
      }
    }
    bf16x8 bfr[2][4];
#pragma unroll
    for (int h = 0; h < 2; ++h)
#pragma unroll
      for (int n = 0; n < 4; ++n)
        bfr[h][n] = frag_ld(Bb, wc * 64 + n * 16 + (lane & 15), h, lane);
#pragma unroll
    for (int m = 0; m < 4; ++m) {
      int arow = wr * 64 + m * 16 + (lane & 15);
      bf16x8 a0 = frag_ld(Ab, arow, 0, lane);
      bf16x8 a1 = frag_ld(Ab, arow, 1, lane);
#pragma unroll
      for (int n = 0; n < 4; ++n)
        acc[m][n] = __builtin_amdgcn_mfma_f32_16x16x32_bf16(a0, bfr[0][n], acc[m][n], 0, 0, 0);
#pragma unroll
      for (int n = 0; n < 4; ++n)
        acc[m][n] = __builtin_amdgcn_mfma_f32_16x16x32_bf16(a0, bfr[1][n], acc[m][n], 0, 0, 0);
#pragma unroll
      for (int n = 0; n < 4; ++n)
        acc[m][n] = __builtin_amdgcn_mfma_f32_16x16x32_bf16(a1, bfr[0][n], acc[m][n], 0, 0, 0);
    }
    __syncthreads();
  }
  float g = 0.f;
  if (MODE == 0) g = gsc[0];
#pragma unroll
  for (int m = 0; m < 4; ++m)
#pragma unroll
    for (int n = 0; n < 4; ++n) {
      int row = mt * 128 + wr * 64 + m * 16 + ((lane >> 4) << 2);
      int col = nbase + wc * 64 + n * 16 + (lane & 15);
#pragma unroll
      for (int r2 = 0; r2 < 4; ++r2) {
        size_t o = (size_t)(row + r2) * HW + col;
        float v = acc[m][n][r2];
        if (MODE == 0) OUTb[o] = g * v + Xb[o];
        else           OUTb[o] = v + bvec[row + r2];
      }
    }
}

// ------------------------------------------------------------ PAM q/k GEMM
// Full-image 1x1 conv: rows 0..31 = Wq, 32..63 = Wk; N = 6400, K = 256.
// Outputs: qt[b][n][32] (n-major, +bq), kf[b][32][n] (+bk). split-bf16.
// B staging: each thread owns rows n4..n4+3 (n4=(tid&63)*4, all 256 rows)
// and k-slots cc = (tid>>6) + 4q, q=0..7 (all 32 k).
__global__ __launch_bounds__(256) void qk_k(const float* __restrict__ X,
                                            const float* __restrict__ Wq,
                                            const float* __restrict__ bq,
                                            const float* __restrict__ Wk,
                                            const float* __restrict__ bk,
                                            float* __restrict__ qt,
                                            float* __restrict__ kf) {
  const int nbase = blockIdx.x * 256;
  const int b = blockIdx.y;
  const float* Xb = X + (size_t)b * CH * HW;
  __shared__ unsigned short lds[(64 + 256) * 64];  // A 8KB + B 32KB
  char* Ab = (char*)lds;
  char* Bb = (char*)lds + 8192;
  const int tid = threadIdx.x, lane = tid & 63, w = tid >> 6;
  const int ar = tid >> 2, akq = tid & 3;          // A staging
  const int n4 = (tid & 63) * 4, c0l = tid >> 6;   // B staging (256 rows)
  const float* Arow = (ar < 32) ? (Wq + (size_t)ar * CH) : (Wk + (size_t)(ar - 32) * CH);
  f32x4 acc[4][4] = {};
  for (int s = 0; s < 8; ++s) {
    const int k0 = s * 32;
    float4 va[2], vb[8];
#pragma unroll
    for (int q = 0; q < 2; ++q)
      va[q] = *(const float4*)(Arow + k0 + akq * 8 + q * 4);
#pragma unroll
    for (int q = 0; q < 8; ++q)
      vb[q] = *(const float4*)(Xb + (size_t)(k0 + c0l + 4 * q) * HW + nbase + n4);
    __syncthreads();   // prev iter's frag reads done
#pragma unroll
    for (int q = 0; q < 2; ++q) {
      ushort4 h4, l4;
      cvt4(va[q], h4, l4);
      *(ushort4*)(Ab + lds_off(ar, 0, akq * 16 + q * 8)) = h4;
      *(ushort4*)(Ab + lds_off(ar, 1, akq * 16 + q * 8)) = l4;
    }
#pragma unroll
    for (int q = 0; q < 8; ++q) {
      int cc = c0l + 4 * q;
      float4 v = vb[q];
#pragma unroll
      for (int jj = 0; jj < 4; ++jj) {
        int j = (jj + tid) & 3;
        float e = (j == 0) ? v.x : (j == 1) ? v.y : (j == 2) ? v.z : v.w;
        unsigned short h, l;
        cvt2(e, h, l);
        int row = n4 + j;
        *(unsigned short*)(Bb + lds_off(row, 0, cc * 2)) = h;
        *(unsigned short*)(Bb + lds_off(row, 1, cc * 2)) = l;
      }
    }
    __syncthreads();
    bf16x8 bfr[2][4];
#pragma unroll
    for (int h = 0; h < 2; ++h)
#pragma unroll
      for (int n = 0; n < 4; ++n)
        bfr[h][n] = frag_ld(Bb, w * 64 + n * 16 + (lane & 15), h, lane);
#pragma unroll
    for (int m = 0; m < 4; ++m) {
      int arow2 = m * 16 + (lane & 15);
      bf16x8 a0 = frag_ld(Ab, arow2, 0, lane);
      bf16x8 a1 = frag_ld(Ab, arow2, 1, lane);
#pragma unroll
      for (int n = 0; n < 4; ++n)
        acc[m][n] = __builtin_amdgcn_mfma_f32_16x16x32_bf16(a0, bfr[0][n], acc[m][n], 0, 0, 0);
#pragma unroll
      for (int n = 0; n < 4; ++n)
        acc[m][n] = __builtin_amdgcn_mfma_f32_16x16x32_bf16(a0, bfr[1][n], acc[m][n], 0, 0, 0);
#pragma unroll
      for (int n = 0; n < 4; ++n)
        acc[m][n] = __builtin_amdgcn_mfma_f32_16x16x32_bf16(a1, bfr[0][n], acc[m][n], 0, 0, 0);
    }
  }
#pragma unroll
  for (int m = 0; m < 4; ++m)
#pragma unroll
    for (int n = 0; n < 4; ++n) {
      int row = m * 16 + ((lane >> 4) << 2);
      int col = nbase + w * 64 + n * 16 + (lane & 15);
#pragma unroll
      for (int r2 = 0; r2 < 4; ++r2) {
        int rr = row + r2;
        float v = acc[m][n][r2];
        if (rr < 32) qt[((size_t)b * HW + col) * 32 + rr] = v + bq[rr];
        else         kf[((size_t)b * 32 + (rr - 32)) * HW + col] = v + bk[rr - 32];
      }
    }
}

// --------------------------------------------------- PAM energy + softmax
// One block per ccb: gathers q (n-major) and k (kk-major) for its chunk,
// P[ccb][j][m] = softmax_m(q[j] . k[.][m]).
__global__ __launch_bounds__(256) void pam_es_k(const float* __restrict__ qt,
                                                const float* __restrict__ kf,
                                                float* __restrict__ Pbuf) {
  const int ccb = blockIdx.x;
  const int ck = ccb >> 4, b = ccb & 15;
  const int gi = ck / 5, gj = ck % 5;
  const int pbase = gi * 16 * IMW + gj * 16;
  float* Pc = Pbuf + (size_t)ccb * 65536;
  __shared__ float qs[256][32];
  __shared__ float S[32][256];
  const int tid = threadIdx.x;
  const float* qb = qt + (size_t)b * HW * 32;
#pragma unroll
  for (int qq = 0; qq < 8; ++qq) {
    int j = (tid >> 3) + 32 * qq;
    int nj = pbase + (j >> 4) * IMW + (j & 15);
    float4 v = *(const float4*)(qb + (size_t)nj * 32 + (tid & 7) * 4);
    *(float4*)&qs[j][(tid & 7) * 4] = v;
  }
  const int nt = pbase + (tid >> 4) * IMW + (tid & 15);
  const float* kb = kf + (size_t)b * 32 * HW;
  float kc[32];
#pragma unroll
  for (int kk = 0; kk < 32; ++kk) kc[kk] = kb[(size_t)kk * HW + nt];
  __syncthreads();
  const int w = tid >> 6, lane = tid & 63;
  for (int p = 0; p < 8; ++p) {
#pragma unroll 4
    for (int j2 = 0; j2 < 32; ++j2) {
      int row = p * 32 + j2;
      float s = 0.f;
#pragma unroll
      for (int k8 = 0; k8 < 8; ++k8) {
        float4 qv = *(const float4*)&qs[row][k8 * 4];
        s = fmaf(qv.x, kc[k8 * 4 + 0], s);
        s = fmaf(qv.y, kc[k8 * 4 + 1], s);
        s = fmaf(qv.z, kc[k8 * 4 + 2], s);
        s = fmaf(qv.w, kc[k8 * 4 + 3], s);
      }
      S[j2][tid] = s;
    }
    __syncthreads();
#pragma unroll
    for (int rr = 0; rr < 8; ++rr) {
      int jj = w * 8 + rr;
      float4 v = *(const float4*)&S[jj][lane << 2];
      float m = fmaxf(fmaxf(v.x, v.y), fmaxf(v.z, v.w));
      for (int o = 32; o; o >>= 1) m = fmaxf(m, __shfl_xor(m, o));
      float4 pv;
      pv.x = __expf(v.x - m); pv.y = __expf(v.y - m);
      pv.z = __expf(v.z - m); pv.w = __expf(v.w - m);
      float s = (pv.x + pv.y) + (pv.z + pv.w);
      for (int o = 32; o; o >>= 1) s += __shfl_xor(s, o);
      const float inv = 1.f / s;
      pv.x *= inv; pv.y *= inv; pv.z *= inv; pv.w *= inv;
      *(float4*)&Pc[(size_t)(p * 32 + jj) * 256 + (lane << 2)] = pv;
    }
    __syncthreads();
  }
}

// ---------------------------------------------------------------- PAM PV
// One 512-thr block per ccb: out[d][j] = g*sum_n V[d][n] P[j][n] + X[d][n(j)],
// written over P[ccb] after all reads complete. split-bf16, 256x256, K=256.
__global__ __launch_bounds__(512) void pam_pv_k(float* __restrict__ P,
                                                const float* __restrict__ V,
                                                const float* __restrict__ fS,
                                                const float* __restrict__ fT,
                                                const float* __restrict__ gsc, int t) {
  const int ccb = blockIdx.x;
  const int ck = ccb >> 4, b = ccb & 15;
  const int gi = ck / 5, gj = ck % 5;
  const float* Xb = (t ? fT : fS) + (size_t)b * CH * HW;
  const float* Vb = V + (size_t)b * CH * HW;
  float* Pc = P + (size_t)ccb * 65536;
  __shared__ unsigned short lds[2 * 256 * 64];
  char* Ab = (char*)lds;
  char* Bb = (char*)lds + 32768;
  const int tid = threadIdx.x, lane = tid & 63, w = tid >> 6;
  const int wr = w >> 2, wc = w & 3;
  const int r0 = tid >> 3, kq = tid & 7;
  const int pbase = gi * 16 * IMW + gj * 16;
  f32x4 acc[8][4] = {};
  for (int s = 0; s < 8; ++s) {
    int k0 = s * 32;
    int jj = k0 + kq * 4;
    int ngl = pbase + (jj >> 4) * IMW + (jj & 15);
#pragma unroll
    for (int q = 0; q < 4; ++q) {
      int rr = r0 + 64 * q;
      float4 va = *(const float4*)(Vb + (size_t)rr * HW + ngl);
      float4 vb = *(const float4*)(Pc + (size_t)rr * 256 + k0 + kq * 4);
      ushort4 h4, l4;
      cvt4(va, h4, l4);
      *(ushort4*)(Ab + lds_off(rr, 0, kq * 8)) = h4;
      *(ushort4*)(Ab + lds_off(rr, 1, kq * 8)) = l4;
      cvt4(vb, h4, l4);
      *(ushort4*)(Bb + lds_off(rr, 0, kq * 8)) = h4;
      *(ushort4*)(Bb + lds_off(rr, 1, kq * 8)) = l4;
    }
    __syncthreads();
    bf16x8 bfr[2][4];
#pragma unroll
    for (int h = 0; h < 2; ++h)
#pragma unroll
      for (int n = 0; n < 4; ++n)
        bfr[h][n] = frag_ld(Bb, wc * 64 + n * 16 + (lane & 15), h, lane);
#pragma unroll
    for (int m = 0; m < 8; ++m) {
      int arow = wr * 128 + m * 16 + (lane & 15);
      bf16x8 a0 = frag_ld(Ab, arow, 0, lane);
      bf16x8 a1 = frag_ld(Ab, arow, 1, lane);
#pragma unroll
      for (int n = 0; n < 4; ++n)
        acc[m][n] = __builtin_amdgcn_mfma_f32_16x16x32_bf16(a0, bfr[0][n], acc[m][n], 0, 0, 0);
#pragma unroll
      for (int n = 0; n < 4; ++n)
        acc[m][n] = __builtin_amdgcn_mfma_f32_16x16x32_bf16(a0, bfr[1][n], acc[m][n], 0, 0, 0);
#pragma unroll
      for (int n = 0; n < 4; ++n)
        acc[m][n] = __builtin_amdgcn_mfma_f32_16x16x32_bf16(a1, bfr[0][n], acc[m][n], 0, 0, 0);
    }
    __syncthreads();
  }
  const float g = gsc[0];
#pragma unroll
  for (int m = 0; m < 8; ++m)
#pragma unroll
    for (int n = 0; n < 4; ++n) {
      int row = wr * 128 + m * 16 + ((lane >> 4) << 2);
      int col = wc * 64 + n * 16 + (lane & 15);
      int ngl = pbase + (col >> 4) * IMW + (col & 15);
#pragma unroll
      for (int r2 = 0; r2 < 4; ++r2) {
        float v = g * acc[m][n][r2] + Xb[(size_t)(row + r2) * HW + ngl];
        Pc[(size_t)(row + r2) * 256 + col] = v;
      }
    }
}

// ------------------------------------------------------------- gram (MFMA)
// G[group][b1][b2] += Z[b1].Z[b2] via split-bf16 MFMA; A-frag == B-frag.
__global__ __launch_bounds__(256) void gram_mfma_k(const float* __restrict__ Z,
                                                   size_t gStride, size_t bStride,
                                                   double* __restrict__ G) {
  const int tid = threadIdx.x, lane = tid & 63, w = tid >> 6;
  const float* Zg = Z + (size_t)blockIdx.y * gStride;
  const float* p = Zg + (size_t)(lane & 15) * bStride +
                   (size_t)blockIdx.x * 4096 + w * 1024 + ((lane >> 4) << 3);
  f32x4 acc = {};
#pragma unroll 4
  for (int s = 0; s < 32; ++s) {
    float4 v0 = *(const float4*)(p + s * 32);
    float4 v1 = *(const float4*)(p + s * 32 + 4);
    bf16x8 hi, lo;
    cvt8(v0, v1, hi, lo);
    acc = __builtin_amdgcn_mfma_f32_16x16x32_bf16(hi, hi, acc, 0, 0, 0);
    acc = __builtin_amdgcn_mfma_f32_16x16x32_bf16(hi, lo, acc, 0, 0, 0);
    acc = __builtin_amdgcn_mfma_f32_16x16x32_bf16(lo, hi, acc, 0, 0, 0);
  }
  double* Gt = G + (size_t)blockIdx.y * 256;
  const int col = lane & 15, row0 = (lane >> 4) << 2;
#pragma unroll
  for (int i = 0; i < 4; ++i)
    atomicAdd(&Gt[(size_t)(row0 + i) * 16 + col], (double)acc[i]);
}

// -------------------------------------------------------------- CKA pairs
__global__ __launch_bounds__(256) void cka_pair_k(const double* __restrict__ G,
                                                  double* __restrict__ losses) {
  const int q = blockIdx.x;
  const double* KX = (q == 0) ? G : G + 512 + (size_t)(q - 1) * 256;
  const double* KY = (q == 0) ? G + 256 : G + 512 + 6400 + (size_t)(q - 1) * 256;
  __shared__ double red[256];
  __shared__ double srm[16], scm[16];
  __shared__ double stm;
  const int tid = threadIdx.x;
  const int r = tid >> 4, c = tid & 15;

  auto center = [&](double k) -> double {
    red[tid] = k;
    __syncthreads();
    for (int off = 8; off; off >>= 1) {
      if (c < off) red[tid] += red[tid + off];
      __syncthreads();
    }
    if (c == 0) srm[r] = red[tid] * (1.0 / 16.0);
    __syncthreads();
    red[c * 16 + r] = k;
    __syncthreads();
    for (int off = 8; off; off >>= 1) {
      if (r < off) red[c * 16 + r] += red[c * 16 + r + off];
      __syncthreads();
    }
    if (r == 0) scm[c] = red[c * 16] * (1.0 / 16.0);
    __syncthreads();
    if (tid == 0) {
      double s = 0.0;
      for (int i = 0; i < 16; ++i) s += srm[i];
      stm = s * (1.0 / 16.0);
    }
    __syncthreads();
    double v = k - srm[r] - scm[c] + stm;
    __syncthreads();
    return v;
  };
  auto reduce_sum = [&](double v) -> double {
    red[tid] = v;
    __syncthreads();
    for (int off = 128; off; off >>= 1) {
      if (tid < off) red[tid] += red[tid + off];
      __syncthreads();
    }
    double s = red[0];
    __syncthreads();
    return s;
  };
  double cx = center(KX[tid]);
  double cy = center(KY[tid]);
  double h = reduce_sum(cx * cy);
  double v1 = reduce_sum(cx * cx);
  double v2 = reduce_sum(cy * cy);
  if (tid == 0) losses[q] = -log(fabs(h / (sqrt(v1) * sqrt(v2))) + 1e-8);
}

__global__ void cka_combine_k(const double* __restrict__ losses,
                              float* __restrict__ out) {
  if (threadIdx.x == 0) {
    out[0] = (float)losses[0];
    double s = 0.0;
    for (int q = 1; q <= 25; ++q) s += losses[q];
    out[1] = (float)(s * (1.0 / 25.0));
  }
}

extern "C" void kernel_launch(void* const* d_in, const int* in_sizes, int n_in,
                              void* d_out, int out_size, void* d_ws, size_t ws_size,
                              hipStream_t stream) {
  (void)in_sizes; (void)n_in; (void)out_size; (void)ws_size;
  const float* fS = (const float*)d_in[0];
  const float* fT = (const float*)d_in[1];
  const float* Wq = (const float*)d_in[2];
  const float* bq = (const float*)d_in[3];
  const float* Wk = (const float*)d_in[4];
  const float* bk = (const float*)d_in[5];
  const float* Wv = (const float*)d_in[6];
  const float* bv = (const float*)d_in[7];
  const float* gcam = (const float*)d_in[8];
  const float* gpam = (const float*)d_in[9];
  float* out = (float*)d_out;

  float* buf0 = (float*)d_ws;              // 26214400 floats
  float* buf1 = buf0 + 26214400;           // 26214400 floats
  double* G = (double*)(buf1 + 26214400);  // 13312 doubles
  float* Pbuf = buf1;                      // 400*65536
  float* qt = buf0;                        // 16*6400*32
  float* kf = buf0 + 3276800;              // 16*32*6400
  double* losses = (double*)buf0;          // 26 doubles, dead region at CKA time

  hipMemsetAsync(G, 0, 13312 * sizeof(double), stream);

  // ---- CAM ----
  cam_energy_k<<<dim3(10, 16, 2), 512, 0, stream>>>(fS, fT, buf1);
  cam_softmax_k<<<dim3(256, 16, 2), 64, 0, stream>>>(buf1);
  for (int t = 0; t < 2; ++t) {
    ax_k<0><<<dim3(100, 16), 256, 0, stream>>>(buf1 + (size_t)t * BB * 65536, 65536,
                                               t ? fT : fS, buf0, nullptr, gcam);
    gram_mfma_k<<<dim3(400, 1), 256, 0, stream>>>(buf0, (size_t)0, (size_t)1638400,
                                                  G + t * 256);
  }
  // ---- PAM ----
  for (int t = 0; t < 2; ++t) {
    const float* X = t ? fT : fS;
    qk_k<<<dim3(25, 16), 256, 0, stream>>>(X, Wq, bq, Wk, bk, qt, kf);
    pam_es_k<<<dim3(400), 256, 0, stream>>>(qt, kf, Pbuf);
    ax_k<1><<<dim3(100, 16), 256, 0, stream>>>(Wv, 0, X, buf0, bv, nullptr);
    pam_pv_k<<<dim3(400), 512, 0, stream>>>(Pbuf, buf0, fS, fT, gpam, t);
    gram_mfma_k<<<dim3(16, 25), 256, 0, stream>>>(Pbuf, (size_t)1048576, (size_t)65536,
                                                  G + 512 + t * 6400);
  }
  cka_pair_k<<<dim3(26), 256, 0, stream>>>(G, losses);
  cka_combine_k<<<dim3(1), 64, 0, stream>>>(losses, out);
}

// Round 8
// 1105.455 us; speedup vs baseline: 2.6655x; 1.0152x over previous
//
#include <hip/hip_runtime.h>

// CriterionSA: CAM + grid-PAM + CKA loss.
// GEMMs in split-bf16 MFMA (hi/lo, 3 MFMAs: hh+hl+lh); cam_energy plain bf16
// (softmax saturated). Grams via MFMA split-bf16 (A-frag == B-frag for Z Z^T),
// fp32 acc -> fp64 atomics. CKA in fp64, 26 parallel blocks.
// R8: register-prefetch software pipeline in cam_energy_k / pam_pv_k / qk_k
// (load s+1 issued before MFMA of s) -- latency hiding, layouts unchanged.
// ws layout (floats): buf0[26214400] | buf1[26214400] | G[13312 doubles]
// required ws = 209,821,696 bytes (~200.1 MiB) -- same as rounds 1-7.

typedef short bf16x8 __attribute__((ext_vector_type(8)));
typedef float f32x4 __attribute__((ext_vector_type(4)));

constexpr int BB = 16;    // batch
constexpr int CH = 256;   // channels
constexpr int HW = 6400;  // 80*80
constexpr int IMW = 80;

__device__ __forceinline__ int lds_off(int row, int half, int k2) {
  return row * 128 + ((((half << 6)) | k2) ^ ((row & 7) << 4));
}

__device__ __forceinline__ bf16x8 frag_ld(const char* base, int row, int half, int lane) {
  int off = row * 128 + ((((half << 6)) | ((lane >> 4) << 4)) ^ ((lane & 7) << 4));
  return *(const bf16x8*)(base + off);
}

__device__ __forceinline__ void cvt2(float x, unsigned short& h, unsigned short& l) {
  unsigned u = __float_as_uint(x);
  h = (unsigned short)(u >> 16);                       // truncated hi
  float r = x - __uint_as_float(u & 0xffff0000u);
  l = (unsigned short)(__float_as_uint(r) >> 16);      // truncated residual
}

__device__ __forceinline__ void cvt4(float4 v, ushort4& h, ushort4& l) {
  cvt2(v.x, h.x, l.x); cvt2(v.y, h.y, l.y);
  cvt2(v.z, h.z, l.z); cvt2(v.w, h.w, l.w);
}

__device__ __forceinline__ void cvt8(float4 v0, float4 v1, bf16x8& hi, bf16x8& lo) {
  unsigned short h, l;
  cvt2(v0.x, h, l); hi[0] = (short)h; lo[0] = (short)l;
  cvt2(v0.y, h, l); hi[1] = (short)h; lo[1] = (short)l;
  cvt2(v0.z, h, l); hi[2] = (short)h; lo[2] = (short)l;
  cvt2(v0.w, h, l); hi[3] = (short)h; lo[3] = (short)l;
  cvt2(v1.x, h, l); hi[4] = (short)h; lo[4] = (short)l;
  cvt2(v1.y, h, l); hi[5] = (short)h; lo[5] = (short)l;
  cvt2(v1.z, h, l); hi[6] = (short)h; lo[6] = (short)l;
  cvt2(v1.w, h, l); hi[7] = (short)h; lo[7] = (short)l;
}

__device__ __forceinline__ unsigned short bf_rnd(float x) {
  unsigned u = __float_as_uint(x);
  return (unsigned short)((u + 0x8000u) >> 16);
}

// ---------------------------------------------------------------- CAM energy
// Partial E[kc][t][b] = X(:,kslice) X(:,kslice)^T, kc=0..9 (K=640 each).
// One 512-thread block computes the FULL 256x256 tile; one LDS panel is both
// MFMA operands. Register-prefetch pipeline: loads for it+1 issued before
// the MFMA phase of it.
__global__ __launch_bounds__(512) void cam_energy_k(const float* __restrict__ fS,
                                                    const float* __restrict__ fT,
                                                    float* __restrict__ part) {
  const int kc = blockIdx.x, b = blockIdx.y, t = blockIdx.z;
  const float* X = (t ? fT : fS) + (size_t)b * CH * HW;
  __shared__ unsigned short lds[256 * 64];  // 32 KB
  char* Ab = (char*)lds;
  const int tid = threadIdx.x, lane = tid & 63, w = tid >> 6;
  const int wr = w >> 2, wc = w & 3;
  const int r0 = tid >> 1, half = tid & 1;
  const float* Xr = X + (size_t)r0 * HW + kc * 640 + half * 32;
  f32x4 acc[8][4] = {};
  float4 v[8];
#pragma unroll
  for (int q = 0; q < 8; ++q) v[q] = *(const float4*)(Xr + q * 4);
  for (int it = 0; it < 10; ++it) {
    __syncthreads();   // prev iter's frag reads done before overwrite
#pragma unroll
    for (int q = 0; q < 8; ++q) {
      ushort4 u;
      u.x = bf_rnd(v[q].x); u.y = bf_rnd(v[q].y);
      u.z = bf_rnd(v[q].z); u.w = bf_rnd(v[q].w);
      *(ushort4*)(Ab + lds_off(r0, half, q * 8)) = u;
    }
    __syncthreads();
    float4 nv[8];
    if (it < 9) {
      const float* Xn = Xr + (it + 1) * 64;
#pragma unroll
      for (int q = 0; q < 8; ++q) nv[q] = *(const float4*)(Xn + q * 4);
    }
    bf16x8 bfr[2][4];
#pragma unroll
    for (int h = 0; h < 2; ++h)
#pragma unroll
      for (int n = 0; n < 4; ++n)
        bfr[h][n] = frag_ld(Ab, wc * 64 + n * 16 + (lane & 15), h, lane);
#pragma unroll
    for (int m = 0; m < 8; ++m) {
      int arow = wr * 128 + m * 16 + (lane & 15);
      bf16x8 a0 = frag_ld(Ab, arow, 0, lane);
      bf16x8 a1 = frag_ld(Ab, arow, 1, lane);
#pragma unroll
      for (int n = 0; n < 4; ++n)
        acc[m][n] = __builtin_amdgcn_mfma_f32_16x16x32_bf16(a0, bfr[0][n], acc[m][n], 0, 0, 0);
#pragma unroll
      for (int n = 0; n < 4; ++n)
        acc[m][n] = __builtin_amdgcn_mfma_f32_16x16x32_bf16(a1, bfr[1][n], acc[m][n], 0, 0, 0);
    }
#pragma unroll
    for (int q = 0; q < 8; ++q) v[q] = nv[q];
  }
  float* Eb = part + (((size_t)kc * 2 + t) * BB + b) * 65536;
#pragma unroll
  for (int m = 0; m < 8; ++m)
#pragma unroll
    for (int n = 0; n < 4; ++n) {
      int row = wr * 128 + m * 16 + ((lane >> 4) << 2);
      int col = wc * 64 + n * 16 + (lane & 15);
#pragma unroll
      for (int r2 = 0; r2 < 4; ++r2)
        Eb[(size_t)(row + r2) * 256 + col] = acc[m][n][r2];
    }
}

// ------------------------------------------------------------- CAM softmax
// attn = exp(rowmin - sum_p partE[p]) / rowsum, written into partial 0.
__global__ __launch_bounds__(64) void cam_softmax_k(float* __restrict__ part) {
  const int c = blockIdx.x, b = blockIdx.y, t = blockIdx.z;
  const size_t base = (((size_t)t * BB + b) * CH + c) * CH;
  const int lane = threadIdx.x;
  float4 x = make_float4(0.f, 0.f, 0.f, 0.f);
#pragma unroll
  for (int p = 0; p < 10; ++p) {
    float4 y = ((const float4*)(part + (size_t)p * 2097152 + base))[lane];
    x.x += y.x; x.y += y.y; x.z += y.z; x.w += y.w;
  }
  float mn = fminf(fminf(x.x, x.y), fminf(x.z, x.w));
  for (int o = 32; o; o >>= 1) mn = fminf(mn, __shfl_xor(mn, o));
  float4 p4;
  p4.x = __expf(mn - x.x); p4.y = __expf(mn - x.y);
  p4.z = __expf(mn - x.z); p4.w = __expf(mn - x.w);
  float s = (p4.x + p4.y) + (p4.z + p4.w);
  for (int o = 32; o; o >>= 1) s += __shfl_xor(s, o);
  const float inv = 1.0f / s;
  p4.x *= inv; p4.y *= inv; p4.z *= inv; p4.w *= inv;
  ((float4*)(part + base))[lane] = p4;
}

// ----------------------------------------------------- A(256x256) @ X GEMM
// MODE 0 (cam_out): OUT[c][n] = g*sum_d A[c][d] X[d][n] + X[c][n]
// MODE 1 (pam_V):   OUT[d][n] = sum_c Wv[d][c] X[c][n] + bv[d]
// split-bf16, 128x128 tile, K=256, B staged transposed. (Already pipelined.)
template <int MODE>
__global__ __launch_bounds__(256) void ax_k(const float* __restrict__ Abase, int Astride,
                                            const float* __restrict__ X,
                                            float* __restrict__ OUT,
                                            const float* __restrict__ bvec,
                                            const float* __restrict__ gsc) {
  const int mt = blockIdx.x / 50, nt = blockIdx.x % 50;
  const int b = blockIdx.y;
  const float* A = Abase + (size_t)b * Astride;
  const float* Xb = X + (size_t)b * CH * HW;
  float* OUTb = OUT + (size_t)b * CH * HW;
  const int nbase = nt * 128;
  __shared__ unsigned short lds[2 * 128 * 64];
  char* Ab = (char*)lds;
  char* Bb = (char*)lds + 16384;
  const int tid = threadIdx.x, lane = tid & 63, w = tid >> 6;
  const int wr = w >> 1, wc = w & 1;
  const int r0 = tid >> 3, kq = tid & 7;      // A staging
  const int n4 = (tid & 31) * 4, c0l = tid >> 5;  // B staging
  f32x4 acc[4][4] = {};
  float4 ra[4], rb[4];
#pragma unroll
  for (int q = 0; q < 4; ++q) {
    ra[q] = *(const float4*)(A + (size_t)(mt * 128 + r0 + 32 * q) * 256 + kq * 4);
    rb[q] = *(const float4*)(Xb + (size_t)(c0l + 8 * q) * HW + nbase + n4);
  }
  for (int s = 0; s < 8; ++s) {
#pragma unroll
    for (int q = 0; q < 4; ++q) {
      int rr = r0 + 32 * q;
      ushort4 h4, l4;
      cvt4(ra[q], h4, l4);
      *(ushort4*)(Ab + lds_off(rr, 0, kq * 8)) = h4;
      *(ushort4*)(Ab + lds_off(rr, 1, kq * 8)) = l4;
    }
#pragma unroll
    for (int q = 0; q < 4; ++q) {
      int cc = c0l + 8 * q;
      float4 v = rb[q];
#pragma unroll
      for (int jj = 0; jj < 4; ++jj) {
        int j = (jj + tid) & 3;   // rotate -> full (row&7) spread per inst
        float e = (j == 0) ? v.x : (j == 1) ? v.y : (j == 2) ? v.z : v.w;
        unsigned short h, l;
        cvt2(e, h, l);
        int row = n4 + j;
        *(unsigned short*)(Bb + lds_off(row, 0, cc * 2)) = h;
        *(unsigned short*)(Bb + lds_off(row, 1, cc * 2)) = l;
      }
    }
    __syncthreads();
    if (s < 7) {
      int k0 = (s + 1) * 32;
#pragma unroll
      for (int q = 0; q < 4; ++q) {
        ra[q] = *(const float4*)(A + (size_t)(mt * 128 + r0 + 32 * q) * 256 + k0 + kq * 4);
        rb[q] = *(const float4*)(Xb + (size_t)(k0 + c0l + 8 * q) * HW + nbase + n4);
      }
    }
    bf16x8 bfr[2][4];
#pragma unroll
    for (int h = 0; h < 2; ++h)
#pragma unroll
      for (int n = 0; n < 4; ++n)
        bfr[h][n] = frag_ld(Bb, wc * 64 + n * 16 + (lane & 15), h, lane);
#pragma unroll
    for (int m = 0; m < 4; ++m) {
      int arow = wr * 64 + m * 16 + (lane & 15);
      bf16x8 a0 = frag_ld(Ab, arow, 0, lane);
      bf16x8 a1 = frag_ld(Ab, arow, 1, lane);
#pragma unroll
      for (int n = 0; n < 4; ++n)
        acc[m][n] = __builtin_amdgcn_mfma_f32_16x16x32_bf16(a0, bfr[0][n], acc[m][n], 0, 0, 0);
#pragma unroll
      for (int n = 0; n < 4; ++n)
        acc[m][n] = __builtin_amdgcn_mfma_f32_16x16x32_bf16(a0, bfr[1][n], acc[m][n], 0, 0, 0);
#pragma unroll
      for (int n = 0; n < 4; ++n)
        acc[m][n] = __builtin_amdgcn_mfma_f32_16x16x32_bf16(a1, bfr[0][n], acc[m][n], 0, 0, 0);
    }
    __syncthreads();
  }
  float g = 0.f;
  if (MODE == 0) g = gsc[0];
#pragma unroll
  for (int m = 0; m < 4; ++m)
#pragma unroll
    for (int n = 0; n < 4; ++n) {
      int row = mt * 128 + wr * 64 + m * 16 + ((lane >> 4) << 2);
      int col = nbase + wc * 64 + n * 16 + (lane & 15);
#pragma unroll
      for (int r2 = 0; r2 < 4; ++r2) {
        size_t o = (size_t)(row + r2) * HW + col;
        float v = acc[m][n][r2];
        if (MODE == 0) OUTb[o] = g * v + Xb[o];
        else           OUTb[o] = v + bvec[row + r2];
      }
    }
}

// ------------------------------------------------------------ PAM q/k GEMM
// Full-image 1x1 conv: rows 0..31 = Wq, 32..63 = Wk; N = 6400, K = 256.
// Outputs: qt[b][n][32] (n-major, +bq), kf[b][32][n] (+bk). split-bf16.
// Register-prefetch pipeline (loads for s+1 before MFMA of s).
__global__ __launch_bounds__(256) void qk_k(const float* __restrict__ X,
                                            const float* __restrict__ Wq,
                                            const float* __restrict__ bq,
                                            const float* __restrict__ Wk,
                                            const float* __restrict__ bk,
                                            float* __restrict__ qt,
                                            float* __restrict__ kf) {
  const int nbase = blockIdx.x * 256;
  const int b = blockIdx.y;
  const float* Xb = X + (size_t)b * CH * HW;
  __shared__ unsigned short lds[(64 + 256) * 64];  // A 8KB + B 32KB
  char* Ab = (char*)lds;
  char* Bb = (char*)lds + 8192;
  const int tid = threadIdx.x, lane = tid & 63, w = tid >> 6;
  const int ar = tid >> 2, akq = tid & 3;          // A staging
  const int n4 = (tid & 63) * 4, c0l = tid >> 6;   // B staging (256 rows)
  const float* Arow = (ar < 32) ? (Wq + (size_t)ar * CH) : (Wk + (size_t)(ar - 32) * CH);
  f32x4 acc[4][4] = {};
  float4 va[2], vb[8];
#pragma unroll
  for (int q = 0; q < 2; ++q)
    va[q] = *(const float4*)(Arow + akq * 8 + q * 4);
#pragma unroll
  for (int q = 0; q < 8; ++q)
    vb[q] = *(const float4*)(Xb + (size_t)(c0l + 4 * q) * HW + nbase + n4);
  for (int s = 0; s < 8; ++s) {
    __syncthreads();   // prev iter's frag reads done
#pragma unroll
    for (int q = 0; q < 2; ++q) {
      ushort4 h4, l4;
      cvt4(va[q], h4, l4);
      *(ushort4*)(Ab + lds_off(ar, 0, akq * 16 + q * 8)) = h4;
      *(ushort4*)(Ab + lds_off(ar, 1, akq * 16 + q * 8)) = l4;
    }
#pragma unroll
    for (int q = 0; q < 8; ++q) {
      int cc = c0l + 4 * q;
      float4 v = vb[q];
#pragma unroll
      for (int jj = 0; jj < 4; ++jj) {
        int j = (jj + tid) & 3;
        float e = (j == 0) ? v.x : (j == 1) ? v.y : (j == 2) ? v.z : v.w;
        unsigned short h, l;
        cvt2(e, h, l);
        int row = n4 + j;
        *(unsigned short*)(Bb + lds_off(row, 0, cc * 2)) = h;
        *(unsigned short*)(Bb + lds_off(row, 1, cc * 2)) = l;
      }
    }
    __syncthreads();
    float4 na[2], nb[8];
    if (s < 7) {
      const int k0 = (s + 1) * 32;
#pragma unroll
      for (int q = 0; q < 2; ++q)
        na[q] = *(const float4*)(Arow + k0 + akq * 8 + q * 4);
#pragma unroll
      for (int q = 0; q < 8; ++q)
        nb[q] = *(const float4*)(Xb + (size_t)(k0 + c0l + 4 * q) * HW + nbase + n4);
    }
    bf16x8 bfr[2][4];
#pragma unroll
    for (int h = 0; h < 2; ++h)
#pragma unroll
      for (int n = 0; n < 4; ++n)
        bfr[h][n] = frag_ld(Bb, w * 64 + n * 16 + (lane & 15), h, lane);
#pragma unroll
    for (int m = 0; m < 4; ++m) {
      int arow2 = m * 16 + (lane & 15);
      bf16x8 a0 = frag_ld(Ab, arow2, 0, lane);
      bf16x8 a1 = frag_ld(Ab, arow2, 1, lane);
#pragma unroll
      for (int n = 0; n < 4; ++n)
        acc[m][n] = __builtin_amdgcn_mfma_f32_16x16x32_bf16(a0, bfr[0][n], acc[m][n], 0, 0, 0);
#pragma unroll
      for (int n = 0; n < 4; ++n)
        acc[m][n] = __builtin_amdgcn_mfma_f32_16x16x32_bf16(a0, bfr[1][n], acc[m][n], 0, 0, 0);
#pragma unroll
      for (int n = 0; n < 4; ++n)
        acc[m][n] = __builtin_amdgcn_mfma_f32_16x16x32_bf16(a1, bfr[0][n], acc[m][n], 0, 0, 0);
    }
#pragma unroll
    for (int q = 0; q < 2; ++q) va[q] = na[q];
#pragma unroll
    for (int q = 0; q < 8; ++q) vb[q] = nb[q];
  }
#pragma unroll
  for (int m = 0; m < 4; ++m)
#pragma unroll
    for (int n = 0; n < 4; ++n) {
      int row = m * 16 + ((lane >> 4) << 2);
      int col = nbase + w * 64 + n * 16 + (lane & 15);
#pragma unroll
      for (int r2 = 0; r2 < 4; ++r2) {
        int rr = row + r2;
        float v = acc[m][n][r2];
        if (rr < 32) qt[((size_t)b * HW + col) * 32 + rr] = v + bq[rr];
        else         kf[((size_t)b * 32 + (rr - 32)) * HW + col] = v + bk[rr - 32];
      }
    }
}

// --------------------------------------------------- PAM energy + softmax
__global__ __launch_bounds__(256) void pam_es_k(const float* __restrict__ qt,
                                                const float* __restrict__ kf,
                                                float* __restrict__ Pbuf) {
  const int ccb = blockIdx.x;
  const int ck = ccb >> 4, b = ccb & 15;
  const int gi = ck / 5, gj = ck % 5;
  const int pbase = gi * 16 * IMW + gj * 16;
  float* Pc = Pbuf + (size_t)ccb * 65536;
  __shared__ float qs[256][32];
  __shared__ float S[32][256];
  const int tid = threadIdx.x;
  const float* qb = qt + (size_t)b * HW * 32;
#pragma unroll
  for (int qq = 0; qq < 8; ++qq) {
    int j = (tid >> 3) + 32 * qq;
    int nj = pbase + (j >> 4) * IMW + (j & 15);
    float4 v = *(const float4*)(qb + (size_t)nj * 32 + (tid & 7) * 4);
    *(float4*)&qs[j][(tid & 7) * 4] = v;
  }
  const int nt = pbase + (tid >> 4) * IMW + (tid & 15);
  const float* kb = kf + (size_t)b * 32 * HW;
  float kc[32];
#pragma unroll
  for (int kk = 0; kk < 32; ++kk) kc[kk] = kb[(size_t)kk * HW + nt];
  __syncthreads();
  const int w = tid >> 6, lane = tid & 63;
  for (int p = 0; p < 8; ++p) {
#pragma unroll 4
    for (int j2 = 0; j2 < 32; ++j2) {
      int row = p * 32 + j2;
      float s = 0.f;
#pragma unroll
      for (int k8 = 0; k8 < 8; ++k8) {
        float4 qv = *(const float4*)&qs[row][k8 * 4];
        s = fmaf(qv.x, kc[k8 * 4 + 0], s);
        s = fmaf(qv.y, kc[k8 * 4 + 1], s);
        s = fmaf(qv.z, kc[k8 * 4 + 2], s);
        s = fmaf(qv.w, kc[k8 * 4 + 3], s);
      }
      S[j2][tid] = s;
    }
    __syncthreads();
#pragma unroll
    for (int rr = 0; rr < 8; ++rr) {
      int jj = w * 8 + rr;
      float4 v = *(const float4*)&S[jj][lane << 2];
      float m = fmaxf(fmaxf(v.x, v.y), fmaxf(v.z, v.w));
      for (int o = 32; o; o >>= 1) m = fmaxf(m, __shfl_xor(m, o));
      float4 pv;
      pv.x = __expf(v.x - m); pv.y = __expf(v.y - m);
      pv.z = __expf(v.z - m); pv.w = __expf(v.w - m);
      float s = (pv.x + pv.y) + (pv.z + pv.w);
      for (int o = 32; o; o >>= 1) s += __shfl_xor(s, o);
      const float inv = 1.f / s;
      pv.x *= inv; pv.y *= inv; pv.z *= inv; pv.w *= inv;
      *(float4*)&Pc[(size_t)(p * 32 + jj) * 256 + (lane << 2)] = pv;
    }
    __syncthreads();
  }
}

// ---------------------------------------------------------------- PAM PV
// One 512-thr block per ccb: out[d][j] = g*sum_n V[d][n] P[j][n] + X[d][n(j)],
// written over P[ccb] after all reads complete. Register-prefetch pipeline.
__global__ __launch_bounds__(512) void pam_pv_k(float* __restrict__ P,
                                                const float* __restrict__ V,
                                                const float* __restrict__ fS,
                                                const float* __restrict__ fT,
                                                const float* __restrict__ gsc, int t) {
  const int ccb = blockIdx.x;
  const int ck = ccb >> 4, b = ccb & 15;
  const int gi = ck / 5, gj = ck % 5;
  const float* Xb = (t ? fT : fS) + (size_t)b * CH * HW;
  const float* Vb = V + (size_t)b * CH * HW;
  float* Pc = P + (size_t)ccb * 65536;
  __shared__ unsigned short lds[2 * 256 * 64];
  char* Ab = (char*)lds;
  char* Bb = (char*)lds + 32768;
  const int tid = threadIdx.x, lane = tid & 63, w = tid >> 6;
  const int wr = w >> 2, wc = w & 3;
  const int r0 = tid >> 3, kq = tid & 7;
  const int pbase = gi * 16 * IMW + gj * 16;
  f32x4 acc[8][4] = {};
  float4 va[4], vb[4];
  {
    int jj = kq * 4;
    int ngl = pbase + (jj >> 4) * IMW + (jj & 15);
#pragma unroll
    for (int q = 0; q < 4; ++q) {
      int rr = r0 + 64 * q;
      va[q] = *(const float4*)(Vb + (size_t)rr * HW + ngl);
      vb[q] = *(const float4*)(Pc + (size_t)rr * 256 + kq * 4);
    }
  }
  for (int s = 0; s < 8; ++s) {
    __syncthreads();   // prev iter's frag reads done
#pragma unroll
    for (int q = 0; q < 4; ++q) {
      int rr = r0 + 64 * q;
      ushort4 h4, l4;
      cvt4(va[q], h4, l4);
      *(ushort4*)(Ab + lds_off(rr, 0, kq * 8)) = h4;
      *(ushort4*)(Ab + lds_off(rr, 1, kq * 8)) = l4;
      cvt4(vb[q], h4, l4);
      *(ushort4*)(Bb + lds_off(rr, 0, kq * 8)) = h4;
      *(ushort4*)(Bb + lds_off(rr, 1, kq * 8)) = l4;
    }
    __syncthreads();
    float4 na[4], nb[4];
    if (s < 7) {
      int k0 = (s + 1) * 32;
      int jj = k0 + kq * 4;
      int ngl = pbase + (jj >> 4) * IMW + (jj & 15);
#pragma unroll
      for (int q = 0; q < 4; ++q) {
        int rr = r0 + 64 * q;
        na[q] = *(const float4*)(Vb + (size_t)rr * HW + ngl);
        nb[q] = *(const float4*)(Pc + (size_t)rr * 256 + k0 + kq * 4);
      }
    }
    bf16x8 bfr[2][4];
#pragma unroll
    for (int h = 0; h < 2; ++h)
#pragma unroll
      for (int n = 0; n < 4; ++n)
        bfr[h][n] = frag_ld(Bb, wc * 64 + n * 16 + (lane & 15), h, lane);
#pragma unroll
    for (int m = 0; m < 8; ++m) {
      int arow = wr * 128 + m * 16 + (lane & 15);
      bf16x8 a0 = frag_ld(Ab, arow, 0, lane);
      bf16x8 a1 = frag_ld(Ab, arow, 1, lane);
#pragma unroll
      for (int n = 0; n < 4; ++n)
        acc[m][n] = __builtin_amdgcn_mfma_f32_16x16x32_bf16(a0, bfr[0][n], acc[m][n], 0, 0, 0);
#pragma unroll
      for (int n = 0; n < 4; ++n)
        acc[m][n] = __builtin_amdgcn_mfma_f32_16x16x32_bf16(a0, bfr[1][n], acc[m][n], 0, 0, 0);
#pragma unroll
      for (int n = 0; n < 4; ++n)
        acc[m][n] = __builtin_amdgcn_mfma_f32_16x16x32_bf16(a1, bfr[0][n], acc[m][n], 0, 0, 0);
    }
#pragma unroll
    for (int q = 0; q < 4; ++q) { va[q] = na[q]; vb[q] = nb[q]; }
  }
  const float g = gsc[0];
#pragma unroll
  for (int m = 0; m < 8; ++m)
#pragma unroll
    for (int n = 0; n < 4; ++n) {
      int row = wr * 128 + m * 16 + ((lane >> 4) << 2);
      int col = wc * 64 + n * 16 + (lane & 15);
      int ngl = pbase + (col >> 4) * IMW + (col & 15);
#pragma unroll
      for (int r2 = 0; r2 < 4; ++r2) {
        float v = g * acc[m][n][r2] + Xb[(size_t)(row + r2) * HW + ngl];
        Pc[(size_t)(row + r2) * 256 + col] = v;
      }
    }
}

// ------------------------------------------------------------- gram (MFMA)
__global__ __launch_bounds__(256) void gram_mfma_k(const float* __restrict__ Z,
                                                   size_t gStride, size_t bStride,
                                                   double* __restrict__ G) {
  const int tid = threadIdx.x, lane = tid & 63, w = tid >> 6;
  const float* Zg = Z + (size_t)blockIdx.y * gStride;
  const float* p = Zg + (size_t)(lane & 15) * bStride +
                   (size_t)blockIdx.x * 4096 + w * 1024 + ((lane >> 4) << 3);
  f32x4 acc = {};
#pragma unroll 4
  for (int s = 0; s < 32; ++s) {
    float4 v0 = *(const float4*)(p + s * 32);
    float4 v1 = *(const float4*)(p + s * 32 + 4);
    bf16x8 hi, lo;
    cvt8(v0, v1, hi, lo);
    acc = __builtin_amdgcn_mfma_f32_16x16x32_bf16(hi, hi, acc, 0, 0, 0);
    acc = __builtin_amdgcn_mfma_f32_16x16x32_bf16(hi, lo, acc, 0, 0, 0);
    acc = __builtin_amdgcn_mfma_f32_16x16x32_bf16(lo, hi, acc, 0, 0, 0);
  }
  double* Gt = G + (size_t)blockIdx.y * 256;
  const int col = lane & 15, row0 = (lane >> 4) << 2;
#pragma unroll
  for (int i = 0; i < 4; ++i)
    atomicAdd(&Gt[(size_t)(row0 + i) * 16 + col], (double)acc[i]);
}

// -------------------------------------------------------------- CKA pairs
__global__ __launch_bounds__(256) void cka_pair_k(const double* __restrict__ G,
                                                  double* __restrict__ losses) {
  const int q = blockIdx.x;
  const double* KX = (q == 0) ? G : G + 512 + (size_t)(q - 1) * 256;
  const double* KY = (q == 0) ? G + 256 : G + 512 + 6400 + (size_t)(q - 1) * 256;
  __shared__ double red[256];
  __shared__ double srm[16], scm[16];
  __shared__ double stm;
  const int tid = threadIdx.x;
  const int r = tid >> 4, c = tid & 15;

  auto center = [&](double k) -> double {
    red[tid] = k;
    __syncthreads();
    for (int off = 8; off; off >>= 1) {
      if (c < off) red[tid] += red[tid + off];
      __syncthreads();
    }
    if (c == 0) srm[r] = red[tid] * (1.0 / 16.0);
    __syncthreads();
    red[c * 16 + r] = k;
    __syncthreads();
    for (int off = 8; off; off >>= 1) {
      if (r < off) red[c * 16 + r] += red[c * 16 + r + off];
      __syncthreads();
    }
    if (r == 0) scm[c] = red[c * 16] * (1.0 / 16.0);
    __syncthreads();
    if (tid == 0) {
      double s = 0.0;
      for (int i = 0; i < 16; ++i) s += srm[i];
      stm = s * (1.0 / 16.0);
    }
    __syncthreads();
    double v = k - srm[r] - scm[c] + stm;
    __syncthreads();
    return v;
  };
  auto reduce_sum = [&](double v) -> double {
    red[tid] = v;
    __syncthreads();
    for (int off = 128; off; off >>= 1) {
      if (tid < off) red[tid] += red[tid + off];
      __syncthreads();
    }
    double s = red[0];
    __syncthreads();
    return s;
  };
  double cx = center(KX[tid]);
  double cy = center(KY[tid]);
  double h = reduce_sum(cx * cy);
  double v1 = reduce_sum(cx * cx);
  double v2 = reduce_sum(cy * cy);
  if (tid == 0) losses[q] = -log(fabs(h / (sqrt(v1) * sqrt(v2))) + 1e-8);
}

__global__ void cka_combine_k(const double* __restrict__ losses,
                              float* __restrict__ out) {
  if (threadIdx.x == 0) {
    out[0] = (float)losses[0];
    double s = 0.0;
    for (int q = 1; q <= 25; ++q) s += losses[q];
    out[1] = (float)(s * (1.0 / 25.0));
  }
}

extern "C" void kernel_launch(void* const* d_in, const int* in_sizes, int n_in,
                              void* d_out, int out_size, void* d_ws, size_t ws_size,
                              hipStream_t stream) {
  (void)in_sizes; (void)n_in; (void)out_size; (void)ws_size;
  const float* fS = (const float*)d_in[0];
  const float* fT = (const float*)d_in[1];
  const float* Wq = (const float*)d_in[2];
  const float* bq = (const float*)d_in[3];
  const float* Wk = (const float*)d_in[4];
  const float* bk = (const float*)d_in[5];
  const float* Wv = (const float*)d_in[6];
  const float* bv = (const float*)d_in[7];
  const float* gcam = (const float*)d_in[8];
  const float* gpam = (const float*)d_in[9];
  float* out = (float*)d_out;

  float* buf0 = (float*)d_ws;              // 26214400 floats
  float* buf1 = buf0 + 26214400;           // 26214400 floats
  double* G = (double*)(buf1 + 26214400);  // 13312 doubles
  float* Pbuf = buf1;                      // 400*65536
  float* qt = buf0;                        // 16*6400*32
  float* kf = buf0 + 3276800;              // 16*32*6400
  double* losses = (double*)buf0;          // 26 doubles, dead region at CKA time

  hipMemsetAsync(G, 0, 13312 * sizeof(double), stream);

  // ---- CAM ----
  cam_energy_k<<<dim3(10, 16, 2), 512, 0, stream>>>(fS, fT, buf1);
  cam_softmax_k<<<dim3(256, 16, 2), 64, 0, stream>>>(buf1);
  for (int t = 0; t < 2; ++t) {
    ax_k<0><<<dim3(100, 16), 256, 0, stream>>>(buf1 + (size_t)t * BB * 65536, 65536,
                                               t ? fT : fS, buf0, nullptr, gcam);
    gram_mfma_k<<<dim3(400, 1), 256, 0, stream>>>(buf0, (size_t)0, (size_t)1638400,
                                                  G + t * 256);
  }
  // ---- PAM ----
  for (int t = 0; t < 2; ++t) {
    const float* X = t ? fT : fS;
    qk_k<<<dim3(25, 16), 256, 0, stream>>>(X, Wq, bq, Wk, bk, qt, kf);
    pam_es_k<<<dim3(400), 256, 0, stream>>>(qt, kf, Pbuf);
    ax_k<1><<<dim3(100, 16), 256, 0, stream>>>(Wv, 0, X, buf0, bv, nullptr);
    pam_pv_k<<<dim3(400), 512, 0, stream>>>(Pbuf, buf0, fS, fT, gpam, t);
    gram_mfma_k<<<dim3(16, 25), 256, 0, stream>>>(Pbuf, (size_t)1048576, (size_t)65536,
                                                  G + 512 + t * 6400);
  }
  cka_pair_k<<<dim3(26), 256, 0, stream>>>(G, losses);
  cka_combine_k<<<dim3(1), 64, 0, stream>>>(losses, out);
}

// Round 11
// 1071.969 us; speedup vs baseline: 2.7488x; 1.0312x over previous
//
#include <hip/hip_runtime.h>

// CriterionSA: CAM + grid-PAM + CKA loss.
// GEMMs in split-bf16 MFMA (hi/lo, 3 MFMAs: hh+hl+lh); cam_energy plain bf16
// (softmax saturated). Grams via MFMA split-bf16; fp32 acc -> fp64 atomics.
// CKA fp64, 26 parallel blocks.
// R9: (1) ax_k retiled to M=256 x N=128 (X read once, was twice);
//     (2) cam_energy nparts=8 (grid=256, 1 round), K=800 w/ zero-pad tail,
//         double-buffered LDS (one barrier/iter).
// ws layout (floats): buf0[26214400] | buf1[26214400] | G[13312 doubles]
// required ws = 209,821,696 bytes (~200.1 MiB) -- same as rounds 1-8.

typedef short bf16x8 __attribute__((ext_vector_type(8)));
typedef float f32x4 __attribute__((ext_vector_type(4)));

constexpr int BB = 16;    // batch
constexpr int CH = 256;   // channels
constexpr int HW = 6400;  // 80*80
constexpr int IMW = 80;

__device__ __forceinline__ int lds_off(int row, int half, int k2) {
  return row * 128 + ((((half << 6)) | k2) ^ ((row & 7) << 4));
}

__device__ __forceinline__ bf16x8 frag_ld(const char* base, int row, int half, int lane) {
  int off = row * 128 + ((((half << 6)) | ((lane >> 4) << 4)) ^ ((lane & 7) << 4));
  return *(const bf16x8*)(base + off);
}

__device__ __forceinline__ void cvt2(float x, unsigned short& h, unsigned short& l) {
  unsigned u = __float_as_uint(x);
  h = (unsigned short)(u >> 16);                       // truncated hi
  float r = x - __uint_as_float(u & 0xffff0000u);
  l = (unsigned short)(__float_as_uint(r) >> 16);      // truncated residual
}

__device__ __forceinline__ void cvt4(float4 v, ushort4& h, ushort4& l) {
  cvt2(v.x, h.x, l.x); cvt2(v.y, h.y, l.y);
  cvt2(v.z, h.z, l.z); cvt2(v.w, h.w, l.w);
}

__device__ __forceinline__ void cvt8(float4 v0, float4 v1, bf16x8& hi, bf16x8& lo) {
  unsigned short h, l;
  cvt2(v0.x, h, l); hi[0] = (short)h; lo[0] = (short)l;
  cvt2(v0.y, h, l); hi[1] = (short)h; lo[1] = (short)l;
  cvt2(v0.z, h, l); hi[2] = (short)h; lo[2] = (short)l;
  cvt2(v0.w, h, l); hi[3] = (short)h; lo[3] = (short)l;
  cvt2(v1.x, h, l); hi[4] = (short)h; lo[4] = (short)l;
  cvt2(v1.y, h, l); hi[5] = (short)h; lo[5] = (short)l;
  cvt2(v1.z, h, l); hi[6] = (short)h; lo[6] = (short)l;
  cvt2(v1.w, h, l); hi[7] = (short)h; lo[7] = (short)l;
}

__device__ __forceinline__ unsigned short bf_rnd(float x) {
  unsigned u = __float_as_uint(x);
  return (unsigned short)((u + 0x8000u) >> 16);
}

// ---------------------------------------------------------------- CAM energy
// Partial E[kc][t][b] = X(:,kslice) X(:,kslice)^T, kc=0..7 (K=800 each,
// 12 x 64 + zero-padded 32 tail). Grid = 256 blocks (1/CU, single round).
// One 512-thread block computes the FULL 256x256 tile; one LDS panel is both
// MFMA operands (A-frag == B-frag). Double-buffered LDS, 1 barrier/iter.
__global__ __launch_bounds__(512) void cam_energy_k(const float* __restrict__ fS,
                                                    const float* __restrict__ fT,
                                                    float* __restrict__ part) {
  const int kc = blockIdx.x, b = blockIdx.y, t = blockIdx.z;
  const float* X = (t ? fT : fS) + (size_t)b * CH * HW;
  __shared__ unsigned short lds[2 * 256 * 64];  // 2 x 32 KB panels
  const int tid = threadIdx.x, lane = tid & 63, w = tid >> 6;
  const int wr = w >> 2, wc = w & 3;
  const int r0 = tid >> 1, half = tid & 1;
  const int kbase = kc * 800 + half * 32;   // this thread's k start per iter
  const float* Xr = X + (size_t)r0 * HW + kbase;
  f32x4 acc[8][4] = {};
  float4 v[8];
#pragma unroll
  for (int q = 0; q < 8; ++q) v[q] = *(const float4*)(Xr + q * 4);
  for (int it = 0; it < 13; ++it) {
    char* pb = (char*)lds + (it & 1) * 32768;
#pragma unroll
    for (int q = 0; q < 8; ++q) {
      ushort4 u;
      u.x = bf_rnd(v[q].x); u.y = bf_rnd(v[q].y);
      u.z = bf_rnd(v[q].z); u.w = bf_rnd(v[q].w);
      *(ushort4*)(pb + lds_off(r0, half, q * 8)) = u;
    }
    __syncthreads();
    float4 nv[8];
    if (it < 12) {
      const int nk = (it + 1) * 64;   // offset within this block's 800-slice
      if (nk + half * 32 < 800) {     // tail iter: half==1 is fully padded
        const float* Xn = Xr + nk;
#pragma unroll
        for (int q = 0; q < 8; ++q) nv[q] = *(const float4*)(Xn + q * 4);
      } else {
#pragma unroll
        for (int q = 0; q < 8; ++q) nv[q] = make_float4(0.f, 0.f, 0.f, 0.f);
      }
    }
    bf16x8 bfr[2][4];
#pragma unroll
    for (int h = 0; h < 2; ++h)
#pragma unroll
      for (int n = 0; n < 4; ++n)
        bfr[h][n] = frag_ld(pb, wc * 64 + n * 16 + (lane & 15), h, lane);
#pragma unroll
    for (int m = 0; m < 8; ++m) {
      int arow = wr * 128 + m * 16 + (lane & 15);
      bf16x8 a0 = frag_ld(pb, arow, 0, lane);
      bf16x8 a1 = frag_ld(pb, arow, 1, lane);
#pragma unroll
      for (int n = 0; n < 4; ++n)
        acc[m][n] = __builtin_amdgcn_mfma_f32_16x16x32_bf16(a0, bfr[0][n], acc[m][n], 0, 0, 0);
#pragma unroll
      for (int n = 0; n < 4; ++n)
        acc[m][n] = __builtin_amdgcn_mfma_f32_16x16x32_bf16(a1, bfr[1][n], acc[m][n], 0, 0, 0);
    }
#pragma unroll
    for (int q = 0; q < 8; ++q) v[q] = nv[q];
  }
  float* Eb = part + (((size_t)kc * 2 + t) * BB + b) * 65536;
#pragma unroll
  for (int m = 0; m < 8; ++m)
#pragma unroll
    for (int n = 0; n < 4; ++n) {
      int row = wr * 128 + m * 16 + ((lane >> 4) << 2);
      int col = wc * 64 + n * 16 + (lane & 15);
#pragma unroll
      for (int r2 = 0; r2 < 4; ++r2)
        Eb[(size_t)(row + r2) * 256 + col] = acc[m][n][r2];
    }
}

// ------------------------------------------------------------- CAM softmax
// attn = exp(rowmin - sum_p partE[p]) / rowsum, written into partial 0.
__global__ __launch_bounds__(64) void cam_softmax_k(float* __restrict__ part) {
  const int c = blockIdx.x, b = blockIdx.y, t = blockIdx.z;
  const size_t base = (((size_t)t * BB + b) * CH + c) * CH;
  const int lane = threadIdx.x;
  float4 x = make_float4(0.f, 0.f, 0.f, 0.f);
#pragma unroll
  for (int p = 0; p < 8; ++p) {
    float4 y = ((const float4*)(part + (size_t)p * 2097152 + base))[lane];
    x.x += y.x; x.y += y.y; x.z += y.z; x.w += y.w;
  }
  float mn = fminf(fminf(x.x, x.y), fminf(x.z, x.w));
  for (int o = 32; o; o >>= 1) mn = fminf(mn, __shfl_xor(mn, o));
  float4 p4;
  p4.x = __expf(mn - x.x); p4.y = __expf(mn - x.y);
  p4.z = __expf(mn - x.z); p4.w = __expf(mn - x.w);
  float s = (p4.x + p4.y) + (p4.z + p4.w);
  for (int o = 32; o; o >>= 1) s += __shfl_xor(s, o);
  const float inv = 1.0f / s;
  p4.x *= inv; p4.y *= inv; p4.z *= inv; p4.w *= inv;
  ((float4*)(part + base))[lane] = p4;
}

// ----------------------------------------------------- A(256x256) @ X GEMM
// MODE 0 (cam_out): OUT[c][n] = g*sum_d A[c][d] X[d][n] + X[c][n]
// MODE 1 (pam_V):   OUT[d][n] = sum_c Wv[d][c] X[c][n] + bv[d]
// R9: tile M=256 (all rows) x N=128, 512 threads, grid (50, BB).
// X main read happens ONCE (was twice with mt=0/1). split-bf16.
template <int MODE>
__global__ __launch_bounds__(512) void ax_k(const float* __restrict__ Abase, int Astride,
                                            const float* __restrict__ X,
                                            float* __restrict__ OUT,
                                            const float* __restrict__ bvec,
                                            const float* __restrict__ gsc) {
  const int nt = blockIdx.x;
  const int b = blockIdx.y;
  const float* A = Abase + (size_t)b * Astride;
  const float* Xb = X + (size_t)b * CH * HW;
  float* OUTb = OUT + (size_t)b * CH * HW;
  const int nbase = nt * 128;
  __shared__ unsigned short lds[(256 + 128) * 64];  // A 32KB + B 16KB
  char* Ab = (char*)lds;
  char* Bb = (char*)lds + 32768;
  const int tid = threadIdx.x, lane = tid & 63, w = tid >> 6;
  const int wr = w >> 1, wc = w & 1;             // 4 x 2 waves -> 64x64 each
  const int r0 = tid >> 1, kq = tid & 1;         // A staging: 4 float4/thread
  const int n4 = (tid & 31) * 4, c0l = tid >> 5; // B staging: 2 float4/thread
  f32x4 acc[4][4] = {};
  float4 ra[4], rb[2];
#pragma unroll
  for (int q = 0; q < 4; ++q)
    ra[q] = *(const float4*)(A + (size_t)r0 * 256 + kq * 16 + q * 4);
#pragma unroll
  for (int q = 0; q < 2; ++q)
    rb[q] = *(const float4*)(Xb + (size_t)(c0l + 16 * q) * HW + nbase + n4);
  for (int s = 0; s < 8; ++s) {
#pragma unroll
    for (int q = 0; q < 4; ++q) {
      ushort4 h4, l4;
      cvt4(ra[q], h4, l4);
      *(ushort4*)(Ab + lds_off(r0, 0, kq * 32 + q * 8)) = h4;
      *(ushort4*)(Ab + lds_off(r0, 1, kq * 32 + q * 8)) = l4;
    }
#pragma unroll
    for (int q = 0; q < 2; ++q) {
      int cc = c0l + 16 * q;
      float4 v = rb[q];
#pragma unroll
      for (int jj = 0; jj < 4; ++jj) {
        int j = (jj + tid) & 3;   // rotate -> spread across (row&7) groups
        float e = (j == 0) ? v.x : (j == 1) ? v.y : (j == 2) ? v.z : v.w;
        unsigned short h, l;
        cvt2(e, h, l);
        int row = n4 + j;
        *(unsigned short*)(Bb + lds_off(row, 0, cc * 2)) = h;
        *(unsigned short*)(Bb + lds_off(row, 1, cc * 2)) = l;
      }
    }
    __syncthreads();
    if (s < 7) {
      int k0 = (s + 1) * 32;
#pragma unroll
      for (int q = 0; q < 4; ++q)
        ra[q] = *(const float4*)(A + (size_t)r0 * 256 + k0 + kq * 16 + q * 4);
#pragma unroll
      for (int q = 0; q < 2; ++q)
        rb[q] = *(const float4*)(Xb + (size_t)(k0 + c0l + 16 * q) * HW + nbase + n4);
    }
    bf16x8 bfr[2][4];
#pragma unroll
    for (int h = 0; h < 2; ++h)
#pragma unroll
      for (int n = 0; n < 4; ++n)
        bfr[h][n] = frag_ld(Bb, wc * 64 + n * 16 + (lane & 15), h, lane);
#pragma unroll
    for (int m = 0; m < 4; ++m) {
      int arow = wr * 64 + m * 16 + (lane & 15);
      bf16x8 a0 = frag_ld(Ab, arow, 0, lane);
      bf16x8 a1 = frag_ld(Ab, arow, 1, lane);
#pragma unroll
      for (int n = 0; n < 4; ++n)
        acc[m][n] = __builtin_amdgcn_mfma_f32_16x16x32_bf16(a0, bfr[0][n], acc[m][n], 0, 0, 0);
#pragma unroll
      for (int n = 0; n < 4; ++n)
        acc[m][n] = __builtin_amdgcn_mfma_f32_16x16x32_bf16(a0, bfr[1][n], acc[m][n], 0, 0, 0);
#pragma unroll
      for (int n = 0; n < 4; ++n)
        acc[m][n] = __builtin_amdgcn_mfma_f32_16x16x32_bf16(a1, bfr[0][n], acc[m][n], 0, 0, 0);
    }
    __syncthreads();
  }
  float g = 0.f;
  if (MODE == 0) g = gsc[0];
#pragma unroll
  for (int m = 0; m < 4; ++m)
#pragma unroll
    for (int n = 0; n < 4; ++n) {
      int row = wr * 64 + m * 16 + ((lane >> 4) << 2);
      int col = nbase + wc * 64 + n * 16 + (lane & 15);
#pragma unroll
      for (int r2 = 0; r2 < 4; ++r2) {
        size_t o = (size_t)(row + r2) * HW + col;
        float v = acc[m][n][r2];
        if (MODE == 0) OUTb[o] = g * v + Xb[o];
        else           OUTb[o] = v + bvec[row + r2];
      }
    }
}

// ------------------------------------------------------------ PAM q/k GEMM
// Full-image 1x1 conv: rows 0..31 = Wq, 32..63 = Wk; N = 6400, K = 256.
// Outputs: qt[b][n][32] (n-major, +bq), kf[b][32][n] (+bk). split-bf16.
__global__ __launch_bounds__(256) void qk_k(const float* __restrict__ X,
                                            const float* __restrict__ Wq,
                                            const float* __restrict__ bq,
                                            const float* __restrict__ Wk,
                                            const float* __restrict__ bk,
                                            float* __restrict__ qt,
                                            float* __restrict__ kf) {
  const int nbase = blockIdx.x * 256;
  const int b = blockIdx.y;
  const float* Xb = X + (size_t)b * CH * HW;
  __shared__ unsigned short lds[(64 + 256) * 64];  // A 8KB + B 32KB
  char* Ab = (char*)lds;
  char* Bb = (char*)lds + 8192;
  const int tid = threadIdx.x, lane = tid & 63, w = tid >> 6;
  const int ar = tid >> 2, akq = tid & 3;          // A staging
  const int n4 = (tid & 63) * 4, c0l = tid >> 6;   // B staging (256 rows)
  const float* Arow = (ar < 32) ? (Wq + (size_t)ar * CH) : (Wk + (size_t)(ar - 32) * CH);
  f32x4 acc[4][4] = {};
  float4 va[2], vb[8];
#pragma unroll
  for (int q = 0; q < 2; ++q)
    va[q] = *(const float4*)(Arow + akq * 8 + q * 4);
#pragma unroll
  for (int q = 0; q < 8; ++q)
    vb[q] = *(const float4*)(Xb + (size_t)(c0l + 4 * q) * HW + nbase + n4);
  for (int s = 0; s < 8; ++s) {
    __syncthreads();   // prev iter's frag reads done
#pragma unroll
    for (int q = 0; q < 2; ++q) {
      ushort4 h4, l4;
      cvt4(va[q], h4, l4);
      *(ushort4*)(Ab + lds_off(ar, 0, akq * 16 + q * 8)) = h4;
      *(ushort4*)(Ab + lds_off(ar, 1, akq * 16 + q * 8)) = l4;
    }
#pragma unroll
    for (int q = 0; q < 8; ++q) {
      int cc = c0l + 4 * q;
      float4 v = vb[q];
#pragma unroll
      for (int jj = 0; jj < 4; ++jj) {
        int j = (jj + tid) & 3;
        float e = (j == 0) ? v.x : (j == 1) ? v.y : (j == 2) ? v.z : v.w;
        unsigned short h, l;
        cvt2(e, h, l);
        int row = n4 + j;
        *(unsigned short*)(Bb + lds_off(row, 0, cc * 2)) = h;
        *(unsigned short*)(Bb + lds_off(row, 1, cc * 2)) = l;
      }
    }
    __syncthreads();
    float4 na[2], nb[8];
    if (s < 7) {
      const int k0 = (s + 1) * 32;
#pragma unroll
      for (int q = 0; q < 2; ++q)
        na[q] = *(const float4*)(Arow + k0 + akq * 8 + q * 4);
#pragma unroll
      for (int q = 0; q < 8; ++q)
        nb[q] = *(const float4*)(Xb + (size_t)(k0 + c0l + 4 * q) * HW + nbase + n4);
    }
    bf16x8 bfr[2][4];
#pragma unroll
    for (int h = 0; h < 2; ++h)
#pragma unroll
      for (int n = 0; n < 4; ++n)
        bfr[h][n] = frag_ld(Bb, w * 64 + n * 16 + (lane & 15), h, lane);
#pragma unroll
    for (int m = 0; m < 4; ++m) {
      int arow2 = m * 16 + (lane & 15);
      bf16x8 a0 = frag_ld(Ab, arow2, 0, lane);
      bf16x8 a1 = frag_ld(Ab, arow2, 1, lane);
#pragma unroll
      for (int n = 0; n < 4; ++n)
        acc[m][n] = __builtin_amdgcn_mfma_f32_16x16x32_bf16(a0, bfr[0][n], acc[m][n], 0, 0, 0);
#pragma unroll
      for (int n = 0; n < 4; ++n)
        acc[m][n] = __builtin_amdgcn_mfma_f32_16x16x32_bf16(a0, bfr[1][n], acc[m][n], 0, 0, 0);
#pragma unroll
      for (int n = 0; n < 4; ++n)
        acc[m][n] = __builtin_amdgcn_mfma_f32_16x16x32_bf16(a1, bfr[0][n], acc[m][n], 0, 0, 0);
    }
#pragma unroll
    for (int q = 0; q < 2; ++q) va[q] = na[q];
#pragma unroll
    for (int q = 0; q < 8; ++q) vb[q] = nb[q];
  }
#pragma unroll
  for (int m = 0; m < 4; ++m)
#pragma unroll
    for (int n = 0; n < 4; ++n) {
      int row = m * 16 + ((lane >> 4) << 2);
      int col = nbase + w * 64 + n * 16 + (lane & 15);
#pragma unroll
      for (int r2 = 0; r2 < 4; ++r2) {
        int rr = row + r2;
        float v = acc[m][n][r2];
        if (rr < 32) qt[((size_t)b * HW + col) * 32 + rr] = v + bq[rr];
        else         kf[((size_t)b * 32 + (rr - 32)) * HW + col] = v + bk[rr - 32];
      }
    }
}

// --------------------------------------------------- PAM energy + softmax
__global__ __launch_bounds__(256) void pam_es_k(const float* __restrict__ qt,
                                                const float* __restrict__ kf,
                                                float* __restrict__ Pbuf) {
  const int ccb = blockIdx.x;
  const int ck = ccb >> 4, b = ccb & 15;
  const int gi = ck / 5, gj = ck % 5;
  const int pbase = gi * 16 * IMW + gj * 16;
  float* Pc = Pbuf + (size_t)ccb * 65536;
  __shared__ float qs[256][32];
  __shared__ float S[32][256];
  const int tid = threadIdx.x;
  const float* qb = qt + (size_t)b * HW * 32;
#pragma unroll
  for (int qq = 0; qq < 8; ++qq) {
    int j = (tid >> 3) + 32 * qq;
    int nj = pbase + (j >> 4) * IMW + (j & 15);
    float4 v = *(const float4*)(qb + (size_t)nj * 32 + (tid & 7) * 4);
    *(float4*)&qs[j][(tid & 7) * 4] = v;
  }
  const int nt = pbase + (tid >> 4) * IMW + (tid & 15);
  const float* kb = kf + (size_t)b * 32 * HW;
  float kc[32];
#pragma unroll
  for (int kk = 0; kk < 32; ++kk) kc[kk] = kb[(size_t)kk * HW + nt];
  __syncthreads();
  const int w = tid >> 6, lane = tid & 63;
  for (int p = 0; p < 8; ++p) {
#pragma unroll 4
    for (int j2 = 0; j2 < 32; ++j2) {
      int row = p * 32 + j2;
      float s = 0.f;
#pragma unroll
      for (int k8 = 0; k8 < 8; ++k8) {
        float4 qv = *(const float4*)&qs[row][k8 * 4];
        s = fmaf(qv.x, kc[k8 * 4 + 0], s);
        s = fmaf(qv.y, kc[k8 * 4 + 1], s);
        s = fmaf(qv.z, kc[k8 * 4 + 2], s);
        s = fmaf(qv.w, kc[k8 * 4 + 3], s);
      }
      S[j2][tid] = s;
    }
    __syncthreads();
#pragma unroll
    for (int rr = 0; rr < 8; ++rr) {
      int jj = w * 8 + rr;
      float4 v = *(const float4*)&S[jj][lane << 2];
      float m = fmaxf(fmaxf(v.x, v.y), fmaxf(v.z, v.w));
      for (int o = 32; o; o >>= 1) m = fmaxf(m, __shfl_xor(m, o));
      float4 pv;
      pv.x = __expf(v.x - m); pv.y = __expf(v.y - m);
      pv.z = __expf(v.z - m); pv.w = __expf(v.w - m);
      float s = (pv.x + pv.y) + (pv.z + pv.w);
      for (int o = 32; o; o >>= 1) s += __shfl_xor(s, o);
      const float inv = 1.f / s;
      pv.x *= inv; pv.y *= inv; pv.z *= inv; pv.w *= inv;
      *(float4*)&Pc[(size_t)(p * 32 + jj) * 256 + (lane << 2)] = pv;
    }
    __syncthreads();
  }
}

// ---------------------------------------------------------------- PAM PV
// One 512-thr block per ccb: out[d][j] = g*sum_n V[d][n] P[j][n] + X[d][n(j)],
// written over P[ccb] after all reads complete. Register-prefetch pipeline.
__global__ __launch_bounds__(512) void pam_pv_k(float* __restrict__ P,
                                                const float* __restrict__ V,
                                                const float* __restrict__ fS,
                                                const float* __restrict__ fT,
                                                const float* __restrict__ gsc, int t) {
  const int ccb = blockIdx.x;
  const int ck = ccb >> 4, b = ccb & 15;
  const int gi = ck / 5, gj = ck % 5;
  const float* Xb = (t ? fT : fS) + (size_t)b * CH * HW;
  const float* Vb = V + (size_t)b * CH * HW;
  float* Pc = P + (size_t)ccb * 65536;
  __shared__ unsigned short lds[2 * 256 * 64];
  char* Ab = (char*)lds;
  char* Bb = (char*)lds + 32768;
  const int tid = threadIdx.x, lane = tid & 63, w = tid >> 6;
  const int wr = w >> 2, wc = w & 3;
  const int r0 = tid >> 3, kq = tid & 7;
  const int pbase = gi * 16 * IMW + gj * 16;
  f32x4 acc[8][4] = {};
  float4 va[4], vb[4];
  {
    int jj = kq * 4;
    int ngl = pbase + (jj >> 4) * IMW + (jj & 15);
#pragma unroll
    for (int q = 0; q < 4; ++q) {
      int rr = r0 + 64 * q;
      va[q] = *(const float4*)(Vb + (size_t)rr * HW + ngl);
      vb[q] = *(const float4*)(Pc + (size_t)rr * 256 + kq * 4);
    }
  }
  for (int s = 0; s < 8; ++s) {
    __syncthreads();   // prev iter's frag reads done
#pragma unroll
    for (int q = 0; q < 4; ++q) {
      int rr = r0 + 64 * q;
      ushort4 h4, l4;
      cvt4(va[q], h4, l4);
      *(ushort4*)(Ab + lds_off(rr, 0, kq * 8)) = h4;
      *(ushort4*)(Ab + lds_off(rr, 1, kq * 8)) = l4;
      cvt4(vb[q], h4, l4);
      *(ushort4*)(Bb + lds_off(rr, 0, kq * 8)) = h4;
      *(ushort4*)(Bb + lds_off(rr, 1, kq * 8)) = l4;
    }
    __syncthreads();
    float4 na[4], nb[4];
    if (s < 7) {
      int k0 = (s + 1) * 32;
      int jj = k0 + kq * 4;
      int ngl = pbase + (jj >> 4) * IMW + (jj & 15);
#pragma unroll
      for (int q = 0; q < 4; ++q) {
        int rr = r0 + 64 * q;
        na[q] = *(const float4*)(Vb + (size_t)rr * HW + ngl);
        nb[q] = *(const float4*)(Pc + (size_t)rr * 256 + k0 + kq * 4);
      }
    }
    bf16x8 bfr[2][4];
#pragma unroll
    for (int h = 0; h < 2; ++h)
#pragma unroll
      for (int n = 0; n < 4; ++n)
        bfr[h][n] = frag_ld(Bb, wc * 64 + n * 16 + (lane & 15), h, lane);
#pragma unroll
    for (int m = 0; m < 8; ++m) {
      int arow = wr * 128 + m * 16 + (lane & 15);
      bf16x8 a0 = frag_ld(Ab, arow, 0, lane);
      bf16x8 a1 = frag_ld(Ab, arow, 1, lane);
#pragma unroll
      for (int n = 0; n < 4; ++n)
        acc[m][n] = __builtin_amdgcn_mfma_f32_16x16x32_bf16(a0, bfr[0][n], acc[m][n], 0, 0, 0);
#pragma unroll
      for (int n = 0; n < 4; ++n)
        acc[m][n] = __builtin_amdgcn_mfma_f32_16x16x32_bf16(a0, bfr[1][n], acc[m][n], 0, 0, 0);
#pragma unroll
      for (int n = 0; n < 4; ++n)
        acc[m][n] = __builtin_amdgcn_mfma_f32_16x16x32_bf16(a1, bfr[0][n], acc[m][n], 0, 0, 0);
    }
#pragma unroll
    for (int q = 0; q < 4; ++q) { va[q] = na[q]; vb[q] = nb[q]; }
  }
  const float g = gsc[0];
#pragma unroll
  for (int m = 0; m < 8; ++m)
#pragma unroll
    for (int n = 0; n < 4; ++n) {
      int row = wr * 128 + m * 16 + ((lane >> 4) << 2);
      int col = wc * 64 + n * 16 + (lane & 15);
      int ngl = pbase + (col >> 4) * IMW + (col & 15);
#pragma unroll
      for (int r2 = 0; r2 < 4; ++r2) {
        float v = g * acc[m][n][r2] + Xb[(size_t)(row + r2) * HW + ngl];
        Pc[(size_t)(row + r2) * 256 + col] = v;
      }
    }
}

// ------------------------------------------------------------- gram (MFMA)
__global__ __launch_bounds__(256) void gram_mfma_k(const float* __restrict__ Z,
                                                   size_t gStride, size_t bStride,
                                                   double* __restrict__ G) {
  const int tid = threadIdx.x, lane = tid & 63, w = tid >> 6;
  const float* Zg = Z + (size_t)blockIdx.y * gStride;
  const float* p = Zg + (size_t)(lane & 15) * bStride +
                   (size_t)blockIdx.x * 4096 + w * 1024 + ((lane >> 4) << 3);
  f32x4 acc = {};
#pragma unroll 4
  for (int s = 0; s < 32; ++s) {
    float4 v0 = *(const float4*)(p + s * 32);
    float4 v1 = *(const float4*)(p + s * 32 + 4);
    bf16x8 hi, lo;
    cvt8(v0, v1, hi, lo);
    acc = __builtin_amdgcn_mfma_f32_16x16x32_bf16(hi, hi, acc, 0, 0, 0);
    acc = __builtin_amdgcn_mfma_f32_16x16x32_bf16(hi, lo, acc, 0, 0, 0);
    acc = __builtin_amdgcn_mfma_f32_16x16x32_bf16(lo, hi, acc, 0, 0, 0);
  }
  double* Gt = G + (size_t)blockIdx.y * 256;
  const int col = lane & 15, row0 = (lane >> 4) << 2;
#pragma unroll
  for (int i = 0; i < 4; ++i)
    atomicAdd(&Gt[(size_t)(row0 + i) * 16 + col], (double)acc[i]);
}

// -------------------------------------------------------------- CKA pairs
__global__ __launch_bounds__(256) void cka_pair_k(const double* __restrict__ G,
                                                  double* __restrict__ losses) {
  const int q = blockIdx.x;
  const double* KX = (q == 0) ? G : G + 512 + (size_t)(q - 1) * 256;
  const double* KY = (q == 0) ? G + 256 : G + 512 + 6400 + (size_t)(q - 1) * 256;
  __shared__ double red[256];
  __shared__ double srm[16], scm[16];
  __shared__ double stm;
  const int tid = threadIdx.x;
  const int r = tid >> 4, c = tid & 15;

  auto center = [&](double k) -> double {
    red[tid] = k;
    __syncthreads();
    for (int off = 8; off; off >>= 1) {
      if (c < off) red[tid] += red[tid + off];
      __syncthreads();
    }
    if (c == 0) srm[r] = red[tid] * (1.0 / 16.0);
    __syncthreads();
    red[c * 16 + r] = k;
    __syncthreads();
    for (int off = 8; off; off >>= 1) {
      if (r < off) red[c * 16 + r] += red[c * 16 + r + off];
      __syncthreads();
    }
    if (r == 0) scm[c] = red[c * 16] * (1.0 / 16.0);
    __syncthreads();
    if (tid == 0) {
      double s = 0.0;
      for (int i = 0; i < 16; ++i) s += srm[i];
      stm = s * (1.0 / 16.0);
    }
    __syncthreads();
    double v = k - srm[r] - scm[c] + stm;
    __syncthreads();
    return v;
  };
  auto reduce_sum = [&](double v) -> double {
    red[tid] = v;
    __syncthreads();
    for (int off = 128; off; off >>= 1) {
      if (tid < off) red[tid] += red[tid + off];
      __syncthreads();
    }
    double s = red[0];
    __syncthreads();
    return s;
  };
  double cx = center(KX[tid]);
  double cy = center(KY[tid]);
  double h = reduce_sum(cx * cy);
  double v1 = reduce_sum(cx * cx);
  double v2 = reduce_sum(cy * cy);
  if (tid == 0) losses[q] = -log(fabs(h / (sqrt(v1) * sqrt(v2))) + 1e-8);
}

__global__ void cka_combine_k(const double* __restrict__ losses,
                              float* __restrict__ out) {
  if (threadIdx.x == 0) {
    out[0] = (float)losses[0];
    double s = 0.0;
    for (int q = 1; q <= 25; ++q) s += losses[q];
    out[1] = (float)(s * (1.0 / 25.0));
  }
}

extern "C" void kernel_launch(void* const* d_in, const int* in_sizes, int n_in,
                              void* d_out, int out_size, void* d_ws, size_t ws_size,
                              hipStream_t stream) {
  (void)in_sizes; (void)n_in; (void)out_size; (void)ws_size;
  const float* fS = (const float*)d_in[0];
  const float* fT = (const float*)d_in[1];
  const float* Wq = (const float*)d_in[2];
  const float* bq = (const float*)d_in[3];
  const float* Wk = (const float*)d_in[4];
  const float* bk = (const float*)d_in[5];
  const float* Wv = (const float*)d_in[6];
  const float* bv = (const float*)d_in[7];
  const float* gcam = (const float*)d_in[8];
  const float* gpam = (const float*)d_in[9];
  float* out = (float*)d_out;

  float* buf0 = (float*)d_ws;              // 26214400 floats
  float* buf1 = buf0 + 26214400;           // 26214400 floats
  double* G = (double*)(buf1 + 26214400);  // 13312 doubles
  float* Pbuf = buf1;                      // 400*65536
  float* qt = buf0;                        // 16*6400*32
  float* kf = buf0 + 3276800;              // 16*32*6400
  double* losses = (double*)buf0;          // 26 doubles, dead region at CKA time

  hipMemsetAsync(G, 0, 13312 * sizeof(double), stream);

  // ---- CAM ----
  cam_energy_k<<<dim3(8, 16, 2), 512, 0, stream>>>(fS, fT, buf1);
  cam_softmax_k<<<dim3(256, 16, 2), 64, 0, stream>>>(buf1);
  for (int t = 0; t < 2; ++t) {
    ax_k<0><<<dim3(50, 16), 512, 0, stream>>>(buf1 + (size_t)t * BB * 65536, 65536,
                                              t ? fT : fS, buf0, nullptr, gcam);
    gram_mfma_k<<<dim3(400, 1), 256, 0, stream>>>(buf0, (size_t)0, (size_t)1638400,
                                                  G + t * 256);
  }
  // ---- PAM ----
  for (int t = 0; t < 2; ++t) {
    const float* X = t ? fT : fS;
    qk_k<<<dim3(25, 16), 256, 0, stream>>>(X, Wq, bq, Wk, bk, qt, kf);
    pam_es_k<<<dim3(400), 256, 0, stream>>>(qt, kf, Pbuf);
    ax_k<1><<<dim3(50, 16), 512, 0, stream>>>(Wv, 0, X, buf0, bv, nullptr);
    pam_pv_k<<<dim3(400), 512, 0, stream>>>(Pbuf, buf0, fS, fT, gpam, t);
    gram_mfma_k<<<dim3(16, 25), 256, 0, stream>>>(Pbuf, (size_t)1048576, (size_t)65536,
                                                  G + 512 + t * 6400);
  }
  cka_pair_k<<<dim3(26), 256, 0, stream>>>(G, losses);
  cka_combine_k<<<dim3(1), 64, 0, stream>>>(losses, out);
}

// Round 12
// 1055.842 us; speedup vs baseline: 2.7908x; 1.0153x over previous
//
#include <hip/hip_runtime.h>

// CriterionSA: CAM + grid-PAM + CKA loss.
// GEMMs in split-bf16 MFMA (hi/lo, 3 MFMAs: hh+hl+lh); cam_energy plain bf16
// (softmax saturated). Grams via MFMA split-bf16; fp32 acc -> fp64 atomics.
// CKA fp64, 26 parallel blocks.
// R12: ax_k B-staging vectorized (coalesced scalar column loads + ushort4
// stores, replacing 16 scalar ushort stores/thread/step -> bank-conflict fix).
// ws layout (floats): buf0[26214400] | buf1[26214400] | G[13312 doubles]
// required ws = 209,821,696 bytes (~200.1 MiB) -- same as rounds 1-11.

typedef short bf16x8 __attribute__((ext_vector_type(8)));
typedef float f32x4 __attribute__((ext_vector_type(4)));

constexpr int BB = 16;    // batch
constexpr int CH = 256;   // channels
constexpr int HW = 6400;  // 80*80
constexpr int IMW = 80;

__device__ __forceinline__ int lds_off(int row, int half, int k2) {
  return row * 128 + ((((half << 6)) | k2) ^ ((row & 7) << 4));
}

__device__ __forceinline__ bf16x8 frag_ld(const char* base, int row, int half, int lane) {
  int off = row * 128 + ((((half << 6)) | ((lane >> 4) << 4)) ^ ((lane & 7) << 4));
  return *(const bf16x8*)(base + off);
}

__device__ __forceinline__ void cvt2(float x, unsigned short& h, unsigned short& l) {
  unsigned u = __float_as_uint(x);
  h = (unsigned short)(u >> 16);                       // truncated hi
  float r = x - __uint_as_float(u & 0xffff0000u);
  l = (unsigned short)(__float_as_uint(r) >> 16);      // truncated residual
}

__device__ __forceinline__ void cvt4(float4 v, ushort4& h, ushort4& l) {
  cvt2(v.x, h.x, l.x); cvt2(v.y, h.y, l.y);
  cvt2(v.z, h.z, l.z); cvt2(v.w, h.w, l.w);
}

__device__ __forceinline__ void cvt8(float4 v0, float4 v1, bf16x8& hi, bf16x8& lo) {
  unsigned short h, l;
  cvt2(v0.x, h, l); hi[0] = (short)h; lo[0] = (short)l;
  cvt2(v0.y, h, l); hi[1] = (short)h; lo[1] = (short)l;
  cvt2(v0.z, h, l); hi[2] = (short)h; lo[2] = (short)l;
  cvt2(v0.w, h, l); hi[3] = (short)h; lo[3] = (short)l;
  cvt2(v1.x, h, l); hi[4] = (short)h; lo[4] = (short)l;
  cvt2(v1.y, h, l); hi[5] = (short)h; lo[5] = (short)l;
  cvt2(v1.z, h, l); hi[6] = (short)h; lo[6] = (short)l;
  cvt2(v1.w, h, l); hi[7] = (short)h; lo[7] = (short)l;
}

__device__ __forceinline__ unsigned short bf_rnd(float x) {
  unsigned u = __float_as_uint(x);
  return (unsigned short)((u + 0x8000u) >> 16);
}

// ---------------------------------------------------------------- CAM energy
// Partial E[kc][t][b] = X(:,kslice) X(:,kslice)^T, kc=0..7 (K=800 each,
// 12 x 64 + zero-padded 32 tail). Grid = 256 blocks (1/CU, single round).
// One 512-thread block computes the FULL 256x256 tile; one LDS panel is both
// MFMA operands (A-frag == B-frag). Double-buffered LDS, 1 barrier/iter.
__global__ __launch_bounds__(512) void cam_energy_k(const float* __restrict__ fS,
                                                    const float* __restrict__ fT,
                                                    float* __restrict__ part) {
  const int kc = blockIdx.x, b = blockIdx.y, t = blockIdx.z;
  const float* X = (t ? fT : fS) + (size_t)b * CH * HW;
  __shared__ unsigned short lds[2 * 256 * 64];  // 2 x 32 KB panels
  const int tid = threadIdx.x, lane = tid & 63, w = tid >> 6;
  const int wr = w >> 2, wc = w & 3;
  const int r0 = tid >> 1, half = tid & 1;
  const int kbase = kc * 800 + half * 32;   // this thread's k start per iter
  const float* Xr = X + (size_t)r0 * HW + kbase;
  f32x4 acc[8][4] = {};
  float4 v[8];
#pragma unroll
  for (int q = 0; q < 8; ++q) v[q] = *(const float4*)(Xr + q * 4);
  for (int it = 0; it < 13; ++it) {
    char* pb = (char*)lds + (it & 1) * 32768;
#pragma unroll
    for (int q = 0; q < 8; ++q) {
      ushort4 u;
      u.x = bf_rnd(v[q].x); u.y = bf_rnd(v[q].y);
      u.z = bf_rnd(v[q].z); u.w = bf_rnd(v[q].w);
      *(ushort4*)(pb + lds_off(r0, half, q * 8)) = u;
    }
    __syncthreads();
    float4 nv[8];
    if (it < 12) {
      const int nk = (it + 1) * 64;   // offset within this block's 800-slice
      if (nk + half * 32 < 800) {     // tail iter: half==1 is fully padded
        const float* Xn = Xr + nk;
#pragma unroll
        for (int q = 0; q < 8; ++q) nv[q] = *(const float4*)(Xn + q * 4);
      } else {
#pragma unroll
        for (int q = 0; q < 8; ++q) nv[q] = make_float4(0.f, 0.f, 0.f, 0.f);
      }
    }
    bf16x8 bfr[2][4];
#pragma unroll
    for (int h = 0; h < 2; ++h)
#pragma unroll
      for (int n = 0; n < 4; ++n)
        bfr[h][n] = frag_ld(pb, wc * 64 + n * 16 + (lane & 15), h, lane);
#pragma unroll
    for (int m = 0; m < 8; ++m) {
      int arow = wr * 128 + m * 16 + (lane & 15);
      bf16x8 a0 = frag_ld(pb, arow, 0, lane);
      bf16x8 a1 = frag_ld(pb, arow, 1, lane);
#pragma unroll
      for (int n = 0; n < 4; ++n)
        acc[m][n] = __builtin_amdgcn_mfma_f32_16x16x32_bf16(a0, bfr[0][n], acc[m][n], 0, 0, 0);
#pragma unroll
      for (int n = 0; n < 4; ++n)
        acc[m][n] = __builtin_amdgcn_mfma_f32_16x16x32_bf16(a1, bfr[1][n], acc[m][n], 0, 0, 0);
    }
#pragma unroll
    for (int q = 0; q < 8; ++q) v[q] = nv[q];
  }
  float* Eb = part + (((size_t)kc * 2 + t) * BB + b) * 65536;
#pragma unroll
  for (int m = 0; m < 8; ++m)
#pragma unroll
    for (int n = 0; n < 4; ++n) {
      int row = wr * 128 + m * 16 + ((lane >> 4) << 2);
      int col = wc * 64 + n * 16 + (lane & 15);
#pragma unroll
      for (int r2 = 0; r2 < 4; ++r2)
        Eb[(size_t)(row + r2) * 256 + col] = acc[m][n][r2];
    }
}

// ------------------------------------------------------------- CAM softmax
// attn = exp(rowmin - sum_p partE[p]) / rowsum, written into partial 0.
__global__ __launch_bounds__(64) void cam_softmax_k(float* __restrict__ part) {
  const int c = blockIdx.x, b = blockIdx.y, t = blockIdx.z;
  const size_t base = (((size_t)t * BB + b) * CH + c) * CH;
  const int lane = threadIdx.x;
  float4 x = make_float4(0.f, 0.f, 0.f, 0.f);
#pragma unroll
  for (int p = 0; p < 8; ++p) {
    float4 y = ((const float4*)(part + (size_t)p * 2097152 + base))[lane];
    x.x += y.x; x.y += y.y; x.z += y.z; x.w += y.w;
  }
  float mn = fminf(fminf(x.x, x.y), fminf(x.z, x.w));
  for (int o = 32; o; o >>= 1) mn = fminf(mn, __shfl_xor(mn, o));
  float4 p4;
  p4.x = __expf(mn - x.x); p4.y = __expf(mn - x.y);
  p4.z = __expf(mn - x.z); p4.w = __expf(mn - x.w);
  float s = (p4.x + p4.y) + (p4.z + p4.w);
  for (int o = 32; o; o >>= 1) s += __shfl_xor(s, o);
  const float inv = 1.0f / s;
  p4.x *= inv; p4.y *= inv; p4.z *= inv; p4.w *= inv;
  ((float4*)(part + base))[lane] = p4;
}

// ----------------------------------------------------- A(256x256) @ X GEMM
// MODE 0 (cam_out): OUT[c][n] = g*sum_d A[c][d] X[d][n] + X[c][n]
// MODE 1 (pam_V):   OUT[d][n] = sum_c Wv[d][c] X[c][n] + bv[d]
// Tile M=256 x N=128, 512 threads, grid (50, BB). X read once.
// R12: B-staging = per-thread (row, k-octet): 8 coalesced scalar loads down
// the c-column + 4 ushort4 stores (was 16 scalar ushort stores -> conflicts).
template <int MODE>
__global__ __launch_bounds__(512) void ax_k(const float* __restrict__ Abase, int Astride,
                                            const float* __restrict__ X,
                                            float* __restrict__ OUT,
                                            const float* __restrict__ bvec,
                                            const float* __restrict__ gsc) {
  const int nt = blockIdx.x;
  const int b = blockIdx.y;
  const float* A = Abase + (size_t)b * Astride;
  const float* Xb = X + (size_t)b * CH * HW;
  float* OUTb = OUT + (size_t)b * CH * HW;
  const int nbase = nt * 128;
  __shared__ unsigned short lds[(256 + 128) * 64];  // A 32KB + B 16KB
  char* Ab = (char*)lds;
  char* Bb = (char*)lds + 32768;
  const int tid = threadIdx.x, lane = tid & 63, w = tid >> 6;
  const int wr = w >> 1, wc = w & 1;             // 4 x 2 waves -> 64x64 each
  const int r0 = tid >> 1, kq = tid & 1;         // A staging: 4 float4/thread
  const int n_r = tid & 127, kg = tid >> 7;      // B staging: row + k-octet
  const float* Xcol = Xb + nbase + n_r;          // column base for B loads
  f32x4 acc[4][4] = {};
  float4 ra[4];
  float vb8[8];
#pragma unroll
  for (int q = 0; q < 4; ++q)
    ra[q] = *(const float4*)(A + (size_t)r0 * 256 + kq * 16 + q * 4);
#pragma unroll
  for (int e = 0; e < 8; ++e)
    vb8[e] = Xcol[(size_t)(kg * 8 + e) * HW];
  for (int s = 0; s < 8; ++s) {
#pragma unroll
    for (int q = 0; q < 4; ++q) {
      ushort4 h4, l4;
      cvt4(ra[q], h4, l4);
      *(ushort4*)(Ab + lds_off(r0, 0, kq * 32 + q * 8)) = h4;
      *(ushort4*)(Ab + lds_off(r0, 1, kq * 32 + q * 8)) = l4;
    }
    {
      unsigned short bh[8], bl[8];
#pragma unroll
      for (int e = 0; e < 8; ++e) cvt2(vb8[e], bh[e], bl[e]);
      ushort4 u;
      u = make_ushort4(bh[0], bh[1], bh[2], bh[3]);
      *(ushort4*)(Bb + lds_off(n_r, 0, kg * 16)) = u;
      u = make_ushort4(bh[4], bh[5], bh[6], bh[7]);
      *(ushort4*)(Bb + lds_off(n_r, 0, kg * 16 + 8)) = u;
      u = make_ushort4(bl[0], bl[1], bl[2], bl[3]);
      *(ushort4*)(Bb + lds_off(n_r, 1, kg * 16)) = u;
      u = make_ushort4(bl[4], bl[5], bl[6], bl[7]);
      *(ushort4*)(Bb + lds_off(n_r, 1, kg * 16 + 8)) = u;
    }
    __syncthreads();
    if (s < 7) {
      int k0 = (s + 1) * 32;
#pragma unroll
      for (int q = 0; q < 4; ++q)
        ra[q] = *(const float4*)(A + (size_t)r0 * 256 + k0 + kq * 16 + q * 4);
#pragma unroll
      for (int e = 0; e < 8; ++e)
        vb8[e] = Xcol[(size_t)(k0 + kg * 8 + e) * HW];
    }
    bf16x8 bfr[2][4];
#pragma unroll
    for (int h = 0; h < 2; ++h)
#pragma unroll
      for (int n = 0; n < 4; ++n)
        bfr[h][n] = frag_ld(Bb, wc * 64 + n * 16 + (lane & 15), h, lane);
#pragma unroll
    for (int m = 0; m < 4; ++m) {
      int arow = wr * 64 + m * 16 + (lane & 15);
      bf16x8 a0 = frag_ld(Ab, arow, 0, lane);
      bf16x8 a1 = frag_ld(Ab, arow, 1, lane);
#pragma unroll
      for (int n = 0; n < 4; ++n)
        acc[m][n] = __builtin_amdgcn_mfma_f32_16x16x32_bf16(a0, bfr[0][n], acc[m][n], 0, 0, 0);
#pragma unroll
      for (int n = 0; n < 4; ++n)
        acc[m][n] = __builtin_amdgcn_mfma_f32_16x16x32_bf16(a0, bfr[1][n], acc[m][n], 0, 0, 0);
#pragma unroll
      for (int n = 0; n < 4; ++n)
        acc[m][n] = __builtin_amdgcn_mfma_f32_16x16x32_bf16(a1, bfr[0][n], acc[m][n], 0, 0, 0);
    }
    __syncthreads();
  }
  float g = 0.f;
  if (MODE == 0) g = gsc[0];
#pragma unroll
  for (int m = 0; m < 4; ++m)
#pragma unroll
    for (int n = 0; n < 4; ++n) {
      int row = wr * 64 + m * 16 + ((lane >> 4) << 2);
      int col = nbase + wc * 64 + n * 16 + (lane & 15);
#pragma unroll
      for (int r2 = 0; r2 < 4; ++r2) {
        size_t o = (size_t)(row + r2) * HW + col;
        float v = acc[m][n][r2];
        if (MODE == 0) OUTb[o] = g * v + Xb[o];
        else           OUTb[o] = v + bvec[row + r2];
      }
    }
}

// ------------------------------------------------------------ PAM q/k GEMM
// Full-image 1x1 conv: rows 0..31 = Wq, 32..63 = Wk; N = 6400, K = 256.
// Outputs: qt[b][n][32] (n-major, +bq), kf[b][32][n] (+bk). split-bf16.
__global__ __launch_bounds__(256) void qk_k(const float* __restrict__ X,
                                            const float* __restrict__ Wq,
                                            const float* __restrict__ bq,
                                            const float* __restrict__ Wk,
                                            const float* __restrict__ bk,
                                            float* __restrict__ qt,
                                            float* __restrict__ kf) {
  const int nbase = blockIdx.x * 256;
  const int b = blockIdx.y;
  const float* Xb = X + (size_t)b * CH * HW;
  __shared__ unsigned short lds[(64 + 256) * 64];  // A 8KB + B 32KB
  char* Ab = (char*)lds;
  char* Bb = (char*)lds + 8192;
  const int tid = threadIdx.x, lane = tid & 63, w = tid >> 6;
  const int ar = tid >> 2, akq = tid & 3;          // A staging
  const int n4 = (tid & 63) * 4, c0l = tid >> 6;   // B staging (256 rows)
  const float* Arow = (ar < 32) ? (Wq + (size_t)ar * CH) : (Wk + (size_t)(ar - 32) * CH);
  f32x4 acc[4][4] = {};
  float4 va[2], vb[8];
#pragma unroll
  for (int q = 0; q < 2; ++q)
    va[q] = *(const float4*)(Arow + akq * 8 + q * 4);
#pragma unroll
  for (int q = 0; q < 8; ++q)
    vb[q] = *(const float4*)(Xb + (size_t)(c0l + 4 * q) * HW + nbase + n4);
  for (int s = 0; s < 8; ++s) {
    __syncthreads();   // prev iter's frag reads done
#pragma unroll
    for (int q = 0; q < 2; ++q) {
      ushort4 h4, l4;
      cvt4(va[q], h4, l4);
      *(ushort4*)(Ab + lds_off(ar, 0, akq * 16 + q * 8)) = h4;
      *(ushort4*)(Ab + lds_off(ar, 1, akq * 16 + q * 8)) = l4;
    }
#pragma unroll
    for (int q = 0; q < 8; ++q) {
      int cc = c0l + 4 * q;
      float4 v = vb[q];
#pragma unroll
      for (int jj = 0; jj < 4; ++jj) {
        int j = (jj + tid) & 3;
        float e = (j == 0) ? v.x : (j == 1) ? v.y : (j == 2) ? v.z : v.w;
        unsigned short h, l;
        cvt2(e, h, l);
        int row = n4 + j;
        *(unsigned short*)(Bb + lds_off(row, 0, cc * 2)) = h;
        *(unsigned short*)(Bb + lds_off(row, 1, cc * 2)) = l;
      }
    }
    __syncthreads();
    float4 na[2], nb[8];
    if (s < 7) {
      const int k0 = (s + 1) * 32;
#pragma unroll
      for (int q = 0; q < 2; ++q)
        na[q] = *(const float4*)(Arow + k0 + akq * 8 + q * 4);
#pragma unroll
      for (int q = 0; q < 8; ++q)
        nb[q] = *(const float4*)(Xb + (size_t)(k0 + c0l + 4 * q) * HW + nbase + n4);
    }
    bf16x8 bfr[2][4];
#pragma unroll
    for (int h = 0; h < 2; ++h)
#pragma unroll
      for (int n = 0; n < 4; ++n)
        bfr[h][n] = frag_ld(Bb, w * 64 + n * 16 + (lane & 15), h, lane);
#pragma unroll
    for (int m = 0; m < 4; ++m) {
      int arow2 = m * 16 + (lane & 15);
      bf16x8 a0 = frag_ld(Ab, arow2, 0, lane);
      bf16x8 a1 = frag_ld(Ab, arow2, 1, lane);
#pragma unroll
      for (int n = 0; n < 4; ++n)
        acc[m][n] = __builtin_amdgcn_mfma_f32_16x16x32_bf16(a0, bfr[0][n], acc[m][n], 0, 0, 0);
#pragma unroll
      for (int n = 0; n < 4; ++n)
        acc[m][n] = __builtin_amdgcn_mfma_f32_16x16x32_bf16(a0, bfr[1][n], acc[m][n], 0, 0, 0);
#pragma unroll
      for (int n = 0; n < 4; ++n)
        acc[m][n] = __builtin_amdgcn_mfma_f32_16x16x32_bf16(a1, bfr[0][n], acc[m][n], 0, 0, 0);
    }
#pragma unroll
    for (int q = 0; q < 2; ++q) va[q] = na[q];
#pragma unroll
    for (int q = 0; q < 8; ++q) vb[q] = nb[q];
  }
#pragma unroll
  for (int m = 0; m < 4; ++m)
#pragma unroll
    for (int n = 0; n < 4; ++n) {
      int row = m * 16 + ((lane >> 4) << 2);
      int col = nbase + w * 64 + n * 16 + (lane & 15);
#pragma unroll
      for (int r2 = 0; r2 < 4; ++r2) {
        int rr = row + r2;
        float v = acc[m][n][r2];
        if (rr < 32) qt[((size_t)b * HW + col) * 32 + rr] = v + bq[rr];
        else         kf[((size_t)b * 32 + (rr - 32)) * HW + col] = v + bk[rr - 32];
      }
    }
}

// --------------------------------------------------- PAM energy + softmax
__global__ __launch_bounds__(256) void pam_es_k(const float* __restrict__ qt,
                                                const float* __restrict__ kf,
                                                float* __restrict__ Pbuf) {
  const int ccb = blockIdx.x;
  const int ck = ccb >> 4, b = ccb & 15;
  const int gi = ck / 5, gj = ck % 5;
  const int pbase = gi * 16 * IMW + gj * 16;
  float* Pc = Pbuf + (size_t)ccb * 65536;
  __shared__ float qs[256][32];
  __shared__ float S[32][256];
  const int tid = threadIdx.x;
  const float* qb = qt + (size_t)b * HW * 32;
#pragma unroll
  for (int qq = 0; qq < 8; ++qq) {
    int j = (tid >> 3) + 32 * qq;
    int nj = pbase + (j >> 4) * IMW + (j & 15);
    float4 v = *(const float4*)(qb + (size_t)nj * 32 + (tid & 7) * 4);
    *(float4*)&qs[j][(tid & 7) * 4] = v;
  }
  const int nt = pbase + (tid >> 4) * IMW + (tid & 15);
  const float* kb = kf + (size_t)b * 32 * HW;
  float kc[32];
#pragma unroll
  for (int kk = 0; kk < 32; ++kk) kc[kk] = kb[(size_t)kk * HW + nt];
  __syncthreads();
  const int w = tid >> 6, lane = tid & 63;
  for (int p = 0; p < 8; ++p) {
#pragma unroll 4
    for (int j2 = 0; j2 < 32; ++j2) {
      int row = p * 32 + j2;
      float s = 0.f;
#pragma unroll
      for (int k8 = 0; k8 < 8; ++k8) {
        float4 qv = *(const float4*)&qs[row][k8 * 4];
        s = fmaf(qv.x, kc[k8 * 4 + 0], s);
        s = fmaf(qv.y, kc[k8 * 4 + 1], s);
        s = fmaf(qv.z, kc[k8 * 4 + 2], s);
        s = fmaf(qv.w, kc[k8 * 4 + 3], s);
      }
      S[j2][tid] = s;
    }
    __syncthreads();
#pragma unroll
    for (int rr = 0; rr < 8; ++rr) {
      int jj = w * 8 + rr;
      float4 v = *(const float4*)&S[jj][lane << 2];
      float m = fmaxf(fmaxf(v.x, v.y), fmaxf(v.z, v.w));
      for (int o = 32; o; o >>= 1) m = fmaxf(m, __shfl_xor(m, o));
      float4 pv;
      pv.x = __expf(v.x - m); pv.y = __expf(v.y - m);
      pv.z = __expf(v.z - m); pv.w = __expf(v.w - m);
      float s = (pv.x + pv.y) + (pv.z + pv.w);
      for (int o = 32; o; o >>= 1) s += __shfl_xor(s, o);
      const float inv = 1.f / s;
      pv.x *= inv; pv.y *= inv; pv.z *= inv; pv.w *= inv;
      *(float4*)&Pc[(size_t)(p * 32 + jj) * 256 + (lane << 2)] = pv;
    }
    __syncthreads();
  }
}

// ---------------------------------------------------------------- PAM PV
// One 512-thr block per ccb: out[d][j] = g*sum_n V[d][n] P[j][n] + X[d][n(j)],
// written over P[ccb] after all reads complete. Register-prefetch pipeline.
__global__ __launch_bounds__(512) void pam_pv_k(float* __restrict__ P,
                                                const float* __restrict__ V,
                                                const float* __restrict__ fS,
                                                const float* __restrict__ fT,
                                                const float* __restrict__ gsc, int t) {
  const int ccb = blockIdx.x;
  const int ck = ccb >> 4, b = ccb & 15;
  const int gi = ck / 5, gj = ck % 5;
  const float* Xb = (t ? fT : fS) + (size_t)b * CH * HW;
  const float* Vb = V + (size_t)b * CH * HW;
  float* Pc = P + (size_t)ccb * 65536;
  __shared__ unsigned short lds[2 * 256 * 64];
  char* Ab = (char*)lds;
  char* Bb = (char*)lds + 32768;
  const int tid = threadIdx.x, lane = tid & 63, w = tid >> 6;
  const int wr = w >> 2, wc = w & 3;
  const int r0 = tid >> 3, kq = tid & 7;
  const int pbase = gi * 16 * IMW + gj * 16;
  f32x4 acc[8][4] = {};
  float4 va[4], vb[4];
  {
    int jj = kq * 4;
    int ngl = pbase + (jj >> 4) * IMW + (jj & 15);
#pragma unroll
    for (int q = 0; q < 4; ++q) {
      int rr = r0 + 64 * q;
      va[q] = *(const float4*)(Vb + (size_t)rr * HW + ngl);
      vb[q] = *(const float4*)(Pc + (size_t)rr * 256 + kq * 4);
    }
  }
  for (int s = 0; s < 8; ++s) {
    __syncthreads();   // prev iter's frag reads done
#pragma unroll
    for (int q = 0; q < 4; ++q) {
      int rr = r0 + 64 * q;
      ushort4 h4, l4;
      cvt4(va[q], h4, l4);
      *(ushort4*)(Ab + lds_off(rr, 0, kq * 8)) = h4;
      *(ushort4*)(Ab + lds_off(rr, 1, kq * 8)) = l4;
      cvt4(vb[q], h4, l4);
      *(ushort4*)(Bb + lds_off(rr, 0, kq * 8)) = h4;
      *(ushort4*)(Bb + lds_off(rr, 1, kq * 8)) = l4;
    }
    __syncthreads();
    float4 na[4], nb[4];
    if (s < 7) {
      int k0 = (s + 1) * 32;
      int jj = k0 + kq * 4;
      int ngl = pbase + (jj >> 4) * IMW + (jj & 15);
#pragma unroll
      for (int q = 0; q < 4; ++q) {
        int rr = r0 + 64 * q;
        na[q] = *(const float4*)(Vb + (size_t)rr * HW + ngl);
        nb[q] = *(const float4*)(Pc + (size_t)rr * 256 + k0 + kq * 4);
      }
    }
    bf16x8 bfr[2][4];
#pragma unroll
    for (int h = 0; h < 2; ++h)
#pragma unroll
      for (int n = 0; n < 4; ++n)
        bfr[h][n] = frag_ld(Bb, wc * 64 + n * 16 + (lane & 15), h, lane);
#pragma unroll
    for (int m = 0; m < 8; ++m) {
      int arow = wr * 128 + m * 16 + (lane & 15);
      bf16x8 a0 = frag_ld(Ab, arow, 0, lane);
      bf16x8 a1 = frag_ld(Ab, arow, 1, lane);
#pragma unroll
      for (int n = 0; n < 4; ++n)
        acc[m][n] = __builtin_amdgcn_mfma_f32_16x16x32_bf16(a0, bfr[0][n], acc[m][n], 0, 0, 0);
#pragma unroll
      for (int n = 0; n < 4; ++n)
        acc[m][n] = __builtin_amdgcn_mfma_f32_16x16x32_bf16(a0, bfr[1][n], acc[m][n], 0, 0, 0);
#pragma unroll
      for (int n = 0; n < 4; ++n)
        acc[m][n] = __builtin_amdgcn_mfma_f32_16x16x32_bf16(a1, bfr[0][n], acc[m][n], 0, 0, 0);
    }
#pragma unroll
    for (int q = 0; q < 4; ++q) { va[q] = na[q]; vb[q] = nb[q]; }
  }
  const float g = gsc[0];
#pragma unroll
  for (int m = 0; m < 8; ++m)
#pragma unroll
    for (int n = 0; n < 4; ++n) {
      int row = wr * 128 + m * 16 + ((lane >> 4) << 2);
      int col = wc * 64 + n * 16 + (lane & 15);
      int ngl = pbase + (col >> 4) * IMW + (col & 15);
#pragma unroll
      for (int r2 = 0; r2 < 4; ++r2) {
        float v = g * acc[m][n][r2] + Xb[(size_t)(row + r2) * HW + ngl];
        Pc[(size_t)(row + r2) * 256 + col] = v;
      }
    }
}

// ------------------------------------------------------------- gram (MFMA)
__global__ __launch_bounds__(256) void gram_mfma_k(const float* __restrict__ Z,
                                                   size_t gStride, size_t bStride,
                                                   double* __restrict__ G) {
  const int tid = threadIdx.x, lane = tid & 63, w = tid >> 6;
  const float* Zg = Z + (size_t)blockIdx.y * gStride;
  const float* p = Zg + (size_t)(lane & 15) * bStride +
                   (size_t)blockIdx.x * 4096 + w * 1024 + ((lane >> 4) << 3);
  f32x4 acc = {};
#pragma unroll 4
  for (int s = 0; s < 32; ++s) {
    float4 v0 = *(const float4*)(p + s * 32);
    float4 v1 = *(const float4*)(p + s * 32 + 4);
    bf16x8 hi, lo;
    cvt8(v0, v1, hi, lo);
    acc = __builtin_amdgcn_mfma_f32_16x16x32_bf16(hi, hi, acc, 0, 0, 0);
    acc = __builtin_amdgcn_mfma_f32_16x16x32_bf16(hi, lo, acc, 0, 0, 0);
    acc = __builtin_amdgcn_mfma_f32_16x16x32_bf16(lo, hi, acc, 0, 0, 0);
  }
  double* Gt = G + (size_t)blockIdx.y * 256;
  const int col = lane & 15, row0 = (lane >> 4) << 2;
#pragma unroll
  for (int i = 0; i < 4; ++i)
    atomicAdd(&Gt[(size_t)(row0 + i) * 16 + col], (double)acc[i]);
}

// -------------------------------------------------------------- CKA pairs
__global__ __launch_bounds__(256) void cka_pair_k(const double* __restrict__ G,
                                                  double* __restrict__ losses) {
  const int q = blockIdx.x;
  const double* KX = (q == 0) ? G : G + 512 + (size_t)(q - 1) * 256;
  const double* KY = (q == 0) ? G + 256 : G + 512 + 6400 + (size_t)(q - 1) * 256;
  __shared__ double red[256];
  __shared__ double srm[16], scm[16];
  __shared__ double stm;
  const int tid = threadIdx.x;
  const int r = tid >> 4, c = tid & 15;

  auto center = [&](double k) -> double {
    red[tid] = k;
    __syncthreads();
    for (int off = 8; off; off >>= 1) {
      if (c < off) red[tid] += red[tid + off];
      __syncthreads();
    }
    if (c == 0) srm[r] = red[tid] * (1.0 / 16.0);
    __syncthreads();
    red[c * 16 + r] = k;
    __syncthreads();
    for (int off = 8; off; off >>= 1) {
      if (r < off) red[c * 16 + r] += red[c * 16 + r + off];
      __syncthreads();
    }
    if (r == 0) scm[c] = red[c * 16] * (1.0 / 16.0);
    __syncthreads();
    if (tid == 0) {
      double s = 0.0;
      for (int i = 0; i < 16; ++i) s += srm[i];
      stm = s * (1.0 / 16.0);
    }
    __syncthreads();
    double v = k - srm[r] - scm[c] + stm;
    __syncthreads();
    return v;
  };
  auto reduce_sum = [&](double v) -> double {
    red[tid] = v;
    __syncthreads();
    for (int off = 128; off; off >>= 1) {
      if (tid < off) red[tid] += red[tid + off];
      __syncthreads();
    }
    double s = red[0];
    __syncthreads();
    return s;
  };
  double cx = center(KX[tid]);
  double cy = center(KY[tid]);
  double h = reduce_sum(cx * cy);
  double v1 = reduce_sum(cx * cx);
  double v2 = reduce_sum(cy * cy);
  if (tid == 0) losses[q] = -log(fabs(h / (sqrt(v1) * sqrt(v2))) + 1e-8);
}

__global__ void cka_combine_k(const double* __restrict__ losses,
                              float* __restrict__ out) {
  if (threadIdx.x == 0) {
    out[0] = (float)losses[0];
    double s = 0.0;
    for (int q = 1; q <= 25; ++q) s += losses[q];
    out[1] = (float)(s * (1.0 / 25.0));
  }
}

extern "C" void kernel_launch(void* const* d_in, const int* in_sizes, int n_in,
                              void* d_out, int out_size, void* d_ws, size_t ws_size,
                              hipStream_t stream) {
  (void)in_sizes; (void)n_in; (void)out_size; (void)ws_size;
  const float* fS = (const float*)d_in[0];
  const float* fT = (const float*)d_in[1];
  const float* Wq = (const float*)d_in[2];
  const float* bq = (const float*)d_in[3];
  const float* Wk = (const float*)d_in[4];
  const float* bk = (const float*)d_in[5];
  const float* Wv = (const float*)d_in[6];
  const float* bv = (const float*)d_in[7];
  const float* gcam = (const float*)d_in[8];
  const float* gpam = (const float*)d_in[9];
  float* out = (float*)d_out;

  float* buf0 = (float*)d_ws;              // 26214400 floats
  float* buf1 = buf0 + 26214400;           // 26214400 floats
  double* G = (double*)(buf1 + 26214400);  // 13312 doubles
  float* Pbuf = buf1;                      // 400*65536
  float* qt = buf0;                        // 16*6400*32
  float* kf = buf0 + 3276800;              // 16*32*6400
  double* losses = (double*)buf0;          // 26 doubles, dead region at CKA time

  hipMemsetAsync(G, 0, 13312 * sizeof(double), stream);

  // ---- CAM ----
  cam_energy_k<<<dim3(8, 16, 2), 512, 0, stream>>>(fS, fT, buf1);
  cam_softmax_k<<<dim3(256, 16, 2), 64, 0, stream>>>(buf1);
  for (int t = 0; t < 2; ++t) {
    ax_k<0><<<dim3(50, 16), 512, 0, stream>>>(buf1 + (size_t)t * BB * 65536, 65536,
                                              t ? fT : fS, buf0, nullptr, gcam);
    gram_mfma_k<<<dim3(400, 1), 256, 0, stream>>>(buf0, (size_t)0, (size_t)1638400,
                                                  G + t * 256);
  }
  // ---- PAM ----
  for (int t = 0; t < 2; ++t) {
    const float* X = t ? fT : fS;
    qk_k<<<dim3(25, 16), 256, 0, stream>>>(X, Wq, bq, Wk, bk, qt, kf);
    pam_es_k<<<dim3(400), 256, 0, stream>>>(qt, kf, Pbuf);
    ax_k<1><<<dim3(50, 16), 512, 0, stream>>>(Wv, 0, X, buf0, bv, nullptr);
    pam_pv_k<<<dim3(400), 512, 0, stream>>>(Pbuf, buf0, fS, fT, gpam, t);
    gram_mfma_k<<<dim3(16, 25), 256, 0, stream>>>(Pbuf, (size_t)1048576, (size_t)65536,
                                                  G + 512 + t * 6400);
  }
  cka_pair_k<<<dim3(26), 256, 0, stream>>>(G, losses);
  cka_combine_k<<<dim3(1), 64, 0, stream>>>(losses, out);
}

// Round 13
// 1000.975 us; speedup vs baseline: 2.9438x; 1.0548x over previous
//
#include <hip/hip_runtime.h>

// CriterionSA: CAM + grid-PAM + CKA loss.
// GEMMs in split-bf16 MFMA (hi/lo, 3 MFMAs: hh+hl+lh); cam_energy plain bf16
// (softmax saturated). Grams via MFMA split-bf16; fp32 acc -> fp64 atomics.
// CKA fp64, 26 parallel blocks.
// R13: wave-widening for occupancy/BW: cam_energy + ax_k -> 1024-thr blocks,
// 16 waves, quarter accumulators (<=128 regs enforced by launch_bounds);
// ax_k also double-buffered LDS (96KB, 1 barrier/step).
// ws layout (floats): buf0[26214400] | buf1[26214400] | G[13312 doubles]
// required ws = 209,821,696 bytes (~200.1 MiB) -- same as rounds 1-12.

typedef short bf16x8 __attribute__((ext_vector_type(8)));
typedef float f32x4 __attribute__((ext_vector_type(4)));

constexpr int BB = 16;    // batch
constexpr int CH = 256;   // channels
constexpr int HW = 6400;  // 80*80
constexpr int IMW = 80;

__device__ __forceinline__ int lds_off(int row, int half, int k2) {
  return row * 128 + ((((half << 6)) | k2) ^ ((row & 7) << 4));
}

__device__ __forceinline__ bf16x8 frag_ld(const char* base, int row, int half, int lane) {
  int off = row * 128 + ((((half << 6)) | ((lane >> 4) << 4)) ^ ((lane & 7) << 4));
  return *(const bf16x8*)(base + off);
}

__device__ __forceinline__ void cvt2(float x, unsigned short& h, unsigned short& l) {
  unsigned u = __float_as_uint(x);
  h = (unsigned short)(u >> 16);                       // truncated hi
  float r = x - __uint_as_float(u & 0xffff0000u);
  l = (unsigned short)(__float_as_uint(r) >> 16);      // truncated residual
}

__device__ __forceinline__ void cvt4(float4 v, ushort4& h, ushort4& l) {
  cvt2(v.x, h.x, l.x); cvt2(v.y, h.y, l.y);
  cvt2(v.z, h.z, l.z); cvt2(v.w, h.w, l.w);
}

__device__ __forceinline__ void cvt8(float4 v0, float4 v1, bf16x8& hi, bf16x8& lo) {
  unsigned short h, l;
  cvt2(v0.x, h, l); hi[0] = (short)h; lo[0] = (short)l;
  cvt2(v0.y, h, l); hi[1] = (short)h; lo[1] = (short)l;
  cvt2(v0.z, h, l); hi[2] = (short)h; lo[2] = (short)l;
  cvt2(v0.w, h, l); hi[3] = (short)h; lo[3] = (short)l;
  cvt2(v1.x, h, l); hi[4] = (short)h; lo[4] = (short)l;
  cvt2(v1.y, h, l); hi[5] = (short)h; lo[5] = (short)l;
  cvt2(v1.z, h, l); hi[6] = (short)h; lo[6] = (short)l;
  cvt2(v1.w, h, l); hi[7] = (short)h; lo[7] = (short)l;
}

__device__ __forceinline__ unsigned short bf_rnd(float x) {
  unsigned u = __float_as_uint(x);
  return (unsigned short)((u + 0x8000u) >> 16);
}

// ---------------------------------------------------------------- CAM energy
// Partial E[kc][t][b] = X(:,kslice) X(:,kslice)^T, kc=0..7 (K=800 each,
// 12 x 64 + zero-padded 32 tail). Grid = 256 blocks, 1024 thr (16 waves of
// 64x64 -> acc[4][4]). One LDS panel is both MFMA operands. Double-buffered.
__global__ __launch_bounds__(1024) void cam_energy_k(const float* __restrict__ fS,
                                                     const float* __restrict__ fT,
                                                     float* __restrict__ part) {
  const int kc = blockIdx.x, b = blockIdx.y, t = blockIdx.z;
  const float* X = (t ? fT : fS) + (size_t)b * CH * HW;
  __shared__ unsigned short lds[2 * 256 * 64];  // 2 x 32 KB panels
  const int tid = threadIdx.x, lane = tid & 63, w = tid >> 6;
  const int wr = w >> 2, wc = w & 3;            // 4x4 waves -> 64x64 each
  const int r0 = tid >> 2, kq = tid & 3;        // staging: 4 float4/thread
  const int half = kq >> 1, k2b = (kq & 1) * 32;
  const float* Xr = X + (size_t)r0 * HW + kc * 800 + kq * 16;
  f32x4 acc[4][4] = {};
  float4 v[4];
#pragma unroll
  for (int q = 0; q < 4; ++q) v[q] = *(const float4*)(Xr + q * 4);
  for (int it = 0; it < 13; ++it) {
    char* pb = (char*)lds + (it & 1) * 32768;
#pragma unroll
    for (int q = 0; q < 4; ++q) {
      ushort4 u;
      u.x = bf_rnd(v[q].x); u.y = bf_rnd(v[q].y);
      u.z = bf_rnd(v[q].z); u.w = bf_rnd(v[q].w);
      *(ushort4*)(pb + lds_off(r0, half, k2b + q * 8)) = u;
    }
    __syncthreads();
    float4 nv[4];
    if (it < 12) {
      const int nk = (it + 1) * 64;
      if (nk + kq * 16 < 800) {
        const float* Xn = Xr + nk;
#pragma unroll
        for (int q = 0; q < 4; ++q) nv[q] = *(const float4*)(Xn + q * 4);
      } else {
#pragma unroll
        for (int q = 0; q < 4; ++q) nv[q] = make_float4(0.f, 0.f, 0.f, 0.f);
      }
    }
#pragma unroll
    for (int h = 0; h < 2; ++h) {
      bf16x8 bh[4];
#pragma unroll
      for (int n = 0; n < 4; ++n)
        bh[n] = frag_ld(pb, wc * 64 + n * 16 + (lane & 15), h, lane);
#pragma unroll
      for (int m = 0; m < 4; ++m) {
        bf16x8 a = frag_ld(pb, wr * 64 + m * 16 + (lane & 15), h, lane);
#pragma unroll
        for (int n = 0; n < 4; ++n)
          acc[m][n] = __builtin_amdgcn_mfma_f32_16x16x32_bf16(a, bh[n], acc[m][n], 0, 0, 0);
      }
    }
#pragma unroll
    for (int q = 0; q < 4; ++q) v[q] = nv[q];
  }
  float* Eb = part + (((size_t)kc * 2 + t) * BB + b) * 65536;
#pragma unroll
  for (int m = 0; m < 4; ++m)
#pragma unroll
    for (int n = 0; n < 4; ++n) {
      int row = wr * 64 + m * 16 + ((lane >> 4) << 2);
      int col = wc * 64 + n * 16 + (lane & 15);
#pragma unroll
      for (int r2 = 0; r2 < 4; ++r2)
        Eb[(size_t)(row + r2) * 256 + col] = acc[m][n][r2];
    }
}

// ------------------------------------------------------------- CAM softmax
// attn = exp(rowmin - sum_p partE[p]) / rowsum, written into partial 0.
__global__ __launch_bounds__(64) void cam_softmax_k(float* __restrict__ part) {
  const int c = blockIdx.x, b = blockIdx.y, t = blockIdx.z;
  const size_t base = (((size_t)t * BB + b) * CH + c) * CH;
  const int lane = threadIdx.x;
  float4 x = make_float4(0.f, 0.f, 0.f, 0.f);
#pragma unroll
  for (int p = 0; p < 8; ++p) {
    float4 y = ((const float4*)(part + (size_t)p * 2097152 + base))[lane];
    x.x += y.x; x.y += y.y; x.z += y.z; x.w += y.w;
  }
  float mn = fminf(fminf(x.x, x.y), fminf(x.z, x.w));
  for (int o = 32; o; o >>= 1) mn = fminf(mn, __shfl_xor(mn, o));
  float4 p4;
  p4.x = __expf(mn - x.x); p4.y = __expf(mn - x.y);
  p4.z = __expf(mn - x.z); p4.w = __expf(mn - x.w);
  float s = (p4.x + p4.y) + (p4.z + p4.w);
  for (int o = 32; o; o >>= 1) s += __shfl_xor(s, o);
  const float inv = 1.0f / s;
  p4.x *= inv; p4.y *= inv; p4.z *= inv; p4.w *= inv;
  ((float4*)(part + base))[lane] = p4;
}

// ----------------------------------------------------- A(256x256) @ X GEMM
// MODE 0 (cam_out): OUT[c][n] = g*sum_d A[c][d] X[d][n] + X[c][n]
// MODE 1 (pam_V):   OUT[d][n] = sum_c Wv[d][c] X[c][n] + bv[d]
// R13: 1024 thr, 16 waves (4x4 of 64x32 -> acc[4][2]); tile M=256 x N=128;
// double-buffered LDS (96KB, 1 barrier/step). X read once.
template <int MODE>
__global__ __launch_bounds__(1024) void ax_k(const float* __restrict__ Abase, int Astride,
                                             const float* __restrict__ X,
                                             float* __restrict__ OUT,
                                             const float* __restrict__ bvec,
                                             const float* __restrict__ gsc) {
  const int nt = blockIdx.x;
  const int b = blockIdx.y;
  const float* A = Abase + (size_t)b * Astride;
  const float* Xb = X + (size_t)b * CH * HW;
  float* OUTb = OUT + (size_t)b * CH * HW;
  const int nbase = nt * 128;
  __shared__ unsigned short lds[2 * (256 + 128) * 64];  // dbuf x (A 32KB + B 16KB)
  const int tid = threadIdx.x, lane = tid & 63, w = tid >> 6;
  const int wr = w >> 2, wc = w & 3;             // 4x4 waves -> 64x32 each
  const int r0 = tid >> 2, kq = tid & 3;         // A staging: 2 float4/thread
  const int n_r = tid & 127, kg = tid >> 7;      // B staging: row + 4-k group
  const float* Xcol = Xb + nbase + n_r;
  f32x4 acc[4][2] = {};
  float4 ra[2];
  float vb4[4];
#pragma unroll
  for (int q = 0; q < 2; ++q)
    ra[q] = *(const float4*)(A + (size_t)r0 * 256 + kq * 8 + q * 4);
#pragma unroll
  for (int e = 0; e < 4; ++e)
    vb4[e] = Xcol[(size_t)(kg * 4 + e) * HW];
  for (int s = 0; s < 8; ++s) {
    char* Ab = (char*)lds + (s & 1) * 49152;
    char* Bb = Ab + 32768;
#pragma unroll
    for (int q = 0; q < 2; ++q) {
      ushort4 h4, l4;
      cvt4(ra[q], h4, l4);
      *(ushort4*)(Ab + lds_off(r0, 0, kq * 16 + q * 8)) = h4;
      *(ushort4*)(Ab + lds_off(r0, 1, kq * 16 + q * 8)) = l4;
    }
    {
      unsigned short bh[4], bl[4];
#pragma unroll
      for (int e = 0; e < 4; ++e) cvt2(vb4[e], bh[e], bl[e]);
      *(ushort4*)(Bb + lds_off(n_r, 0, kg * 8)) = make_ushort4(bh[0], bh[1], bh[2], bh[3]);
      *(ushort4*)(Bb + lds_off(n_r, 1, kg * 8)) = make_ushort4(bl[0], bl[1], bl[2], bl[3]);
    }
    __syncthreads();
    if (s < 7) {
      int k0 = (s + 1) * 32;
#pragma unroll
      for (int q = 0; q < 2; ++q)
        ra[q] = *(const float4*)(A + (size_t)r0 * 256 + k0 + kq * 8 + q * 4);
#pragma unroll
      for (int e = 0; e < 4; ++e)
        vb4[e] = Xcol[(size_t)(k0 + kg * 4 + e) * HW];
    }
    bf16x8 bfr[2][2];
#pragma unroll
    for (int h = 0; h < 2; ++h)
#pragma unroll
      for (int n = 0; n < 2; ++n)
        bfr[h][n] = frag_ld(Bb, wc * 32 + n * 16 + (lane & 15), h, lane);
#pragma unroll
    for (int m = 0; m < 4; ++m) {
      int arow = wr * 64 + m * 16 + (lane & 15);
      bf16x8 a0 = frag_ld(Ab, arow, 0, lane);
      bf16x8 a1 = frag_ld(Ab, arow, 1, lane);
#pragma unroll
      for (int n = 0; n < 2; ++n)
        acc[m][n] = __builtin_amdgcn_mfma_f32_16x16x32_bf16(a0, bfr[0][n], acc[m][n], 0, 0, 0);
#pragma unroll
      for (int n = 0; n < 2; ++n)
        acc[m][n] = __builtin_amdgcn_mfma_f32_16x16x32_bf16(a0, bfr[1][n], acc[m][n], 0, 0, 0);
#pragma unroll
      for (int n = 0; n < 2; ++n)
        acc[m][n] = __builtin_amdgcn_mfma_f32_16x16x32_bf16(a1, bfr[0][n], acc[m][n], 0, 0, 0);
    }
  }
  float g = 0.f;
  if (MODE == 0) g = gsc[0];
#pragma unroll
  for (int m = 0; m < 4; ++m)
#pragma unroll
    for (int n = 0; n < 2; ++n) {
      int row = wr * 64 + m * 16 + ((lane >> 4) << 2);
      int col = nbase + wc * 32 + n * 16 + (lane & 15);
#pragma unroll
      for (int r2 = 0; r2 < 4; ++r2) {
        size_t o = (size_t)(row + r2) * HW + col;
        float v = acc[m][n][r2];
        if (MODE == 0) OUTb[o] = g * v + Xb[o];
        else           OUTb[o] = v + bvec[row + r2];
      }
    }
}

// ------------------------------------------------------------ PAM q/k GEMM
// Full-image 1x1 conv: rows 0..31 = Wq, 32..63 = Wk; N = 6400, K = 256.
// Outputs: qt[b][n][32] (n-major, +bq), kf[b][32][n] (+bk). split-bf16.
__global__ __launch_bounds__(256) void qk_k(const float* __restrict__ X,
                                            const float* __restrict__ Wq,
                                            const float* __restrict__ bq,
                                            const float* __restrict__ Wk,
                                            const float* __restrict__ bk,
                                            float* __restrict__ qt,
                                            float* __restrict__ kf) {
  const int nbase = blockIdx.x * 256;
  const int b = blockIdx.y;
  const float* Xb = X + (size_t)b * CH * HW;
  __shared__ unsigned short lds[(64 + 256) * 64];  // A 8KB + B 32KB
  char* Ab = (char*)lds;
  char* Bb = (char*)lds + 8192;
  const int tid = threadIdx.x, lane = tid & 63, w = tid >> 6;
  const int ar = tid >> 2, akq = tid & 3;          // A staging
  const int n4 = (tid & 63) * 4, c0l = tid >> 6;   // B staging (256 rows)
  const float* Arow = (ar < 32) ? (Wq + (size_t)ar * CH) : (Wk + (size_t)(ar - 32) * CH);
  f32x4 acc[4][4] = {};
  float4 va[2], vb[8];
#pragma unroll
  for (int q = 0; q < 2; ++q)
    va[q] = *(const float4*)(Arow + akq * 8 + q * 4);
#pragma unroll
  for (int q = 0; q < 8; ++q)
    vb[q] = *(const float4*)(Xb + (size_t)(c0l + 4 * q) * HW + nbase + n4);
  for (int s = 0; s < 8; ++s) {
    __syncthreads();   // prev iter's frag reads done
#pragma unroll
    for (int q = 0; q < 2; ++q) {
      ushort4 h4, l4;
      cvt4(va[q], h4, l4);
      *(ushort4*)(Ab + lds_off(ar, 0, akq * 16 + q * 8)) = h4;
      *(ushort4*)(Ab + lds_off(ar, 1, akq * 16 + q * 8)) = l4;
    }
#pragma unroll
    for (int q = 0; q < 8; ++q) {
      int cc = c0l + 4 * q;
      float4 v = vb[q];
#pragma unroll
      for (int jj = 0; jj < 4; ++jj) {
        int j = (jj + tid) & 3;
        float e = (j == 0) ? v.x : (j == 1) ? v.y : (j == 2) ? v.z : v.w;
        unsigned short h, l;
        cvt2(e, h, l);
        int row = n4 + j;
        *(unsigned short*)(Bb + lds_off(row, 0, cc * 2)) = h;
        *(unsigned short*)(Bb + lds_off(row, 1, cc * 2)) = l;
      }
    }
    __syncthreads();
    float4 na[2], nb[8];
    if (s < 7) {
      const int k0 = (s + 1) * 32;
#pragma unroll
      for (int q = 0; q < 2; ++q)
        na[q] = *(const float4*)(Arow + k0 + akq * 8 + q * 4);
#pragma unroll
      for (int q = 0; q < 8; ++q)
        nb[q] = *(const float4*)(Xb + (size_t)(k0 + c0l + 4 * q) * HW + nbase + n4);
    }
    bf16x8 bfr[2][4];
#pragma unroll
    for (int h = 0; h < 2; ++h)
#pragma unroll
      for (int n = 0; n < 4; ++n)
        bfr[h][n] = frag_ld(Bb, w * 64 + n * 16 + (lane & 15), h, lane);
#pragma unroll
    for (int m = 0; m < 4; ++m) {
      int arow2 = m * 16 + (lane & 15);
      bf16x8 a0 = frag_ld(Ab, arow2, 0, lane);
      bf16x8 a1 = frag_ld(Ab, arow2, 1, lane);
#pragma unroll
      for (int n = 0; n < 4; ++n)
        acc[m][n] = __builtin_amdgcn_mfma_f32_16x16x32_bf16(a0, bfr[0][n], acc[m][n], 0, 0, 0);
#pragma unroll
      for (int n = 0; n < 4; ++n)
        acc[m][n] = __builtin_amdgcn_mfma_f32_16x16x32_bf16(a0, bfr[1][n], acc[m][n], 0, 0, 0);
#pragma unroll
      for (int n = 0; n < 4; ++n)
        acc[m][n] = __builtin_amdgcn_mfma_f32_16x16x32_bf16(a1, bfr[0][n], acc[m][n], 0, 0, 0);
    }
#pragma unroll
    for (int q = 0; q < 2; ++q) va[q] = na[q];
#pragma unroll
    for (int q = 0; q < 8; ++q) vb[q] = nb[q];
  }
#pragma unroll
  for (int m = 0; m < 4; ++m)
#pragma unroll
    for (int n = 0; n < 4; ++n) {
      int row = m * 16 + ((lane >> 4) << 2);
      int col = nbase + w * 64 + n * 16 + (lane & 15);
#pragma unroll
      for (int r2 = 0; r2 < 4; ++r2) {
        int rr = row + r2;
        float v = acc[m][n][r2];
        if (rr < 32) qt[((size_t)b * HW + col) * 32 + rr] = v + bq[rr];
        else         kf[((size_t)b * 32 + (rr - 32)) * HW + col] = v + bk[rr - 32];
      }
    }
}

// --------------------------------------------------- PAM energy + softmax
__global__ __launch_bounds__(256) void pam_es_k(const float* __restrict__ qt,
                                                const float* __restrict__ kf,
                                                float* __restrict__ Pbuf) {
  const int ccb = blockIdx.x;
  const int ck = ccb >> 4, b = ccb & 15;
  const int gi = ck / 5, gj = ck % 5;
  const int pbase = gi * 16 * IMW + gj * 16;
  float* Pc = Pbuf + (size_t)ccb * 65536;
  __shared__ float qs[256][32];
  __shared__ float S[32][256];
  const int tid = threadIdx.x;
  const float* qb = qt + (size_t)b * HW * 32;
#pragma unroll
  for (int qq = 0; qq < 8; ++qq) {
    int j = (tid >> 3) + 32 * qq;
    int nj = pbase + (j >> 4) * IMW + (j & 15);
    float4 v = *(const float4*)(qb + (size_t)nj * 32 + (tid & 7) * 4);
    *(float4*)&qs[j][(tid & 7) * 4] = v;
  }
  const int nt = pbase + (tid >> 4) * IMW + (tid & 15);
  const float* kb = kf + (size_t)b * 32 * HW;
  float kc[32];
#pragma unroll
  for (int kk = 0; kk < 32; ++kk) kc[kk] = kb[(size_t)kk * HW + nt];
  __syncthreads();
  const int w = tid >> 6, lane = tid & 63;
  for (int p = 0; p < 8; ++p) {
#pragma unroll 4
    for (int j2 = 0; j2 < 32; ++j2) {
      int row = p * 32 + j2;
      float s = 0.f;
#pragma unroll
      for (int k8 = 0; k8 < 8; ++k8) {
        float4 qv = *(const float4*)&qs[row][k8 * 4];
        s = fmaf(qv.x, kc[k8 * 4 + 0], s);
        s = fmaf(qv.y, kc[k8 * 4 + 1], s);
        s = fmaf(qv.z, kc[k8 * 4 + 2], s);
        s = fmaf(qv.w, kc[k8 * 4 + 3], s);
      }
      S[j2][tid] = s;
    }
    __syncthreads();
#pragma unroll
    for (int rr = 0; rr < 8; ++rr) {
      int jj = w * 8 + rr;
      float4 v = *(const float4*)&S[jj][lane << 2];
      float m = fmaxf(fmaxf(v.x, v.y), fmaxf(v.z, v.w));
      for (int o = 32; o; o >>= 1) m = fmaxf(m, __shfl_xor(m, o));
      float4 pv;
      pv.x = __expf(v.x - m); pv.y = __expf(v.y - m);
      pv.z = __expf(v.z - m); pv.w = __expf(v.w - m);
      float s = (pv.x + pv.y) + (pv.z + pv.w);
      for (int o = 32; o; o >>= 1) s += __shfl_xor(s, o);
      const float inv = 1.f / s;
      pv.x *= inv; pv.y *= inv; pv.z *= inv; pv.w *= inv;
      *(float4*)&Pc[(size_t)(p * 32 + jj) * 256 + (lane << 2)] = pv;
    }
    __syncthreads();
  }
}

// ---------------------------------------------------------------- PAM PV
// One 512-thr block per ccb: out[d][j] = g*sum_n V[d][n] P[j][n] + X[d][n(j)],
// written over P[ccb] after all reads complete. Register-prefetch pipeline.
__global__ __launch_bounds__(512) void pam_pv_k(float* __restrict__ P,
                                                const float* __restrict__ V,
                                                const float* __restrict__ fS,
                                                const float* __restrict__ fT,
                                                const float* __restrict__ gsc, int t) {
  const int ccb = blockIdx.x;
  const int ck = ccb >> 4, b = ccb & 15;
  const int gi = ck / 5, gj = ck % 5;
  const float* Xb = (t ? fT : fS) + (size_t)b * CH * HW;
  const float* Vb = V + (size_t)b * CH * HW;
  float* Pc = P + (size_t)ccb * 65536;
  __shared__ unsigned short lds[2 * 256 * 64];
  char* Ab = (char*)lds;
  char* Bb = (char*)lds + 32768;
  const int tid = threadIdx.x, lane = tid & 63, w = tid >> 6;
  const int wr = w >> 2, wc = w & 3;
  const int r0 = tid >> 3, kq = tid & 7;
  const int pbase = gi * 16 * IMW + gj * 16;
  f32x4 acc[8][4] = {};
  float4 va[4], vb[4];
  {
    int jj = kq * 4;
    int ngl = pbase + (jj >> 4) * IMW + (jj & 15);
#pragma unroll
    for (int q = 0; q < 4; ++q) {
      int rr = r0 + 64 * q;
      va[q] = *(const float4*)(Vb + (size_t)rr * HW + ngl);
      vb[q] = *(const float4*)(Pc + (size_t)rr * 256 + kq * 4);
    }
  }
  for (int s = 0; s < 8; ++s) {
    __syncthreads();   // prev iter's frag reads done
#pragma unroll
    for (int q = 0; q < 4; ++q) {
      int rr = r0 + 64 * q;
      ushort4 h4, l4;
      cvt4(va[q], h4, l4);
      *(ushort4*)(Ab + lds_off(rr, 0, kq * 8)) = h4;
      *(ushort4*)(Ab + lds_off(rr, 1, kq * 8)) = l4;
      cvt4(vb[q], h4, l4);
      *(ushort4*)(Bb + lds_off(rr, 0, kq * 8)) = h4;
      *(ushort4*)(Bb + lds_off(rr, 1, kq * 8)) = l4;
    }
    __syncthreads();
    float4 na[4], nb[4];
    if (s < 7) {
      int k0 = (s + 1) * 32;
      int jj = k0 + kq * 4;
      int ngl = pbase + (jj >> 4) * IMW + (jj & 15);
#pragma unroll
      for (int q = 0; q < 4; ++q) {
        int rr = r0 + 64 * q;
        na[q] = *(const float4*)(Vb + (size_t)rr * HW + ngl);
        nb[q] = *(const float4*)(Pc + (size_t)rr * 256 + k0 + kq * 4);
      }
    }
    bf16x8 bfr[2][4];
#pragma unroll
    for (int h = 0; h < 2; ++h)
#pragma unroll
      for (int n = 0; n < 4; ++n)
        bfr[h][n] = frag_ld(Bb, wc * 64 + n * 16 + (lane & 15), h, lane);
#pragma unroll
    for (int m = 0; m < 8; ++m) {
      int arow = wr * 128 + m * 16 + (lane & 15);
      bf16x8 a0 = frag_ld(Ab, arow, 0, lane);
      bf16x8 a1 = frag_ld(Ab, arow, 1, lane);
#pragma unroll
      for (int n = 0; n < 4; ++n)
        acc[m][n] = __builtin_amdgcn_mfma_f32_16x16x32_bf16(a0, bfr[0][n], acc[m][n], 0, 0, 0);
#pragma unroll
      for (int n = 0; n < 4; ++n)
        acc[m][n] = __builtin_amdgcn_mfma_f32_16x16x32_bf16(a0, bfr[1][n], acc[m][n], 0, 0, 0);
#pragma unroll
      for (int n = 0; n < 4; ++n)
        acc[m][n] = __builtin_amdgcn_mfma_f32_16x16x32_bf16(a1, bfr[0][n], acc[m][n], 0, 0, 0);
    }
#pragma unroll
    for (int q = 0; q < 4; ++q) { va[q] = na[q]; vb[q] = nb[q]; }
  }
  const float g = gsc[0];
#pragma unroll
  for (int m = 0; m < 8; ++m)
#pragma unroll
    for (int n = 0; n < 4; ++n) {
      int row = wr * 128 + m * 16 + ((lane >> 4) << 2);
      int col = wc * 64 + n * 16 + (lane & 15);
      int ngl = pbase + (col >> 4) * IMW + (col & 15);
#pragma unroll
      for (int r2 = 0; r2 < 4; ++r2) {
        float v = g * acc[m][n][r2] + Xb[(size_t)(row + r2) * HW + ngl];
        Pc[(size_t)(row + r2) * 256 + col] = v;
      }
    }
}

// ------------------------------------------------------------- gram (MFMA)
__global__ __launch_bounds__(256) void gram_mfma_k(const float* __restrict__ Z,
                                                   size_t gStride, size_t bStride,
                                                   double* __restrict__ G) {
  const int tid = threadIdx.x, lane = tid & 63, w = tid >> 6;
  const float* Zg = Z + (size_t)blockIdx.y * gStride;
  const float* p = Zg + (size_t)(lane & 15) * bStride +
                   (size_t)blockIdx.x * 4096 + w * 1024 + ((lane >> 4) << 3);
  f32x4 acc = {};
#pragma unroll 4
  for (int s = 0; s < 32; ++s) {
    float4 v0 = *(const float4*)(p + s * 32);
    float4 v1 = *(const float4*)(p + s * 32 + 4);
    bf16x8 hi, lo;
    cvt8(v0, v1, hi, lo);
    acc = __builtin_amdgcn_mfma_f32_16x16x32_bf16(hi, hi, acc, 0, 0, 0);
    acc = __builtin_amdgcn_mfma_f32_16x16x32_bf16(hi, lo, acc, 0, 0, 0);
    acc = __builtin_amdgcn_mfma_f32_16x16x32_bf16(lo, hi, acc, 0, 0, 0);
  }
  double* Gt = G + (size_t)blockIdx.y * 256;
  const int col = lane & 15, row0 = (lane >> 4) << 2;
#pragma unroll
  for (int i = 0; i < 4; ++i)
    atomicAdd(&Gt[(size_t)(row0 + i) * 16 + col], (double)acc[i]);
}

// -------------------------------------------------------------- CKA pairs
__global__ __launch_bounds__(256) void cka_pair_k(const double* __restrict__ G,
                                                  double* __restrict__ losses) {
  const int q = blockIdx.x;
  const double* KX = (q == 0) ? G : G + 512 + (size_t)(q - 1) * 256;
  const double* KY = (q == 0) ? G + 256 : G + 512 + 6400 + (size_t)(q - 1) * 256;
  __shared__ double red[256];
  __shared__ double srm[16], scm[16];
  __shared__ double stm;
  const int tid = threadIdx.x;
  const int r = tid >> 4, c = tid & 15;

  auto center = [&](double k) -> double {
    red[tid] = k;
    __syncthreads();
    for (int off = 8; off; off >>= 1) {
      if (c < off) red[tid] += red[tid + off];
      __syncthreads();
    }
    if (c == 0) srm[r] = red[tid] * (1.0 / 16.0);
    __syncthreads();
    red[c * 16 + r] = k;
    __syncthreads();
    for (int off = 8; off; off >>= 1) {
      if (r < off) red[c * 16 + r] += red[c * 16 + r + off];
      __syncthreads();
    }
    if (r == 0) scm[c] = red[c * 16] * (1.0 / 16.0);
    __syncthreads();
    if (tid == 0) {
      double s = 0.0;
      for (int i = 0; i < 16; ++i) s += srm[i];
      stm = s * (1.0 / 16.0);
    }
    __syncthreads();
    double v = k - srm[r] - scm[c] + stm;
    __syncthreads();
    return v;
  };
  auto reduce_sum = [&](double v) -> double {
    red[tid] = v;
    __syncthreads();
    for (int off = 128; off; off >>= 1) {
      if (tid < off) red[tid] += red[tid + off];
      __syncthreads();
    }
    double s = red[0];
    __syncthreads();
    return s;
  };
  double cx = center(KX[tid]);
  double cy = center(KY[tid]);
  double h = reduce_sum(cx * cy);
  double v1 = reduce_sum(cx * cx);
  double v2 = reduce_sum(cy * cy);
  if (tid == 0) losses[q] = -log(fabs(h / (sqrt(v1) * sqrt(v2))) + 1e-8);
}

__global__ void cka_combine_k(const double* __restrict__ losses,
                              float* __restrict__ out) {
  if (threadIdx.x == 0) {
    out[0] = (float)losses[0];
    double s = 0.0;
    for (int q = 1; q <= 25; ++q) s += losses[q];
    out[1] = (float)(s * (1.0 / 25.0));
  }
}

extern "C" void kernel_launch(void* const* d_in, const int* in_sizes, int n_in,
                              void* d_out, int out_size, void* d_ws, size_t ws_size,
                              hipStream_t stream) {
  (void)in_sizes; (void)n_in; (void)out_size; (void)ws_size;
  const float* fS = (const float*)d_in[0];
  const float* fT = (const float*)d_in[1];
  const float* Wq = (const float*)d_in[2];
  const float* bq = (const float*)d_in[3];
  const float* Wk = (const float*)d_in[4];
  const float* bk = (const float*)d_in[5];
  const float* Wv = (const float*)d_in[6];
  const float* bv = (const float*)d_in[7];
  const float* gcam = (const float*)d_in[8];
  const float* gpam = (const float*)d_in[9];
  float* out = (float*)d_out;

  float* buf0 = (float*)d_ws;              // 26214400 floats
  float* buf1 = buf0 + 26214400;           // 26214400 floats
  double* G = (double*)(buf1 + 26214400);  // 13312 doubles
  float* Pbuf = buf1;                      // 400*65536
  float* qt = buf0;                        // 16*6400*32
  float* kf = buf0 + 3276800;              // 16*32*6400
  double* losses = (double*)buf0;          // 26 doubles, dead region at CKA time

  hipMemsetAsync(G, 0, 13312 * sizeof(double), stream);

  // ---- CAM ----
  cam_energy_k<<<dim3(8, 16, 2), 1024, 0, stream>>>(fS, fT, buf1);
  cam_softmax_k<<<dim3(256, 16, 2), 64, 0, stream>>>(buf1);
  for (int t = 0; t < 2; ++t) {
    ax_k<0><<<dim3(50, 16), 1024, 0, stream>>>(buf1 + (size_t)t * BB * 65536, 65536,
                                               t ? fT : fS, buf0, nullptr, gcam);
    gram_mfma_k<<<dim3(400, 1), 256, 0, stream>>>(buf0, (size_t)0, (size_t)1638400,
                                                  G + t * 256);
  }
  // ---- PAM ----
  for (int t = 0; t < 2; ++t) {
    const float* X = t ? fT : fS;
    qk_k<<<dim3(25, 16), 256, 0, stream>>>(X, Wq, bq, Wk, bk, qt, kf);
    pam_es_k<<<dim3(400), 256, 0, stream>>>(qt, kf, Pbuf);
    ax_k<1><<<dim3(50, 16), 1024, 0, stream>>>(Wv, 0, X, buf0, bv, nullptr);
    pam_pv_k<<<dim3(400), 512, 0, stream>>>(Pbuf, buf0, fS, fT, gpam, t);
    gram_mfma_k<<<dim3(16, 25), 256, 0, stream>>>(Pbuf, (size_t)1048576, (size_t)65536,
                                                  G + 512 + t * 6400);
  }
  cka_pair_k<<<dim3(26), 256, 0, stream>>>(G, losses);
  cka_combine_k<<<dim3(1), 64, 0, stream>>>(losses, out);
}

// Round 14
// 992.845 us; speedup vs baseline: 2.9679x; 1.0082x over previous
//
#include <hip/hip_runtime.h>

// CriterionSA: CAM + grid-PAM + CKA loss.
// GEMMs in split-bf16 MFMA (hi/lo, 3 MFMAs: hh+hl+lh); cam_energy plain bf16
// (softmax saturated). Grams via MFMA split-bf16; fp32 acc -> fp64 atomics.
// CKA fp64, 26 parallel blocks.
// R14: pam_pv_k wave-widened to 1024 thr (16 waves of 64x64, acc[4][4],
// h-outer MFMA to stay <=128 regs), double-buffered LDS (128KB, 1 barrier).
// ws layout (floats): buf0[26214400] | buf1[26214400] | G[13312 doubles]
// required ws = 209,821,696 bytes (~200.1 MiB) -- same as rounds 1-13.

typedef short bf16x8 __attribute__((ext_vector_type(8)));
typedef float f32x4 __attribute__((ext_vector_type(4)));

constexpr int BB = 16;    // batch
constexpr int CH = 256;   // channels
constexpr int HW = 6400;  // 80*80
constexpr int IMW = 80;

__device__ __forceinline__ int lds_off(int row, int half, int k2) {
  return row * 128 + ((((half << 6)) | k2) ^ ((row & 7) << 4));
}

__device__ __forceinline__ bf16x8 frag_ld(const char* base, int row, int half, int lane) {
  int off = row * 128 + ((((half << 6)) | ((lane >> 4) << 4)) ^ ((lane & 7) << 4));
  return *(const bf16x8*)(base + off);
}

__device__ __forceinline__ void cvt2(float x, unsigned short& h, unsigned short& l) {
  unsigned u = __float_as_uint(x);
  h = (unsigned short)(u >> 16);                       // truncated hi
  float r = x - __uint_as_float(u & 0xffff0000u);
  l = (unsigned short)(__float_as_uint(r) >> 16);      // truncated residual
}

__device__ __forceinline__ void cvt4(float4 v, ushort4& h, ushort4& l) {
  cvt2(v.x, h.x, l.x); cvt2(v.y, h.y, l.y);
  cvt2(v.z, h.z, l.z); cvt2(v.w, h.w, l.w);
}

__device__ __forceinline__ void cvt8(float4 v0, float4 v1, bf16x8& hi, bf16x8& lo) {
  unsigned short h, l;
  cvt2(v0.x, h, l); hi[0] = (short)h; lo[0] = (short)l;
  cvt2(v0.y, h, l); hi[1] = (short)h; lo[1] = (short)l;
  cvt2(v0.z, h, l); hi[2] = (short)h; lo[2] = (short)l;
  cvt2(v0.w, h, l); hi[3] = (short)h; lo[3] = (short)l;
  cvt2(v1.x, h, l); hi[4] = (short)h; lo[4] = (short)l;
  cvt2(v1.y, h, l); hi[5] = (short)h; lo[5] = (short)l;
  cvt2(v1.z, h, l); hi[6] = (short)h; lo[6] = (short)l;
  cvt2(v1.w, h, l); hi[7] = (short)h; lo[7] = (short)l;
}

__device__ __forceinline__ unsigned short bf_rnd(float x) {
  unsigned u = __float_as_uint(x);
  return (unsigned short)((u + 0x8000u) >> 16);
}

// ---------------------------------------------------------------- CAM energy
// Partial E[kc][t][b] = X(:,kslice) X(:,kslice)^T, kc=0..7 (K=800 each,
// 12 x 64 + zero-padded 32 tail). Grid = 256 blocks, 1024 thr (16 waves of
// 64x64 -> acc[4][4]). One LDS panel is both MFMA operands. Double-buffered.
__global__ __launch_bounds__(1024) void cam_energy_k(const float* __restrict__ fS,
                                                     const float* __restrict__ fT,
                                                     float* __restrict__ part) {
  const int kc = blockIdx.x, b = blockIdx.y, t = blockIdx.z;
  const float* X = (t ? fT : fS) + (size_t)b * CH * HW;
  __shared__ unsigned short lds[2 * 256 * 64];  // 2 x 32 KB panels
  const int tid = threadIdx.x, lane = tid & 63, w = tid >> 6;
  const int wr = w >> 2, wc = w & 3;            // 4x4 waves -> 64x64 each
  const int r0 = tid >> 2, kq = tid & 3;        // staging: 4 float4/thread
  const int half = kq >> 1, k2b = (kq & 1) * 32;
  const float* Xr = X + (size_t)r0 * HW + kc * 800 + kq * 16;
  f32x4 acc[4][4] = {};
  float4 v[4];
#pragma unroll
  for (int q = 0; q < 4; ++q) v[q] = *(const float4*)(Xr + q * 4);
  for (int it = 0; it < 13; ++it) {
    char* pb = (char*)lds + (it & 1) * 32768;
#pragma unroll
    for (int q = 0; q < 4; ++q) {
      ushort4 u;
      u.x = bf_rnd(v[q].x); u.y = bf_rnd(v[q].y);
      u.z = bf_rnd(v[q].z); u.w = bf_rnd(v[q].w);
      *(ushort4*)(pb + lds_off(r0, half, k2b + q * 8)) = u;
    }
    __syncthreads();
    float4 nv[4];
    if (it < 12) {
      const int nk = (it + 1) * 64;
      if (nk + kq * 16 < 800) {
        const float* Xn = Xr + nk;
#pragma unroll
        for (int q = 0; q < 4; ++q) nv[q] = *(const float4*)(Xn + q * 4);
      } else {
#pragma unroll
        for (int q = 0; q < 4; ++q) nv[q] = make_float4(0.f, 0.f, 0.f, 0.f);
      }
    }
#pragma unroll
    for (int h = 0; h < 2; ++h) {
      bf16x8 bh[4];
#pragma unroll
      for (int n = 0; n < 4; ++n)
        bh[n] = frag_ld(pb, wc * 64 + n * 16 + (lane & 15), h, lane);
#pragma unroll
      for (int m = 0; m < 4; ++m) {
        bf16x8 a = frag_ld(pb, wr * 64 + m * 16 + (lane & 15), h, lane);
#pragma unroll
        for (int n = 0; n < 4; ++n)
          acc[m][n] = __builtin_amdgcn_mfma_f32_16x16x32_bf16(a, bh[n], acc[m][n], 0, 0, 0);
      }
    }
#pragma unroll
    for (int q = 0; q < 4; ++q) v[q] = nv[q];
  }
  float* Eb = part + (((size_t)kc * 2 + t) * BB + b) * 65536;
#pragma unroll
  for (int m = 0; m < 4; ++m)
#pragma unroll
    for (int n = 0; n < 4; ++n) {
      int row = wr * 64 + m * 16 + ((lane >> 4) << 2);
      int col = wc * 64 + n * 16 + (lane & 15);
#pragma unroll
      for (int r2 = 0; r2 < 4; ++r2)
        Eb[(size_t)(row + r2) * 256 + col] = acc[m][n][r2];
    }
}

// ------------------------------------------------------------- CAM softmax
// attn = exp(rowmin - sum_p partE[p]) / rowsum, written into partial 0.
__global__ __launch_bounds__(64) void cam_softmax_k(float* __restrict__ part) {
  const int c = blockIdx.x, b = blockIdx.y, t = blockIdx.z;
  const size_t base = (((size_t)t * BB + b) * CH + c) * CH;
  const int lane = threadIdx.x;
  float4 x = make_float4(0.f, 0.f, 0.f, 0.f);
#pragma unroll
  for (int p = 0; p < 8; ++p) {
    float4 y = ((const float4*)(part + (size_t)p * 2097152 + base))[lane];
    x.x += y.x; x.y += y.y; x.z += y.z; x.w += y.w;
  }
  float mn = fminf(fminf(x.x, x.y), fminf(x.z, x.w));
  for (int o = 32; o; o >>= 1) mn = fminf(mn, __shfl_xor(mn, o));
  float4 p4;
  p4.x = __expf(mn - x.x); p4.y = __expf(mn - x.y);
  p4.z = __expf(mn - x.z); p4.w = __expf(mn - x.w);
  float s = (p4.x + p4.y) + (p4.z + p4.w);
  for (int o = 32; o; o >>= 1) s += __shfl_xor(s, o);
  const float inv = 1.0f / s;
  p4.x *= inv; p4.y *= inv; p4.z *= inv; p4.w *= inv;
  ((float4*)(part + base))[lane] = p4;
}

// ----------------------------------------------------- A(256x256) @ X GEMM
// MODE 0 (cam_out): OUT[c][n] = g*sum_d A[c][d] X[d][n] + X[c][n]
// MODE 1 (pam_V):   OUT[d][n] = sum_c Wv[d][c] X[c][n] + bv[d]
// 1024 thr, 16 waves (4x4 of 64x32 -> acc[4][2]); tile M=256 x N=128;
// double-buffered LDS (96KB, 1 barrier/step). X read once.
template <int MODE>
__global__ __launch_bounds__(1024) void ax_k(const float* __restrict__ Abase, int Astride,
                                             const float* __restrict__ X,
                                             float* __restrict__ OUT,
                                             const float* __restrict__ bvec,
                                             const float* __restrict__ gsc) {
  const int nt = blockIdx.x;
  const int b = blockIdx.y;
  const float* A = Abase + (size_t)b * Astride;
  const float* Xb = X + (size_t)b * CH * HW;
  float* OUTb = OUT + (size_t)b * CH * HW;
  const int nbase = nt * 128;
  __shared__ unsigned short lds[2 * (256 + 128) * 64];  // dbuf x (A 32KB + B 16KB)
  const int tid = threadIdx.x, lane = tid & 63, w = tid >> 6;
  const int wr = w >> 2, wc = w & 3;             // 4x4 waves -> 64x32 each
  const int r0 = tid >> 2, kq = tid & 3;         // A staging: 2 float4/thread
  const int n_r = tid & 127, kg = tid >> 7;      // B staging: row + 4-k group
  const float* Xcol = Xb + nbase + n_r;
  f32x4 acc[4][2] = {};
  float4 ra[2];
  float vb4[4];
#pragma unroll
  for (int q = 0; q < 2; ++q)
    ra[q] = *(const float4*)(A + (size_t)r0 * 256 + kq * 8 + q * 4);
#pragma unroll
  for (int e = 0; e < 4; ++e)
    vb4[e] = Xcol[(size_t)(kg * 4 + e) * HW];
  for (int s = 0; s < 8; ++s) {
    char* Ab = (char*)lds + (s & 1) * 49152;
    char* Bb = Ab + 32768;
#pragma unroll
    for (int q = 0; q < 2; ++q) {
      ushort4 h4, l4;
      cvt4(ra[q], h4, l4);
      *(ushort4*)(Ab + lds_off(r0, 0, kq * 16 + q * 8)) = h4;
      *(ushort4*)(Ab + lds_off(r0, 1, kq * 16 + q * 8)) = l4;
    }
    {
      unsigned short bh[4], bl[4];
#pragma unroll
      for (int e = 0; e < 4; ++e) cvt2(vb4[e], bh[e], bl[e]);
      *(ushort4*)(Bb + lds_off(n_r, 0, kg * 8)) = make_ushort4(bh[0], bh[1], bh[2], bh[3]);
      *(ushort4*)(Bb + lds_off(n_r, 1, kg * 8)) = make_ushort4(bl[0], bl[1], bl[2], bl[3]);
    }
    __syncthreads();
    if (s < 7) {
      int k0 = (s + 1) * 32;
#pragma unroll
      for (int q = 0; q < 2; ++q)
        ra[q] = *(const float4*)(A + (size_t)r0 * 256 + k0 + kq * 8 + q * 4);
#pragma unroll
      for (int e = 0; e < 4; ++e)
        vb4[e] = Xcol[(size_t)(k0 + kg * 4 + e) * HW];
    }
    bf16x8 bfr[2][2];
#pragma unroll
    for (int h = 0; h < 2; ++h)
#pragma unroll
      for (int n = 0; n < 2; ++n)
        bfr[h][n] = frag_ld(Bb, wc * 32 + n * 16 + (lane & 15), h, lane);
#pragma unroll
    for (int m = 0; m < 4; ++m) {
      int arow = wr * 64 + m * 16 + (lane & 15);
      bf16x8 a0 = frag_ld(Ab, arow, 0, lane);
      bf16x8 a1 = frag_ld(Ab, arow, 1, lane);
#pragma unroll
      for (int n = 0; n < 2; ++n)
        acc[m][n] = __builtin_amdgcn_mfma_f32_16x16x32_bf16(a0, bfr[0][n], acc[m][n], 0, 0, 0);
#pragma unroll
      for (int n = 0; n < 2; ++n)
        acc[m][n] = __builtin_amdgcn_mfma_f32_16x16x32_bf16(a0, bfr[1][n], acc[m][n], 0, 0, 0);
#pragma unroll
      for (int n = 0; n < 2; ++n)
        acc[m][n] = __builtin_amdgcn_mfma_f32_16x16x32_bf16(a1, bfr[0][n], acc[m][n], 0, 0, 0);
    }
  }
  float g = 0.f;
  if (MODE == 0) g = gsc[0];
#pragma unroll
  for (int m = 0; m < 4; ++m)
#pragma unroll
    for (int n = 0; n < 2; ++n) {
      int row = wr * 64 + m * 16 + ((lane >> 4) << 2);
      int col = nbase + wc * 32 + n * 16 + (lane & 15);
#pragma unroll
      for (int r2 = 0; r2 < 4; ++r2) {
        size_t o = (size_t)(row + r2) * HW + col;
        float v = acc[m][n][r2];
        if (MODE == 0) OUTb[o] = g * v + Xb[o];
        else           OUTb[o] = v + bvec[row + r2];
      }
    }
}

// ------------------------------------------------------------ PAM q/k GEMM
// Full-image 1x1 conv: rows 0..31 = Wq, 32..63 = Wk; N = 6400, K = 256.
// Outputs: qt[b][n][32] (n-major, +bq), kf[b][32][n] (+bk). split-bf16.
__global__ __launch_bounds__(256) void qk_k(const float* __restrict__ X,
                                            const float* __restrict__ Wq,
                                            const float* __restrict__ bq,
                                            const float* __restrict__ Wk,
                                            const float* __restrict__ bk,
                                            float* __restrict__ qt,
                                            float* __restrict__ kf) {
  const int nbase = blockIdx.x * 256;
  const int b = blockIdx.y;
  const float* Xb = X + (size_t)b * CH * HW;
  __shared__ unsigned short lds[(64 + 256) * 64];  // A 8KB + B 32KB
  char* Ab = (char*)lds;
  char* Bb = (char*)lds + 8192;
  const int tid = threadIdx.x, lane = tid & 63, w = tid >> 6;
  const int ar = tid >> 2, akq = tid & 3;          // A staging
  const int n4 = (tid & 63) * 4, c0l = tid >> 6;   // B staging (256 rows)
  const float* Arow = (ar < 32) ? (Wq + (size_t)ar * CH) : (Wk + (size_t)(ar - 32) * CH);
  f32x4 acc[4][4] = {};
  float4 va[2], vb[8];
#pragma unroll
  for (int q = 0; q < 2; ++q)
    va[q] = *(const float4*)(Arow + akq * 8 + q * 4);
#pragma unroll
  for (int q = 0; q < 8; ++q)
    vb[q] = *(const float4*)(Xb + (size_t)(c0l + 4 * q) * HW + nbase + n4);
  for (int s = 0; s < 8; ++s) {
    __syncthreads();   // prev iter's frag reads done
#pragma unroll
    for (int q = 0; q < 2; ++q) {
      ushort4 h4, l4;
      cvt4(va[q], h4, l4);
      *(ushort4*)(Ab + lds_off(ar, 0, akq * 16 + q * 8)) = h4;
      *(ushort4*)(Ab + lds_off(ar, 1, akq * 16 + q * 8)) = l4;
    }
#pragma unroll
    for (int q = 0; q < 8; ++q) {
      int cc = c0l + 4 * q;
      float4 v = vb[q];
#pragma unroll
      for (int jj = 0; jj < 4; ++jj) {
        int j = (jj + tid) & 3;
        float e = (j == 0) ? v.x : (j == 1) ? v.y : (j == 2) ? v.z : v.w;
        unsigned short h, l;
        cvt2(e, h, l);
        int row = n4 + j;
        *(unsigned short*)(Bb + lds_off(row, 0, cc * 2)) = h;
        *(unsigned short*)(Bb + lds_off(row, 1, cc * 2)) = l;
      }
    }
    __syncthreads();
    float4 na[2], nb[8];
    if (s < 7) {
      const int k0 = (s + 1) * 32;
#pragma unroll
      for (int q = 0; q < 2; ++q)
        na[q] = *(const float4*)(Arow + k0 + akq * 8 + q * 4);
#pragma unroll
      for (int q = 0; q < 8; ++q)
        nb[q] = *(const float4*)(Xb + (size_t)(k0 + c0l + 4 * q) * HW + nbase + n4);
    }
    bf16x8 bfr[2][4];
#pragma unroll
    for (int h = 0; h < 2; ++h)
#pragma unroll
      for (int n = 0; n < 4; ++n)
        bfr[h][n] = frag_ld(Bb, w * 64 + n * 16 + (lane & 15), h, lane);
#pragma unroll
    for (int m = 0; m < 4; ++m) {
      int arow2 = m * 16 + (lane & 15);
      bf16x8 a0 = frag_ld(Ab, arow2, 0, lane);
      bf16x8 a1 = frag_ld(Ab, arow2, 1, lane);
#pragma unroll
      for (int n = 0; n < 4; ++n)
        acc[m][n] = __builtin_amdgcn_mfma_f32_16x16x32_bf16(a0, bfr[0][n], acc[m][n], 0, 0, 0);
#pragma unroll
      for (int n = 0; n < 4; ++n)
        acc[m][n] = __builtin_amdgcn_mfma_f32_16x16x32_bf16(a0, bfr[1][n], acc[m][n], 0, 0, 0);
#pragma unroll
      for (int n = 0; n < 4; ++n)
        acc[m][n] = __builtin_amdgcn_mfma_f32_16x16x32_bf16(a1, bfr[0][n], acc[m][n], 0, 0, 0);
    }
#pragma unroll
    for (int q = 0; q < 2; ++q) va[q] = na[q];
#pragma unroll
    for (int q = 0; q < 8; ++q) vb[q] = nb[q];
  }
#pragma unroll
  for (int m = 0; m < 4; ++m)
#pragma unroll
    for (int n = 0; n < 4; ++n) {
      int row = m * 16 + ((lane >> 4) << 2);
      int col = nbase + w * 64 + n * 16 + (lane & 15);
#pragma unroll
      for (int r2 = 0; r2 < 4; ++r2) {
        int rr = row + r2;
        float v = acc[m][n][r2];
        if (rr < 32) qt[((size_t)b * HW + col) * 32 + rr] = v + bq[rr];
        else         kf[((size_t)b * 32 + (rr - 32)) * HW + col] = v + bk[rr - 32];
      }
    }
}

// --------------------------------------------------- PAM energy + softmax
__global__ __launch_bounds__(256) void pam_es_k(const float* __restrict__ qt,
                                                const float* __restrict__ kf,
                                                float* __restrict__ Pbuf) {
  const int ccb = blockIdx.x;
  const int ck = ccb >> 4, b = ccb & 15;
  const int gi = ck / 5, gj = ck % 5;
  const int pbase = gi * 16 * IMW + gj * 16;
  float* Pc = Pbuf + (size_t)ccb * 65536;
  __shared__ float qs[256][32];
  __shared__ float S[32][256];
  const int tid = threadIdx.x;
  const float* qb = qt + (size_t)b * HW * 32;
#pragma unroll
  for (int qq = 0; qq < 8; ++qq) {
    int j = (tid >> 3) + 32 * qq;
    int nj = pbase + (j >> 4) * IMW + (j & 15);
    float4 v = *(const float4*)(qb + (size_t)nj * 32 + (tid & 7) * 4);
    *(float4*)&qs[j][(tid & 7) * 4] = v;
  }
  const int nt = pbase + (tid >> 4) * IMW + (tid & 15);
  const float* kb = kf + (size_t)b * 32 * HW;
  float kc[32];
#pragma unroll
  for (int kk = 0; kk < 32; ++kk) kc[kk] = kb[(size_t)kk * HW + nt];
  __syncthreads();
  const int w = tid >> 6, lane = tid & 63;
  for (int p = 0; p < 8; ++p) {
#pragma unroll 4
    for (int j2 = 0; j2 < 32; ++j2) {
      int row = p * 32 + j2;
      float s = 0.f;
#pragma unroll
      for (int k8 = 0; k8 < 8; ++k8) {
        float4 qv = *(const float4*)&qs[row][k8 * 4];
        s = fmaf(qv.x, kc[k8 * 4 + 0], s);
        s = fmaf(qv.y, kc[k8 * 4 + 1], s);
        s = fmaf(qv.z, kc[k8 * 4 + 2], s);
        s = fmaf(qv.w, kc[k8 * 4 + 3], s);
      }
      S[j2][tid] = s;
    }
    __syncthreads();
#pragma unroll
    for (int rr = 0; rr < 8; ++rr) {
      int jj = w * 8 + rr;
      float4 v = *(const float4*)&S[jj][lane << 2];
      float m = fmaxf(fmaxf(v.x, v.y), fmaxf(v.z, v.w));
      for (int o = 32; o; o >>= 1) m = fmaxf(m, __shfl_xor(m, o));
      float4 pv;
      pv.x = __expf(v.x - m); pv.y = __expf(v.y - m);
      pv.z = __expf(v.z - m); pv.w = __expf(v.w - m);
      float s = (pv.x + pv.y) + (pv.z + pv.w);
      for (int o = 32; o; o >>= 1) s += __shfl_xor(s, o);
      const float inv = 1.f / s;
      pv.x *= inv; pv.y *= inv; pv.z *= inv; pv.w *= inv;
      *(float4*)&Pc[(size_t)(p * 32 + jj) * 256 + (lane << 2)] = pv;
    }
    __syncthreads();
  }
}

// ---------------------------------------------------------------- PAM PV
// One 1024-thr block per ccb: out[d][j] = g*sum_n V[d][n] P[j][n] + X[d][n(j)],
// written over P[ccb] after all reads complete. 16 waves of 64x64 (acc[4][4]),
// h-outer MFMA (hh+lh with b_hi, hl with b_lo), dbuf LDS, reg prefetch.
__global__ __launch_bounds__(1024) void pam_pv_k(float* __restrict__ P,
                                                 const float* __restrict__ V,
                                                 const float* __restrict__ fS,
                                                 const float* __restrict__ fT,
                                                 const float* __restrict__ gsc, int t) {
  const int ccb = blockIdx.x;
  const int ck = ccb >> 4, b = ccb & 15;
  const int gi = ck / 5, gj = ck % 5;
  const float* Xb = (t ? fT : fS) + (size_t)b * CH * HW;
  const float* Vb = V + (size_t)b * CH * HW;
  float* Pc = P + (size_t)ccb * 65536;
  __shared__ unsigned short lds[2 * 2 * 256 * 64];  // dbuf x (A 32KB + B 32KB)
  const int tid = threadIdx.x, lane = tid & 63, w = tid >> 6;
  const int wr = w >> 2, wc = w & 3;       // 4x4 waves -> 64x64 each
  const int r0 = tid >> 2, kq = tid & 3;   // staging: row + k-octet (8 k)
  const int pbase = gi * 16 * IMW + gj * 16;
  f32x4 acc[4][4] = {};
  float4 va[2], vb[2];
  {
    int jj = kq * 8;
    int ngl = pbase + (jj >> 4) * IMW + (jj & 15);
    va[0] = *(const float4*)(Vb + (size_t)r0 * HW + ngl);
    va[1] = *(const float4*)(Vb + (size_t)r0 * HW + ngl + 4);
    vb[0] = *(const float4*)(Pc + (size_t)r0 * 256 + jj);
    vb[1] = *(const float4*)(Pc + (size_t)r0 * 256 + jj + 4);
  }
  for (int s = 0; s < 8; ++s) {
    char* Ab = (char*)lds + (s & 1) * 65536;
    char* Bb = Ab + 32768;
    {
      ushort4 h4, l4;
      cvt4(va[0], h4, l4);
      *(ushort4*)(Ab + lds_off(r0, 0, kq * 16)) = h4;
      *(ushort4*)(Ab + lds_off(r0, 1, kq * 16)) = l4;
      cvt4(va[1], h4, l4);
      *(ushort4*)(Ab + lds_off(r0, 0, kq * 16 + 8)) = h4;
      *(ushort4*)(Ab + lds_off(r0, 1, kq * 16 + 8)) = l4;
      cvt4(vb[0], h4, l4);
      *(ushort4*)(Bb + lds_off(r0, 0, kq * 16)) = h4;
      *(ushort4*)(Bb + lds_off(r0, 1, kq * 16)) = l4;
      cvt4(vb[1], h4, l4);
      *(ushort4*)(Bb + lds_off(r0, 0, kq * 16 + 8)) = h4;
      *(ushort4*)(Bb + lds_off(r0, 1, kq * 16 + 8)) = l4;
    }
    __syncthreads();
    if (s < 7) {
      int k0 = (s + 1) * 32;
      int jj = k0 + kq * 8;
      int ngl = pbase + (jj >> 4) * IMW + (jj & 15);
      va[0] = *(const float4*)(Vb + (size_t)r0 * HW + ngl);
      va[1] = *(const float4*)(Vb + (size_t)r0 * HW + ngl + 4);
      vb[0] = *(const float4*)(Pc + (size_t)r0 * 256 + k0 + kq * 8);
      vb[1] = *(const float4*)(Pc + (size_t)r0 * 256 + k0 + kq * 8 + 4);
    }
#pragma unroll
    for (int hb = 0; hb < 2; ++hb) {
      bf16x8 bh[4];
#pragma unroll
      for (int n = 0; n < 4; ++n)
        bh[n] = frag_ld(Bb, wc * 64 + n * 16 + (lane & 15), hb, lane);
#pragma unroll
      for (int m = 0; m < 4; ++m) {
        int arow = wr * 64 + m * 16 + (lane & 15);
        bf16x8 a0 = frag_ld(Ab, arow, 0, lane);
#pragma unroll
        for (int n = 0; n < 4; ++n)
          acc[m][n] = __builtin_amdgcn_mfma_f32_16x16x32_bf16(a0, bh[n], acc[m][n], 0, 0, 0);
        if (hb == 0) {
          bf16x8 a1 = frag_ld(Ab, arow, 1, lane);
#pragma unroll
          for (int n = 0; n < 4; ++n)
            acc[m][n] = __builtin_amdgcn_mfma_f32_16x16x32_bf16(a1, bh[n], acc[m][n], 0, 0, 0);
        }
      }
    }
  }
  const float g = gsc[0];
#pragma unroll
  for (int m = 0; m < 4; ++m)
#pragma unroll
    for (int n = 0; n < 4; ++n) {
      int row = wr * 64 + m * 16 + ((lane >> 4) << 2);
      int col = wc * 64 + n * 16 + (lane & 15);
      int ngl = pbase + (col >> 4) * IMW + (col & 15);
#pragma unroll
      for (int r2 = 0; r2 < 4; ++r2) {
        float v = g * acc[m][n][r2] + Xb[(size_t)(row + r2) * HW + ngl];
        Pc[(size_t)(row + r2) * 256 + col] = v;
      }
    }
}

// ------------------------------------------------------------- gram (MFMA)
__global__ __launch_bounds__(256) void gram_mfma_k(const float* __restrict__ Z,
                                                   size_t gStride, size_t bStride,
                                                   double* __restrict__ G) {
  const int tid = threadIdx.x, lane = tid & 63, w = tid >> 6;
  const float* Zg = Z + (size_t)blockIdx.y * gStride;
  const float* p = Zg + (size_t)(lane & 15) * bStride +
                   (size_t)blockIdx.x * 4096 + w * 1024 + ((lane >> 4) << 3);
  f32x4 acc = {};
#pragma unroll 4
  for (int s = 0; s < 32; ++s) {
    float4 v0 = *(const float4*)(p + s * 32);
    float4 v1 = *(const float4*)(p + s * 32 + 4);
    bf16x8 hi, lo;
    cvt8(v0, v1, hi, lo);
    acc = __builtin_amdgcn_mfma_f32_16x16x32_bf16(hi, hi, acc, 0, 0, 0);
    acc = __builtin_amdgcn_mfma_f32_16x16x32_bf16(hi, lo, acc, 0, 0, 0);
    acc = __builtin_amdgcn_mfma_f32_16x16x32_bf16(lo, hi, acc, 0, 0, 0);
  }
  double* Gt = G + (size_t)blockIdx.y * 256;
  const int col = lane & 15, row0 = (lane >> 4) << 2;
#pragma unroll
  for (int i = 0; i < 4; ++i)
    atomicAdd(&Gt[(size_t)(row0 + i) * 16 + col], (double)acc[i]);
}

// -------------------------------------------------------------- CKA pairs
__global__ __launch_bounds__(256) void cka_pair_k(const double* __restrict__ G,
                                                  double* __restrict__ losses) {
  const int q = blockIdx.x;
  const double* KX = (q == 0) ? G : G + 512 + (size_t)(q - 1) * 256;
  const double* KY = (q == 0) ? G + 256 : G + 512 + 6400 + (size_t)(q - 1) * 256;
  __shared__ double red[256];
  __shared__ double srm[16], scm[16];
  __shared__ double stm;
  const int tid = threadIdx.x;
  const int r = tid >> 4, c = tid & 15;

  auto center = [&](double k) -> double {
    red[tid] = k;
    __syncthreads();
    for (int off = 8; off; off >>= 1) {
      if (c < off) red[tid] += red[tid + off];
      __syncthreads();
    }
    if (c == 0) srm[r] = red[tid] * (1.0 / 16.0);
    __syncthreads();
    red[c * 16 + r] = k;
    __syncthreads();
    for (int off = 8; off; off >>= 1) {
      if (r < off) red[c * 16 + r] += red[c * 16 + r + off];
      __syncthreads();
    }
    if (r == 0) scm[c] = red[c * 16] * (1.0 / 16.0);
    __syncthreads();
    if (tid == 0) {
      double s = 0.0;
      for (int i = 0; i < 16; ++i) s += srm[i];
      stm = s * (1.0 / 16.0);
    }
    __syncthreads();
    double v = k - srm[r] - scm[c] + stm;
    __syncthreads();
    return v;
  };
  auto reduce_sum = [&](double v) -> double {
    red[tid] = v;
    __syncthreads();
    for (int off = 128; off; off >>= 1) {
      if (tid < off) red[tid] += red[tid + off];
      __syncthreads();
    }
    double s = red[0];
    __syncthreads();
    return s;
  };
  double cx = center(KX[tid]);
  double cy = center(KY[tid]);
  double h = reduce_sum(cx * cy);
  double v1 = reduce_sum(cx * cx);
  double v2 = reduce_sum(cy * cy);
  if (tid == 0) losses[q] = -log(fabs(h / (sqrt(v1) * sqrt(v2))) + 1e-8);
}

__global__ void cka_combine_k(const double* __restrict__ losses,
                              float* __restrict__ out) {
  if (threadIdx.x == 0) {
    out[0] = (float)losses[0];
    double s = 0.0;
    for (int q = 1; q <= 25; ++q) s += losses[q];
    out[1] = (float)(s * (1.0 / 25.0));
  }
}

extern "C" void kernel_launch(void* const* d_in, const int* in_sizes, int n_in,
                              void* d_out, int out_size, void* d_ws, size_t ws_size,
                              hipStream_t stream) {
  (void)in_sizes; (void)n_in; (void)out_size; (void)ws_size;
  const float* fS = (const float*)d_in[0];
  const float* fT = (const float*)d_in[1];
  const float* Wq = (const float*)d_in[2];
  const float* bq = (const float*)d_in[3];
  const float* Wk = (const float*)d_in[4];
  const float* bk = (const float*)d_in[5];
  const float* Wv = (const float*)d_in[6];
  const float* bv = (const float*)d_in[7];
  const float* gcam = (const float*)d_in[8];
  const float* gpam = (const float*)d_in[9];
  float* out = (float*)d_out;

  float* buf0 = (float*)d_ws;              // 26214400 floats
  float* buf1 = buf0 + 26214400;           // 26214400 floats
  double* G = (double*)(buf1 + 26214400);  // 13312 doubles
  float* Pbuf = buf1;                      // 400*65536
  float* qt = buf0;                        // 16*6400*32
  float* kf = buf0 + 3276800;              // 16*32*6400
  double* losses = (double*)buf0;          // 26 doubles, dead region at CKA time

  hipMemsetAsync(G, 0, 13312 * sizeof(double), stream);

  // ---- CAM ----
  cam_energy_k<<<dim3(8, 16, 2), 1024, 0, stream>>>(fS, fT, buf1);
  cam_softmax_k<<<dim3(256, 16, 2), 64, 0, stream>>>(buf1);
  for (int t = 0; t < 2; ++t) {
    ax_k<0><<<dim3(50, 16), 1024, 0, stream>>>(buf1 + (size_t)t * BB * 65536, 65536,
                                               t ? fT : fS, buf0, nullptr, gcam);
    gram_mfma_k<<<dim3(400, 1), 256, 0, stream>>>(buf0, (size_t)0, (size_t)1638400,
                                                  G + t * 256);
  }
  // ---- PAM ----
  for (int t = 0; t < 2; ++t) {
    const float* X = t ? fT : fS;
    qk_k<<<dim3(25, 16), 256, 0, stream>>>(X, Wq, bq, Wk, bk, qt, kf);
    pam_es_k<<<dim3(400), 256, 0, stream>>>(qt, kf, Pbuf);
    ax_k<1><<<dim3(50, 16), 1024, 0, stream>>>(Wv, 0, X, buf0, bv, nullptr);
    pam_pv_k<<<dim3(400), 1024, 0, stream>>>(Pbuf, buf0, fS, fT, gpam, t);
    gram_mfma_k<<<dim3(16, 25), 256, 0, stream>>>(Pbuf, (size_t)1048576, (size_t)65536,
                                                  G + 512 + t * 6400);
  }
  cka_pair_k<<<dim3(26), 256, 0, stream>>>(G, losses);
  cka_combine_k<<<dim3(1), 64, 0, stream>>>(losses, out);
}